// Round 1
// baseline (5850.678 us; speedup 1.0000x reference)
//
#include <hip/hip_runtime.h>
#include <math.h>

#define NN 100000
#define NE 1600000

constexpr float EPS = 1e-8f;
constexpr float LN_EPS = 1e-5f;

__device__ __forceinline__ float silu_f(float v) {
    return v / (1.0f + __expf(-v));
}

// One thread per edge. Wave = 64 edges. Full edge MLP fused; m_ij never
// materialized. LDS used only as a per-lane private, dynamically-indexable
// store (each lane touches column `lane` only -> no barriers, no conflicts).
__global__ __launch_bounds__(64) void edge_kernel(
    const float* __restrict__ h, const float* __restrict__ x,
    const int* __restrict__ ei, const float* __restrict__ ea,
    const float* __restrict__ W1, const float* __restrict__ B1,
    const float* __restrict__ W2, const float* __restrict__ B2,
    const float* __restrict__ Wc1, const float* __restrict__ Bc1,
    const float* __restrict__ Wc2,
    float* __restrict__ m_acc, float* __restrict__ xagg)
{
    __shared__ float lds[64 * 64];   // [k][lane], column-private per lane
    const int lane = threadIdx.x;
    const int e = blockIdx.x * 64 + lane;   // NE % 64 == 0, no tail

    const int row = ei[e];
    const int col = ei[NE + e];

    const float dx = x[row * 3 + 0] - x[col * 3 + 0];
    const float dy = x[row * 3 + 1] - x[col * 3 + 1];
    const float dz = x[row * 3 + 2] - x[col * 3 + 2];
    const float dist_sq = dx * dx + dy * dy + dz * dz;
    const float dist = sqrtf(dist_sq + EPS);
    const float logd = log1pf(dist_sq);

    // ---- msg layer 1: a1[j] = B1[j] + sum_k in[k] * W1[k][j] ----
    float a1[64];
    #pragma unroll
    for (int j = 0; j < 64; ++j) a1[j] = B1[j];

    const float4* hr4 = (const float4*)(h + (size_t)row * 64);
    for (int k4 = 0; k4 < 16; ++k4) {
        const float4 v4 = hr4[k4];
        #pragma unroll
        for (int c = 0; c < 4; ++c) {
            const float v = (c == 0) ? v4.x : (c == 1) ? v4.y : (c == 2) ? v4.z : v4.w;
            const float* w = W1 + (k4 * 4 + c) * 64;
            #pragma unroll
            for (int j = 0; j < 64; ++j) a1[j] = fmaf(v, w[j], a1[j]);
        }
    }
    const float4* hc4 = (const float4*)(h + (size_t)col * 64);
    for (int k4 = 0; k4 < 16; ++k4) {
        const float4 v4 = hc4[k4];
        #pragma unroll
        for (int c = 0; c < 4; ++c) {
            const float v = (c == 0) ? v4.x : (c == 1) ? v4.y : (c == 2) ? v4.z : v4.w;
            const float* w = W1 + (64 + k4 * 4 + c) * 64;
            #pragma unroll
            for (int j = 0; j < 64; ++j) a1[j] = fmaf(v, w[j], a1[j]);
        }
    }
    {
        const float* w = W1 + 128 * 64;
        #pragma unroll
        for (int j = 0; j < 64; ++j) a1[j] = fmaf(logd, w[j], a1[j]);
    }
    const float4* ea4 = (const float4*)(ea + (size_t)e * 16);
    for (int k4 = 0; k4 < 4; ++k4) {
        const float4 v4 = ea4[k4];
        #pragma unroll
        for (int c = 0; c < 4; ++c) {
            const float v = (c == 0) ? v4.x : (c == 1) ? v4.y : (c == 2) ? v4.z : v4.w;
            const float* w = W1 + (129 + k4 * 4 + c) * 64;
            #pragma unroll
            for (int j = 0; j < 64; ++j) a1[j] = fmaf(v, w[j], a1[j]);
        }
    }

    // stash silu(a1) in private LDS column (need dynamic k-indexing below)
    #pragma unroll
    for (int j = 0; j < 64; ++j) lds[j * 64 + lane] = silu_f(a1[j]);

    // ---- msg layer 2 ----
    float a2[64];
    #pragma unroll
    for (int j = 0; j < 64; ++j) a2[j] = B2[j];
    for (int k = 0; k < 64; ++k) {
        const float v = lds[k * 64 + lane];
        const float* w = W2 + k * 64;
        #pragma unroll
        for (int j = 0; j < 64; ++j) a2[j] = fmaf(v, w[j], a2[j]);
    }

    // m_ij = silu(a2); accumulate segment sum; stash m in LDS for coord MLP
    float* mrow = m_acc + (size_t)row * 64;
    #pragma unroll
    for (int j = 0; j < 64; ++j) {
        const float mj = silu_f(a2[j]);
        lds[j * 64 + lane] = mj;
        atomicAdd(mrow + j, mj);
    }

    // ---- coord layer 1: t[j] = Bc1[j] + sum_k m[k] * Wc1[k][j] ----
    float t[64];
    #pragma unroll
    for (int j = 0; j < 64; ++j) t[j] = Bc1[j];
    for (int k = 0; k < 64; ++k) {
        const float v = lds[k * 64 + lane];
        const float* w = Wc1 + k * 64;
        #pragma unroll
        for (int j = 0; j < 64; ++j) t[j] = fmaf(v, w[j], t[j]);
    }
    float g = 0.0f;
    #pragma unroll
    for (int j = 0; j < 64; ++j) g += silu_f(t[j]) * Wc2[j];

    const float gate = tanhf(g) * 0.1f;
    const float s = gate / (dist + EPS);
    atomicAdd(&xagg[row * 4 + 0], dx * s);
    atomicAdd(&xagg[row * 4 + 1], dy * s);
    atomicAdd(&xagg[row * 4 + 2], dz * s);
    atomicAdd(&xagg[row * 4 + 3], 1.0f);
}

// One thread per node. Reads m_acc (aliases h_out region: each thread reads
// its own row before writing it -> safe). LayerNorm is thread-local.
__global__ __launch_bounds__(64) void node_kernel(
    const float* __restrict__ h,
    const float* __restrict__ m_acc, const float* __restrict__ xagg,
    const float* __restrict__ Wn1, const float* __restrict__ Bn1,
    const float* __restrict__ Wn2, const float* __restrict__ Bn2,
    const float* __restrict__ ln_g, const float* __restrict__ ln_b,
    float* __restrict__ h_out)
{
    __shared__ float lds[64 * 64];
    const int lane = threadIdx.x;
    const int node = blockIdx.x * 64 + lane;
    const bool act = node < NN;
    const int n = act ? node : 0;

    const float inv_cnt = 1.0f / (xagg[n * 4 + 3] + EPS);

    float a1[64];
    #pragma unroll
    for (int j = 0; j < 64; ++j) a1[j] = Bn1[j];

    const float* hr = h + (size_t)n * 64;
    const float4* hr4 = (const float4*)hr;
    for (int k4 = 0; k4 < 16; ++k4) {
        const float4 v4 = hr4[k4];
        #pragma unroll
        for (int c = 0; c < 4; ++c) {
            const float v = (c == 0) ? v4.x : (c == 1) ? v4.y : (c == 2) ? v4.z : v4.w;
            const float* w = Wn1 + (k4 * 4 + c) * 64;
            #pragma unroll
            for (int j = 0; j < 64; ++j) a1[j] = fmaf(v, w[j], a1[j]);
        }
    }
    const float4* mr4 = (const float4*)(m_acc + (size_t)n * 64);
    for (int k4 = 0; k4 < 16; ++k4) {
        const float4 v4 = mr4[k4];
        #pragma unroll
        for (int c = 0; c < 4; ++c) {
            const float v = ((c == 0) ? v4.x : (c == 1) ? v4.y : (c == 2) ? v4.z : v4.w) * inv_cnt;
            const float* w = Wn1 + (64 + k4 * 4 + c) * 64;
            #pragma unroll
            for (int j = 0; j < 64; ++j) a1[j] = fmaf(v, w[j], a1[j]);
        }
    }

    #pragma unroll
    for (int j = 0; j < 64; ++j) lds[j * 64 + lane] = silu_f(a1[j]);

    float a2[64];
    #pragma unroll
    for (int j = 0; j < 64; ++j) a2[j] = Bn2[j];
    for (int k = 0; k < 64; ++k) {
        const float v = lds[k * 64 + lane];
        const float* w = Wn2 + k * 64;
        #pragma unroll
        for (int j = 0; j < 64; ++j) a2[j] = fmaf(v, w[j], a2[j]);
    }

    // h_new = h + a2; LayerNorm
    float mu = 0.0f;
    #pragma unroll
    for (int j = 0; j < 64; ++j) { a2[j] += hr[j]; mu += a2[j]; }
    mu *= (1.0f / 64.0f);
    float var = 0.0f;
    #pragma unroll
    for (int j = 0; j < 64; ++j) { const float d = a2[j] - mu; var += d * d; }
    var *= (1.0f / 64.0f);
    const float rstd = rsqrtf(var + LN_EPS);

    if (act) {
        #pragma unroll
        for (int j = 0; j < 64; ++j)
            h_out[(size_t)n * 64 + j] = (a2[j] - mu) * rstd * ln_g[j] + ln_b[j];
    }
}

__global__ void x_kernel(const float* __restrict__ x, const float* __restrict__ xagg,
                         float* __restrict__ x_out)
{
    const int i = blockIdx.x * 256 + threadIdx.x;
    if (i >= NN) return;
    const float inv_cnt = 1.0f / (xagg[i * 4 + 3] + EPS);
    #pragma unroll
    for (int c = 0; c < 3; ++c)
        x_out[(size_t)i * 3 + c] = x[(size_t)i * 3 + c] + xagg[i * 4 + c] * inv_cnt;
}

extern "C" void kernel_launch(void* const* d_in, const int* in_sizes, int n_in,
                              void* d_out, int out_size, void* d_ws, size_t ws_size,
                              hipStream_t stream)
{
    const float* h   = (const float*)d_in[0];
    const float* x   = (const float*)d_in[1];
    const int*   ei  = (const int*)d_in[2];
    const float* ea  = (const float*)d_in[3];
    const float* W1  = (const float*)d_in[4];
    const float* B1  = (const float*)d_in[5];
    const float* W2  = (const float*)d_in[6];
    const float* B2  = (const float*)d_in[7];
    const float* Wn1 = (const float*)d_in[8];
    const float* Bn1 = (const float*)d_in[9];
    const float* Wn2 = (const float*)d_in[10];
    const float* Bn2 = (const float*)d_in[11];
    const float* Wc1 = (const float*)d_in[12];
    const float* Bc1 = (const float*)d_in[13];
    const float* Wc2 = (const float*)d_in[14];
    const float* lng = (const float*)d_in[15];
    const float* lnb = (const float*)d_in[16];

    float* out   = (float*)d_out;
    float* m_acc = out;                       // [N,64]: m_i accumulator, then h_out
    float* x_out = out + (size_t)NN * 64;     // [N,3]
    float* xagg  = (float*)d_ws;              // [N,4]: xyz agg + count

    hipMemsetAsync(m_acc, 0, (size_t)NN * 64 * sizeof(float), stream);
    hipMemsetAsync(xagg, 0, (size_t)NN * 4 * sizeof(float), stream);

    edge_kernel<<<NE / 64, 64, 0, stream>>>(h, x, ei, ea, W1, B1, W2, B2,
                                            Wc1, Bc1, Wc2, m_acc, xagg);
    node_kernel<<<(NN + 63) / 64, 64, 0, stream>>>(h, m_acc, xagg, Wn1, Bn1,
                                                   Wn2, Bn2, lng, lnb, m_acc);
    x_kernel<<<(NN + 255) / 256, 256, 0, stream>>>(x, xagg, x_out);
}

// Round 2
// 1337.590 us; speedup vs baseline: 4.3740x; 4.3740x over previous
//
#include <hip/hip_runtime.h>
#include <math.h>

#define NN 100000
#define NE 1600000

constexpr float EPS = 1e-8f;
constexpr float LN_EPS = 1e-5f;

__device__ __forceinline__ float silu_f(float v) {
    return v / (1.0f + __expf(-v));
}
__device__ __forceinline__ unsigned short f2bf(float f) {
    unsigned int u = __float_as_uint(f);
    unsigned int r = (u + 0x7FFFu + ((u >> 16) & 1u)) >> 16;   // RNE
    return (unsigned short)r;
}
__device__ __forceinline__ float bf2f(unsigned short s) {
    return __uint_as_float(((unsigned int)s) << 16);
}
__device__ __forceinline__ unsigned int pk2(float lo, float hi) {
    return (unsigned int)f2bf(lo) | ((unsigned int)f2bf(hi) << 16);
}

// ---------------- CSR build ----------------

__global__ void count_kernel(const int* __restrict__ ei, int* __restrict__ counts) {
    const int e = blockIdx.x * 256 + threadIdx.x;
    if (e < NE) atomicAdd(&counts[ei[e]], 1);
}

#define SCAN_B 512
__global__ __launch_bounds__(SCAN_B) void scan1_kernel(const int* __restrict__ counts,
                                                       int* __restrict__ offs,
                                                       int* __restrict__ bsum) {
    __shared__ int s[SCAN_B];
    const int tid = threadIdx.x;
    const int idx = blockIdx.x * SCAN_B + tid;
    const int v = (idx < NN) ? counts[idx] : 0;
    s[tid] = v;
    __syncthreads();
    for (int off = 1; off < SCAN_B; off <<= 1) {
        const int t = (tid >= off) ? s[tid - off] : 0;
        __syncthreads();
        s[tid] += t;
        __syncthreads();
    }
    if (idx < NN) offs[idx] = s[tid] - v;       // exclusive, block-local
    if (tid == SCAN_B - 1) bsum[blockIdx.x] = s[tid];
}

__global__ void scan2_kernel(int* __restrict__ bsum, int nblk, int* __restrict__ offs) {
    if (threadIdx.x == 0 && blockIdx.x == 0) {
        int run = 0;
        for (int b = 0; b < nblk; ++b) { const int t = bsum[b]; bsum[b] = run; run += t; }
        offs[NN] = run;   // == NE
    }
}

__global__ __launch_bounds__(SCAN_B) void scan3_kernel(int* __restrict__ offs,
                                                       const int* __restrict__ bsum) {
    const int idx = blockIdx.x * SCAN_B + threadIdx.x;
    if (idx < NN) offs[idx] += bsum[blockIdx.x];
}

__global__ void scatter_kernel(const int* __restrict__ ei, const int* __restrict__ offs,
                               int* __restrict__ cursor, int* __restrict__ ids) {
    const int e = blockIdx.x * 256 + threadIdx.x;
    if (e >= NE) return;
    const int r = ei[e];
    const int pos = offs[r] + atomicAdd(&cursor[r], 1);
    ids[pos] = e;
}

// ---------------- edge MLP (no atomics) ----------------
// 256 threads = 4 waves, one edge per thread. bf16 LDS stash for the
// dynamically-indexed activations (8KB/wave). m_ij -> bf16 scratch, trans -> f32.

__global__ __launch_bounds__(256) void edge_csr_kernel(
    const float* __restrict__ h, const float* __restrict__ x,
    const int* __restrict__ ei, const float* __restrict__ ea,
    const float* __restrict__ W1, const float* __restrict__ B1,
    const float* __restrict__ W2, const float* __restrict__ B2,
    const float* __restrict__ Wc1, const float* __restrict__ Bc1,
    const float* __restrict__ Wc2,
    unsigned short* __restrict__ m_scr, float* __restrict__ trans)
{
    __shared__ unsigned short sst[64][256];
    const int tid = threadIdx.x;
    const int e = blockIdx.x * 256 + tid;       // NE % 256 == 0

    const int row = ei[e];
    const int col = ei[NE + e];

    const float dx = x[row * 3 + 0] - x[col * 3 + 0];
    const float dy = x[row * 3 + 1] - x[col * 3 + 1];
    const float dz = x[row * 3 + 2] - x[col * 3 + 2];
    const float dist_sq = dx * dx + dy * dy + dz * dz;
    const float dist = sqrtf(dist_sq + EPS);
    const float logd = log1pf(dist_sq);

    // ---- msg layer 1 ----
    float a1[64];
    #pragma unroll
    for (int j = 0; j < 64; ++j) a1[j] = B1[j];

    const float4* hr4 = (const float4*)(h + (size_t)row * 64);
    for (int k4 = 0; k4 < 16; ++k4) {
        const float4 v4 = hr4[k4];
        #pragma unroll
        for (int c = 0; c < 4; ++c) {
            const float v = (c == 0) ? v4.x : (c == 1) ? v4.y : (c == 2) ? v4.z : v4.w;
            const float* w = W1 + (k4 * 4 + c) * 64;
            #pragma unroll
            for (int j = 0; j < 64; ++j) a1[j] = fmaf(v, w[j], a1[j]);
        }
    }
    const float4* hc4 = (const float4*)(h + (size_t)col * 64);
    for (int k4 = 0; k4 < 16; ++k4) {
        const float4 v4 = hc4[k4];
        #pragma unroll
        for (int c = 0; c < 4; ++c) {
            const float v = (c == 0) ? v4.x : (c == 1) ? v4.y : (c == 2) ? v4.z : v4.w;
            const float* w = W1 + (64 + k4 * 4 + c) * 64;
            #pragma unroll
            for (int j = 0; j < 64; ++j) a1[j] = fmaf(v, w[j], a1[j]);
        }
    }
    {
        const float* w = W1 + 128 * 64;
        #pragma unroll
        for (int j = 0; j < 64; ++j) a1[j] = fmaf(logd, w[j], a1[j]);
    }
    const float4* ea4 = (const float4*)(ea + (size_t)e * 16);
    for (int k4 = 0; k4 < 4; ++k4) {
        const float4 v4 = ea4[k4];
        #pragma unroll
        for (int c = 0; c < 4; ++c) {
            const float v = (c == 0) ? v4.x : (c == 1) ? v4.y : (c == 2) ? v4.z : v4.w;
            const float* w = W1 + (129 + k4 * 4 + c) * 64;
            #pragma unroll
            for (int j = 0; j < 64; ++j) a1[j] = fmaf(v, w[j], a1[j]);
        }
    }

    #pragma unroll
    for (int j = 0; j < 64; ++j) sst[j][tid] = f2bf(silu_f(a1[j]));
    // per-lane private column: no barrier needed

    // ---- msg layer 2 ----
    float a2[64];
    #pragma unroll
    for (int j = 0; j < 64; ++j) a2[j] = B2[j];
    #pragma unroll 4
    for (int k = 0; k < 64; ++k) {
        const float v = bf2f(sst[k][tid]);
        const float* w = W2 + k * 64;
        #pragma unroll
        for (int j = 0; j < 64; ++j) a2[j] = fmaf(v, w[j], a2[j]);
    }
    #pragma unroll
    for (int j = 0; j < 64; ++j) a2[j] = silu_f(a2[j]);   // = m_ij

    // stash m (bf16) for coord MLP + stream to scratch
    #pragma unroll
    for (int j = 0; j < 64; ++j) sst[j][tid] = f2bf(a2[j]);

    {
        uint4* dst = (uint4*)(m_scr + (size_t)e * 64);
        #pragma unroll
        for (int c = 0; c < 8; ++c) {
            uint4 u;
            u.x = pk2(a2[8 * c + 0], a2[8 * c + 1]);
            u.y = pk2(a2[8 * c + 2], a2[8 * c + 3]);
            u.z = pk2(a2[8 * c + 4], a2[8 * c + 5]);
            u.w = pk2(a2[8 * c + 6], a2[8 * c + 7]);
            dst[c] = u;
        }
    }

    // ---- coord MLP ----
    float t[64];
    #pragma unroll
    for (int j = 0; j < 64; ++j) t[j] = Bc1[j];
    #pragma unroll 4
    for (int k = 0; k < 64; ++k) {
        const float v = bf2f(sst[k][tid]);
        const float* w = Wc1 + k * 64;
        #pragma unroll
        for (int j = 0; j < 64; ++j) t[j] = fmaf(v, w[j], t[j]);
    }
    float g = 0.0f;
    #pragma unroll
    for (int j = 0; j < 64; ++j) g += silu_f(t[j]) * Wc2[j];

    const float s = tanhf(g) * 0.1f / (dist + EPS);
    trans[(size_t)e * 3 + 0] = dx * s;
    trans[(size_t)e * 3 + 1] = dy * s;
    trans[(size_t)e * 3 + 2] = dz * s;
}

// ---------------- gathers ----------------

// wave per node, lane = hidden channel j; coalesced 128B reads per edge
__global__ __launch_bounds__(256) void gather_m_kernel(
    const unsigned short* __restrict__ m_scr, const int* __restrict__ ids,
    const int* __restrict__ offs, float* __restrict__ m_i)
{
    const int wid = blockIdx.x * 4 + (threadIdx.x >> 6);   // node
    const int lane = threadIdx.x & 63;
    const int o0 = offs[wid], o1 = offs[wid + 1];
    float acc = 0.0f;
    for (int o = o0; o < o1; ++o) {
        const int eid = ids[o];
        acc += bf2f(m_scr[(size_t)eid * 64 + lane]);
    }
    m_i[(size_t)wid * 64 + lane] = acc / ((float)(o1 - o0) + EPS);
}

__global__ void gather_x_kernel(const float* __restrict__ x,
                                const float* __restrict__ trans,
                                const int* __restrict__ ids,
                                const int* __restrict__ offs,
                                float* __restrict__ x_out)
{
    const int i = blockIdx.x * 256 + threadIdx.x;
    if (i >= NN) return;
    const int o0 = offs[i], o1 = offs[i + 1];
    float sx = 0.0f, sy = 0.0f, sz = 0.0f;
    for (int o = o0; o < o1; ++o) {
        const int eid = ids[o];
        sx += trans[(size_t)eid * 3 + 0];
        sy += trans[(size_t)eid * 3 + 1];
        sz += trans[(size_t)eid * 3 + 2];
    }
    const float inv = 1.0f / ((float)(o1 - o0) + EPS);
    x_out[(size_t)i * 3 + 0] = x[(size_t)i * 3 + 0] + sx * inv;
    x_out[(size_t)i * 3 + 1] = x[(size_t)i * 3 + 1] + sy * inv;
    x_out[(size_t)i * 3 + 2] = x[(size_t)i * 3 + 2] + sz * inv;
}

// ---------------- node MLP + LayerNorm ----------------

__global__ __launch_bounds__(64) void node_csr_kernel(
    const float* __restrict__ h,
    const float* __restrict__ m_i,
    const float* __restrict__ Wn1, const float* __restrict__ Bn1,
    const float* __restrict__ Wn2, const float* __restrict__ Bn2,
    const float* __restrict__ ln_g, const float* __restrict__ ln_b,
    float* __restrict__ h_out)
{
    __shared__ float lds[64 * 64];
    const int lane = threadIdx.x;
    const int node = blockIdx.x * 64 + lane;
    const bool act = node < NN;
    const int n = act ? node : 0;

    float a1[64];
    #pragma unroll
    for (int j = 0; j < 64; ++j) a1[j] = Bn1[j];

    const float* hr = h + (size_t)n * 64;
    const float4* hr4 = (const float4*)hr;
    for (int k4 = 0; k4 < 16; ++k4) {
        const float4 v4 = hr4[k4];
        #pragma unroll
        for (int c = 0; c < 4; ++c) {
            const float v = (c == 0) ? v4.x : (c == 1) ? v4.y : (c == 2) ? v4.z : v4.w;
            const float* w = Wn1 + (k4 * 4 + c) * 64;
            #pragma unroll
            for (int j = 0; j < 64; ++j) a1[j] = fmaf(v, w[j], a1[j]);
        }
    }
    const float4* mr4 = (const float4*)(m_i + (size_t)n * 64);
    for (int k4 = 0; k4 < 16; ++k4) {
        const float4 v4 = mr4[k4];
        #pragma unroll
        for (int c = 0; c < 4; ++c) {
            const float v = (c == 0) ? v4.x : (c == 1) ? v4.y : (c == 2) ? v4.z : v4.w;
            const float* w = Wn1 + (64 + k4 * 4 + c) * 64;
            #pragma unroll
            for (int j = 0; j < 64; ++j) a1[j] = fmaf(v, w[j], a1[j]);
        }
    }

    #pragma unroll
    for (int j = 0; j < 64; ++j) lds[j * 64 + lane] = silu_f(a1[j]);

    float a2[64];
    #pragma unroll
    for (int j = 0; j < 64; ++j) a2[j] = Bn2[j];
    for (int k = 0; k < 64; ++k) {
        const float v = lds[k * 64 + lane];
        const float* w = Wn2 + k * 64;
        #pragma unroll
        for (int j = 0; j < 64; ++j) a2[j] = fmaf(v, w[j], a2[j]);
    }

    float mu = 0.0f;
    #pragma unroll
    for (int j = 0; j < 64; ++j) { a2[j] += hr[j]; mu += a2[j]; }
    mu *= (1.0f / 64.0f);
    float var = 0.0f;
    #pragma unroll
    for (int j = 0; j < 64; ++j) { const float d = a2[j] - mu; var += d * d; }
    var *= (1.0f / 64.0f);
    const float rstd = rsqrtf(var + LN_EPS);

    if (act) {
        #pragma unroll
        for (int j = 0; j < 64; ++j)
            h_out[(size_t)n * 64 + j] = (a2[j] - mu) * rstd * ln_g[j] + ln_b[j];
    }
}

// ---------------- fallback (round-1 atomic path) ----------------

__global__ __launch_bounds__(64) void edge_atomic_kernel(
    const float* __restrict__ h, const float* __restrict__ x,
    const int* __restrict__ ei, const float* __restrict__ ea,
    const float* __restrict__ W1, const float* __restrict__ B1,
    const float* __restrict__ W2, const float* __restrict__ B2,
    const float* __restrict__ Wc1, const float* __restrict__ Bc1,
    const float* __restrict__ Wc2,
    float* __restrict__ m_acc, float* __restrict__ xagg)
{
    __shared__ float lds[64 * 64];
    const int lane = threadIdx.x;
    const int e = blockIdx.x * 64 + lane;

    const int row = ei[e];
    const int col = ei[NE + e];

    const float dx = x[row * 3 + 0] - x[col * 3 + 0];
    const float dy = x[row * 3 + 1] - x[col * 3 + 1];
    const float dz = x[row * 3 + 2] - x[col * 3 + 2];
    const float dist_sq = dx * dx + dy * dy + dz * dz;
    const float dist = sqrtf(dist_sq + EPS);
    const float logd = log1pf(dist_sq);

    float a1[64];
    #pragma unroll
    for (int j = 0; j < 64; ++j) a1[j] = B1[j];
    const float4* hr4 = (const float4*)(h + (size_t)row * 64);
    for (int k4 = 0; k4 < 16; ++k4) {
        const float4 v4 = hr4[k4];
        #pragma unroll
        for (int c = 0; c < 4; ++c) {
            const float v = (c == 0) ? v4.x : (c == 1) ? v4.y : (c == 2) ? v4.z : v4.w;
            const float* w = W1 + (k4 * 4 + c) * 64;
            #pragma unroll
            for (int j = 0; j < 64; ++j) a1[j] = fmaf(v, w[j], a1[j]);
        }
    }
    const float4* hc4 = (const float4*)(h + (size_t)col * 64);
    for (int k4 = 0; k4 < 16; ++k4) {
        const float4 v4 = hc4[k4];
        #pragma unroll
        for (int c = 0; c < 4; ++c) {
            const float v = (c == 0) ? v4.x : (c == 1) ? v4.y : (c == 2) ? v4.z : v4.w;
            const float* w = W1 + (64 + k4 * 4 + c) * 64;
            #pragma unroll
            for (int j = 0; j < 64; ++j) a1[j] = fmaf(v, w[j], a1[j]);
        }
    }
    {
        const float* w = W1 + 128 * 64;
        #pragma unroll
        for (int j = 0; j < 64; ++j) a1[j] = fmaf(logd, w[j], a1[j]);
    }
    const float4* ea4 = (const float4*)(ea + (size_t)e * 16);
    for (int k4 = 0; k4 < 4; ++k4) {
        const float4 v4 = ea4[k4];
        #pragma unroll
        for (int c = 0; c < 4; ++c) {
            const float v = (c == 0) ? v4.x : (c == 1) ? v4.y : (c == 2) ? v4.z : v4.w;
            const float* w = W1 + (129 + k4 * 4 + c) * 64;
            #pragma unroll
            for (int j = 0; j < 64; ++j) a1[j] = fmaf(v, w[j], a1[j]);
        }
    }

    #pragma unroll
    for (int j = 0; j < 64; ++j) lds[j * 64 + lane] = silu_f(a1[j]);

    float a2[64];
    #pragma unroll
    for (int j = 0; j < 64; ++j) a2[j] = B2[j];
    for (int k = 0; k < 64; ++k) {
        const float v = lds[k * 64 + lane];
        const float* w = W2 + k * 64;
        #pragma unroll
        for (int j = 0; j < 64; ++j) a2[j] = fmaf(v, w[j], a2[j]);
    }

    float* mrow = m_acc + (size_t)row * 64;
    #pragma unroll
    for (int j = 0; j < 64; ++j) {
        const float mj = silu_f(a2[j]);
        lds[j * 64 + lane] = mj;
        atomicAdd(mrow + j, mj);
    }

    float t[64];
    #pragma unroll
    for (int j = 0; j < 64; ++j) t[j] = Bc1[j];
    for (int k = 0; k < 64; ++k) {
        const float v = lds[k * 64 + lane];
        const float* w = Wc1 + k * 64;
        #pragma unroll
        for (int j = 0; j < 64; ++j) t[j] = fmaf(v, w[j], t[j]);
    }
    float g = 0.0f;
    #pragma unroll
    for (int j = 0; j < 64; ++j) g += silu_f(t[j]) * Wc2[j];

    const float gate = tanhf(g) * 0.1f;
    const float s = gate / (dist + EPS);
    atomicAdd(&xagg[row * 4 + 0], dx * s);
    atomicAdd(&xagg[row * 4 + 1], dy * s);
    atomicAdd(&xagg[row * 4 + 2], dz * s);
    atomicAdd(&xagg[row * 4 + 3], 1.0f);
}

__global__ __launch_bounds__(64) void node_atomic_kernel(
    const float* __restrict__ h,
    const float* __restrict__ m_acc, const float* __restrict__ xagg,
    const float* __restrict__ Wn1, const float* __restrict__ Bn1,
    const float* __restrict__ Wn2, const float* __restrict__ Bn2,
    const float* __restrict__ ln_g, const float* __restrict__ ln_b,
    float* __restrict__ h_out)
{
    __shared__ float lds[64 * 64];
    const int lane = threadIdx.x;
    const int node = blockIdx.x * 64 + lane;
    const bool act = node < NN;
    const int n = act ? node : 0;

    const float inv_cnt = 1.0f / (xagg[n * 4 + 3] + EPS);

    float a1[64];
    #pragma unroll
    for (int j = 0; j < 64; ++j) a1[j] = Bn1[j];
    const float* hr = h + (size_t)n * 64;
    const float4* hr4 = (const float4*)hr;
    for (int k4 = 0; k4 < 16; ++k4) {
        const float4 v4 = hr4[k4];
        #pragma unroll
        for (int c = 0; c < 4; ++c) {
            const float v = (c == 0) ? v4.x : (c == 1) ? v4.y : (c == 2) ? v4.z : v4.w;
            const float* w = Wn1 + (k4 * 4 + c) * 64;
            #pragma unroll
            for (int j = 0; j < 64; ++j) a1[j] = fmaf(v, w[j], a1[j]);
        }
    }
    const float4* mr4 = (const float4*)(m_acc + (size_t)n * 64);
    for (int k4 = 0; k4 < 16; ++k4) {
        const float4 v4 = mr4[k4];
        #pragma unroll
        for (int c = 0; c < 4; ++c) {
            const float v = ((c == 0) ? v4.x : (c == 1) ? v4.y : (c == 2) ? v4.z : v4.w) * inv_cnt;
            const float* w = Wn1 + (64 + k4 * 4 + c) * 64;
            #pragma unroll
            for (int j = 0; j < 64; ++j) a1[j] = fmaf(v, w[j], a1[j]);
        }
    }

    #pragma unroll
    for (int j = 0; j < 64; ++j) lds[j * 64 + lane] = silu_f(a1[j]);

    float a2[64];
    #pragma unroll
    for (int j = 0; j < 64; ++j) a2[j] = Bn2[j];
    for (int k = 0; k < 64; ++k) {
        const float v = lds[k * 64 + lane];
        const float* w = Wn2 + k * 64;
        #pragma unroll
        for (int j = 0; j < 64; ++j) a2[j] = fmaf(v, w[j], a2[j]);
    }

    float mu = 0.0f;
    #pragma unroll
    for (int j = 0; j < 64; ++j) { a2[j] += hr[j]; mu += a2[j]; }
    mu *= (1.0f / 64.0f);
    float var = 0.0f;
    #pragma unroll
    for (int j = 0; j < 64; ++j) { const float d = a2[j] - mu; var += d * d; }
    var *= (1.0f / 64.0f);
    const float rstd = rsqrtf(var + LN_EPS);

    if (act) {
        #pragma unroll
        for (int j = 0; j < 64; ++j)
            h_out[(size_t)n * 64 + j] = (a2[j] - mu) * rstd * ln_g[j] + ln_b[j];
    }
}

__global__ void x_atomic_kernel(const float* __restrict__ x, const float* __restrict__ xagg,
                                float* __restrict__ x_out)
{
    const int i = blockIdx.x * 256 + threadIdx.x;
    if (i >= NN) return;
    const float inv_cnt = 1.0f / (xagg[i * 4 + 3] + EPS);
    #pragma unroll
    for (int c = 0; c < 3; ++c)
        x_out[(size_t)i * 3 + c] = x[(size_t)i * 3 + c] + xagg[i * 4 + c] * inv_cnt;
}

// ---------------- launch ----------------

extern "C" void kernel_launch(void* const* d_in, const int* in_sizes, int n_in,
                              void* d_out, int out_size, void* d_ws, size_t ws_size,
                              hipStream_t stream)
{
    const float* h   = (const float*)d_in[0];
    const float* x   = (const float*)d_in[1];
    const int*   ei  = (const int*)d_in[2];
    const float* ea  = (const float*)d_in[3];
    const float* W1  = (const float*)d_in[4];
    const float* B1  = (const float*)d_in[5];
    const float* W2  = (const float*)d_in[6];
    const float* B2  = (const float*)d_in[7];
    const float* Wn1 = (const float*)d_in[8];
    const float* Bn1 = (const float*)d_in[9];
    const float* Wn2 = (const float*)d_in[10];
    const float* Bn2 = (const float*)d_in[11];
    const float* Wc1 = (const float*)d_in[12];
    const float* Bc1 = (const float*)d_in[13];
    const float* Wc2 = (const float*)d_in[14];
    const float* lng = (const float*)d_in[15];
    const float* lnb = (const float*)d_in[16];

    float* out   = (float*)d_out;
    float* x_out = out + (size_t)NN * 64;

    // ws layout
    size_t off = 0;
    auto take = [&](size_t bytes) { size_t p = off; off = (off + bytes + 255) & ~(size_t)255; return p; };
    char* ws = (char*)d_ws;
    const size_t o_mscr   = take((size_t)NE * 64 * 2);
    const size_t o_trans  = take((size_t)NE * 3 * 4);
    const size_t o_ids    = take((size_t)NE * 4);
    const size_t o_counts = take((size_t)NN * 4);
    const size_t o_cursor = take((size_t)NN * 4);
    const size_t o_offs   = take((size_t)(NN + 1) * 4);
    const size_t o_bsum   = take((size_t)1024 * 4);
    const size_t o_mi     = take((size_t)NN * 64 * 4);
    const size_t need = off;

    if (ws_size >= need) {
        unsigned short* m_scr = (unsigned short*)(ws + o_mscr);
        float* trans  = (float*)(ws + o_trans);
        int*   ids    = (int*)(ws + o_ids);
        int*   counts = (int*)(ws + o_counts);
        int*   cursor = (int*)(ws + o_cursor);
        int*   offs   = (int*)(ws + o_offs);
        int*   bsum   = (int*)(ws + o_bsum);
        float* m_i    = (float*)(ws + o_mi);

        hipMemsetAsync(counts, 0, (size_t)NN * 4, stream);
        hipMemsetAsync(cursor, 0, (size_t)NN * 4, stream);

        const int nblk = (NN + SCAN_B - 1) / SCAN_B;
        count_kernel<<<(NE + 255) / 256, 256, 0, stream>>>(ei, counts);
        scan1_kernel<<<nblk, SCAN_B, 0, stream>>>(counts, offs, bsum);
        scan2_kernel<<<1, 64, 0, stream>>>(bsum, nblk, offs);
        scan3_kernel<<<nblk, SCAN_B, 0, stream>>>(offs, bsum);
        scatter_kernel<<<(NE + 255) / 256, 256, 0, stream>>>(ei, offs, cursor, ids);

        edge_csr_kernel<<<NE / 256, 256, 0, stream>>>(h, x, ei, ea, W1, B1, W2, B2,
                                                      Wc1, Bc1, Wc2, m_scr, trans);
        gather_m_kernel<<<NN / 4, 256, 0, stream>>>(m_scr, ids, offs, m_i);
        gather_x_kernel<<<(NN + 255) / 256, 256, 0, stream>>>(x, trans, ids, offs, x_out);
        node_csr_kernel<<<(NN + 63) / 64, 64, 0, stream>>>(h, m_i, Wn1, Bn1, Wn2, Bn2,
                                                           lng, lnb, out);
    } else {
        float* m_acc = out;
        float* xagg  = (float*)d_ws;   // [N,4]
        hipMemsetAsync(m_acc, 0, (size_t)NN * 64 * 4, stream);
        hipMemsetAsync(xagg, 0, (size_t)NN * 4 * 4, stream);
        edge_atomic_kernel<<<NE / 64, 64, 0, stream>>>(h, x, ei, ea, W1, B1, W2, B2,
                                                       Wc1, Bc1, Wc2, m_acc, xagg);
        node_atomic_kernel<<<(NN + 63) / 64, 64, 0, stream>>>(h, m_acc, xagg, Wn1, Bn1,
                                                              Wn2, Bn2, lng, lnb, m_acc);
        x_atomic_kernel<<<(NN + 255) / 256, 256, 0, stream>>>(x, xagg, x_out);
    }
}

// Round 3
// 691.650 us; speedup vs baseline: 8.4590x; 1.9339x over previous
//
#include <hip/hip_runtime.h>
#include <math.h>

#define NN 100000
#define NE 1600000

constexpr float EPS = 1e-8f;
constexpr float LN_EPS = 1e-5f;

typedef short bf16x8 __attribute__((ext_vector_type(8)));
typedef float f32x4 __attribute__((ext_vector_type(4)));

__device__ __forceinline__ float silu_f(float v) {
    return v / (1.0f + __expf(-v));
}
__device__ __forceinline__ unsigned short f2bf(float f) {
    unsigned int u = __float_as_uint(f);
    unsigned int r = (u + 0x7FFFu + ((u >> 16) & 1u)) >> 16;   // RNE
    return (unsigned short)r;
}
__device__ __forceinline__ float bf2f(unsigned short s) {
    return __uint_as_float(((unsigned int)s) << 16);
}
__device__ __forceinline__ unsigned int pk2(float lo, float hi) {
    return (unsigned int)f2bf(lo) | ((unsigned int)f2bf(hi) << 16);
}

// ---------------- prep: bf16 h, frag-ordered bf16 weights ----------------

__global__ void prep_h_kernel(const float* __restrict__ h, unsigned short* __restrict__ hbf) {
    const int i = blockIdx.x * 256 + threadIdx.x;   // 4 elems each
    if (i < NN * 64 / 4) {
        const float4 v = ((const float4*)h)[i];
        uint2 u; u.x = pk2(v.x, v.y); u.y = pk2(v.z, v.w);
        ((uint2*)hbf)[i] = u;
    }
}

// frag order: elem ((c*4+nt)*64 + l)*8 + j  ==  W[k = c*32+(l>>4)*8+j][n = nt*16+(l&15)]
__global__ void prep_w_kernel(const float* __restrict__ W1, const float* __restrict__ W2,
                              const float* __restrict__ Wc1,
                              unsigned short* __restrict__ W1p, unsigned short* __restrict__ W2p,
                              unsigned short* __restrict__ Wc1p) {
    const int idx = blockIdx.x * 256 + threadIdx.x;
    if (idx < 10240) {                       // W1: K=160 (145 real), 5 chunks
        const int j = idx & 7, l = (idx >> 3) & 63, nt = (idx >> 9) & 3, c = idx >> 11;
        const int k = c * 32 + (l >> 4) * 8 + j, n = nt * 16 + (l & 15);
        W1p[idx] = (k < 145) ? f2bf(W1[k * 64 + n]) : (unsigned short)0;
    } else if (idx < 10240 + 4096) {         // W2: K=64, 2 chunks
        const int t = idx - 10240;
        const int j = t & 7, l = (t >> 3) & 63, nt = (t >> 9) & 3, c = t >> 11;
        W2p[t] = f2bf(W2[(c * 32 + (l >> 4) * 8 + j) * 64 + nt * 16 + (l & 15)]);
    } else if (idx < 10240 + 8192) {         // Wc1: K=64, 2 chunks
        const int t = idx - 14336;
        const int j = t & 7, l = (t >> 3) & 63, nt = (t >> 9) & 3, c = t >> 11;
        Wc1p[t] = f2bf(Wc1[(c * 32 + (l >> 4) * 8 + j) * 64 + nt * 16 + (l & 15)]);
    }
}

// ---------------- CSR build ----------------

__global__ void count_kernel(const int* __restrict__ ei, int* __restrict__ counts) {
    const int e = blockIdx.x * 256 + threadIdx.x;
    if (e < NE) atomicAdd(&counts[ei[e]], 1);
}

#define SCAN_B 512
__global__ __launch_bounds__(SCAN_B) void scan1_kernel(const int* __restrict__ counts,
                                                       int* __restrict__ offs,
                                                       int* __restrict__ bsum) {
    __shared__ int s[SCAN_B];
    const int tid = threadIdx.x;
    const int idx = blockIdx.x * SCAN_B + tid;
    const int v = (idx < NN) ? counts[idx] : 0;
    s[tid] = v;
    __syncthreads();
    for (int off = 1; off < SCAN_B; off <<= 1) {
        const int t = (tid >= off) ? s[tid - off] : 0;
        __syncthreads();
        s[tid] += t;
        __syncthreads();
    }
    if (idx < NN) offs[idx] = s[tid] - v;
    if (tid == SCAN_B - 1) bsum[blockIdx.x] = s[tid];
}

__global__ void scan2_kernel(int* __restrict__ bsum, int nblk, int* __restrict__ offs) {
    if (threadIdx.x == 0 && blockIdx.x == 0) {
        int run = 0;
        for (int b = 0; b < nblk; ++b) { const int t = bsum[b]; bsum[b] = run; run += t; }
        offs[NN] = run;
    }
}

__global__ __launch_bounds__(SCAN_B) void scan3_kernel(int* __restrict__ offs,
                                                       const int* __restrict__ bsum) {
    const int idx = blockIdx.x * SCAN_B + threadIdx.x;
    if (idx < NN) offs[idx] += bsum[blockIdx.x];
}

__global__ void scatter_kernel(const int* __restrict__ ei, const int* __restrict__ offs,
                               int* __restrict__ cursor, int4* __restrict__ quads) {
    const int e = blockIdx.x * 256 + threadIdx.x;
    if (e >= NE) return;
    const int r = ei[e];
    const int c = ei[NE + e];
    const int pos = offs[r] + atomicAdd(&cursor[r], 1);
    quads[pos] = make_int4(e, r, c, 0);
}

// ---------------- MFMA edge kernel ----------------
// 256 thr = 4 waves, 64 CSR-ordered edges/block, 16 edges/wave.
// One barrier (weight staging); all activation tiles are per-wave-private rows.

#define FSTR 168   // bf16 row stride of sA (160 + 8 pad; 336B, 16B-aligned)

__global__ __launch_bounds__(256) void edge_mfma_kernel(
    const unsigned short* __restrict__ hbf, const float* __restrict__ x,
    const float* __restrict__ ea,
    const unsigned short* __restrict__ W1p, const unsigned short* __restrict__ W2p,
    const unsigned short* __restrict__ Wc1p,
    const float* __restrict__ B1, const float* __restrict__ B2,
    const float* __restrict__ Bc1, const float* __restrict__ Wc2,
    const int4* __restrict__ quads,
    unsigned short* __restrict__ m_scr, float* __restrict__ trans)
{
    __shared__ short sW1[10240];      // 20480 B
    __shared__ short sW2[4096];       //  8192 B
    __shared__ float sBias[256];      // B1 | B2 | Bc1 | Wc2
    __shared__ short sA[64 * FSTR];   // 21504 B feature/activation tile
    __shared__ float sGeom[64 * 4];   // dx,dy,dz,dist

    const int tid = threadIdx.x;
    const int p0 = blockIdx.x * 64;

    // stage weights (flat, coalesced)
    for (int i = tid; i < 1280; i += 256) ((uint4*)sW1)[i] = ((const uint4*)W1p)[i];
    for (int i = tid; i < 512;  i += 256) ((uint4*)sW2)[i] = ((const uint4*)W2p)[i];
    if (tid < 64) {
        sBias[tid]       = B1[tid];
        sBias[64 + tid]  = B2[tid];
        sBias[128 + tid] = Bc1[tid];
        sBias[192 + tid] = Wc2[tid];
    }

    // stage features: 4 threads per edge slot
    {
        const int s = tid >> 2, q = tid & 3;
        const int4 pr = quads[p0 + s];
        const int eid = pr.x, row = pr.y, col = pr.z;

        const uint4* hr = (const uint4*)(hbf + (size_t)row * 64);
        *(uint4*)&sA[s * FSTR + q * 16]     = hr[q * 2];
        *(uint4*)&sA[s * FSTR + q * 16 + 8] = hr[q * 2 + 1];
        const uint4* hc = (const uint4*)(hbf + (size_t)col * 64);
        *(uint4*)&sA[s * FSTR + 64 + q * 16]     = hc[q * 2];
        *(uint4*)&sA[s * FSTR + 64 + q * 16 + 8] = hc[q * 2 + 1];

        const float4 e4 = ((const float4*)(ea + (size_t)eid * 16))[q];
        sA[s * FSTR + 129 + q * 4 + 0] = (short)f2bf(e4.x);
        sA[s * FSTR + 129 + q * 4 + 1] = (short)f2bf(e4.y);
        sA[s * FSTR + 129 + q * 4 + 2] = (short)f2bf(e4.z);
        sA[s * FSTR + 129 + q * 4 + 3] = (short)f2bf(e4.w);

        if (q == 0) {
            const float dx = x[row * 3 + 0] - x[col * 3 + 0];
            const float dy = x[row * 3 + 1] - x[col * 3 + 1];
            const float dz = x[row * 3 + 2] - x[col * 3 + 2];
            const float dist_sq = dx * dx + dy * dy + dz * dz;
            sGeom[s * 4 + 0] = dx;
            sGeom[s * 4 + 1] = dy;
            sGeom[s * 4 + 2] = dz;
            sGeom[s * 4 + 3] = sqrtf(dist_sq + EPS);
            sA[s * FSTR + 128] = (short)f2bf(log1pf(dist_sq));
        } else if (q == 1) {
            #pragma unroll
            for (int k = 145; k < 160; ++k) sA[s * FSTR + k] = 0;
        }
    }
    __syncthreads();

    const int w = tid >> 6, l = tid & 63;
    const int lr = l & 15;      // A row within wave tile / C col
    const int ks = l >> 4;      // k-segment / C row group
    short* myA = &sA[(w * 16 + lr) * FSTR];

    // ---- msg layer 1: [16,160] @ [160,64] ----
    f32x4 acc[4];
    #pragma unroll
    for (int nt = 0; nt < 4; ++nt) {
        const float b = sBias[nt * 16 + lr];
        acc[nt] = (f32x4){b, b, b, b};
    }
    #pragma unroll
    for (int c = 0; c < 5; ++c) {
        const bf16x8 af = *(const bf16x8*)&myA[c * 32 + ks * 8];
        #pragma unroll
        for (int nt = 0; nt < 4; ++nt) {
            const bf16x8 bf = *(const bf16x8*)&sW1[((c * 4 + nt) * 64 + l) * 8];
            acc[nt] = __builtin_amdgcn_mfma_f32_16x16x32_bf16(af, bf, acc[nt], 0, 0, 0);
        }
    }
    // h1 = silu -> LDS (own wave rows: row (ks*4+i), col nt*16+lr)
    #pragma unroll
    for (int nt = 0; nt < 4; ++nt)
        #pragma unroll
        for (int i = 0; i < 4; ++i)
            sA[(w * 16 + ks * 4 + i) * FSTR + nt * 16 + lr] = (short)f2bf(silu_f(acc[nt][i]));

    // ---- msg layer 2: [16,64] @ [64,64] ----
    f32x4 acc2[4];
    #pragma unroll
    for (int nt = 0; nt < 4; ++nt) {
        const float b = sBias[64 + nt * 16 + lr];
        acc2[nt] = (f32x4){b, b, b, b};
    }
    #pragma unroll
    for (int c = 0; c < 2; ++c) {
        const bf16x8 af = *(const bf16x8*)&myA[c * 32 + ks * 8];
        #pragma unroll
        for (int nt = 0; nt < 4; ++nt) {
            const bf16x8 bf = *(const bf16x8*)&sW2[((c * 4 + nt) * 64 + l) * 8];
            acc2[nt] = __builtin_amdgcn_mfma_f32_16x16x32_bf16(af, bf, acc2[nt], 0, 0, 0);
        }
    }
    // m = silu -> LDS (same rows, cols 0..63)
    #pragma unroll
    for (int nt = 0; nt < 4; ++nt)
        #pragma unroll
        for (int i = 0; i < 4; ++i)
            sA[(w * 16 + ks * 4 + i) * FSTR + nt * 16 + lr] = (short)f2bf(silu_f(acc2[nt][i]));

    // stream m tile to global, coalesced: lane -> row l>>2, 32B chunk l&3
    {
        const short* src = &sA[(w * 16 + (l >> 2)) * FSTR + (l & 3) * 16];
        uint4* dst = (uint4*)(m_scr + ((size_t)(p0 + w * 16 + (l >> 2))) * 64 + (l & 3) * 16);
        dst[0] = *(const uint4*)src;
        dst[1] = *(const uint4*)(src + 8);
    }

    // ---- coord layer 1: [16,64] @ [64,64], B direct from L2 ----
    f32x4 acc3[4];
    #pragma unroll
    for (int nt = 0; nt < 4; ++nt) {
        const float b = sBias[128 + nt * 16 + lr];
        acc3[nt] = (f32x4){b, b, b, b};
    }
    #pragma unroll
    for (int c = 0; c < 2; ++c) {
        const bf16x8 af = *(const bf16x8*)&myA[c * 32 + ks * 8];
        #pragma unroll
        for (int nt = 0; nt < 4; ++nt) {
            const bf16x8 bf = *(const bf16x8*)&Wc1p[((c * 4 + nt) * 64 + l) * 8];
            acc3[nt] = __builtin_amdgcn_mfma_f32_16x16x32_bf16(af, bf, acc3[nt], 0, 0, 0);
        }
    }
    // g[row] = sum_n silu(t[row][n]) * Wc2[n]; reduce across the 16 cols
    float part[4] = {0.0f, 0.0f, 0.0f, 0.0f};
    #pragma unroll
    for (int nt = 0; nt < 4; ++nt) {
        const float wv = sBias[192 + nt * 16 + lr];
        #pragma unroll
        for (int i = 0; i < 4; ++i) part[i] += silu_f(acc3[nt][i]) * wv;
    }
    #pragma unroll
    for (int m = 1; m <= 8; m <<= 1) {
        #pragma unroll
        for (int i = 0; i < 4; ++i) part[i] += __shfl_xor(part[i], m, 64);
    }
    if (lr == 0) {
        #pragma unroll
        for (int i = 0; i < 4; ++i) {
            const int slot = w * 16 + ks * 4 + i;
            const float dist = sGeom[slot * 4 + 3];
            const float sc = tanhf(part[i]) * 0.1f / (dist + EPS);
            const size_t o = (size_t)(p0 + slot) * 3;
            trans[o + 0] = sGeom[slot * 4 + 0] * sc;
            trans[o + 1] = sGeom[slot * 4 + 1] * sc;
            trans[o + 2] = sGeom[slot * 4 + 2] * sc;
        }
    }
}

// ---------------- gathers (streaming, CSR-position-ordered scratch) ----------------

__global__ __launch_bounds__(256) void gather_m_kernel(
    const unsigned short* __restrict__ m_scr, const int* __restrict__ offs,
    float* __restrict__ m_i)
{
    const int wid = blockIdx.x * 4 + (threadIdx.x >> 6);
    const int lane = threadIdx.x & 63;
    const int o0 = offs[wid], o1 = offs[wid + 1];
    float acc = 0.0f;
    int o = o0;
    for (; o + 1 < o1; o += 2)
        acc += bf2f(m_scr[(size_t)o * 64 + lane]) + bf2f(m_scr[(size_t)(o + 1) * 64 + lane]);
    if (o < o1) acc += bf2f(m_scr[(size_t)o * 64 + lane]);
    m_i[(size_t)wid * 64 + lane] = acc / ((float)(o1 - o0) + EPS);
}

__global__ void gather_x_kernel(const float* __restrict__ x,
                                const float* __restrict__ trans,
                                const int* __restrict__ offs,
                                float* __restrict__ x_out)
{
    const int i = blockIdx.x * 256 + threadIdx.x;
    if (i >= NN) return;
    const int o0 = offs[i], o1 = offs[i + 1];
    float sx = 0.0f, sy = 0.0f, sz = 0.0f;
    for (int o = o0; o < o1; ++o) {
        sx += trans[(size_t)o * 3 + 0];
        sy += trans[(size_t)o * 3 + 1];
        sz += trans[(size_t)o * 3 + 2];
    }
    const float inv = 1.0f / ((float)(o1 - o0) + EPS);
    x_out[(size_t)i * 3 + 0] = x[(size_t)i * 3 + 0] + sx * inv;
    x_out[(size_t)i * 3 + 1] = x[(size_t)i * 3 + 1] + sy * inv;
    x_out[(size_t)i * 3 + 2] = x[(size_t)i * 3 + 2] + sz * inv;
}

// ---------------- node MLP + LayerNorm (m_i aliases h_out region) ----------------

__global__ __launch_bounds__(64) void node_csr_kernel(
    const float* __restrict__ h,
    const float* __restrict__ m_i,
    const float* __restrict__ Wn1, const float* __restrict__ Bn1,
    const float* __restrict__ Wn2, const float* __restrict__ Bn2,
    const float* __restrict__ ln_g, const float* __restrict__ ln_b,
    float* __restrict__ h_out)
{
    __shared__ float lds[64 * 64];
    const int lane = threadIdx.x;
    const int node = blockIdx.x * 64 + lane;
    const bool act = node < NN;
    const int n = act ? node : 0;

    float a1[64];
    #pragma unroll
    for (int j = 0; j < 64; ++j) a1[j] = Bn1[j];

    const float* hr = h + (size_t)n * 64;
    const float4* hr4 = (const float4*)hr;
    for (int k4 = 0; k4 < 16; ++k4) {
        const float4 v4 = hr4[k4];
        #pragma unroll
        for (int c = 0; c < 4; ++c) {
            const float v = (c == 0) ? v4.x : (c == 1) ? v4.y : (c == 2) ? v4.z : v4.w;
            const float* w = Wn1 + (k4 * 4 + c) * 64;
            #pragma unroll
            for (int j = 0; j < 64; ++j) a1[j] = fmaf(v, w[j], a1[j]);
        }
    }
    const float4* mr4 = (const float4*)(m_i + (size_t)n * 64);
    for (int k4 = 0; k4 < 16; ++k4) {
        const float4 v4 = mr4[k4];
        #pragma unroll
        for (int c = 0; c < 4; ++c) {
            const float v = (c == 0) ? v4.x : (c == 1) ? v4.y : (c == 2) ? v4.z : v4.w;
            const float* w = Wn1 + (64 + k4 * 4 + c) * 64;
            #pragma unroll
            for (int j = 0; j < 64; ++j) a1[j] = fmaf(v, w[j], a1[j]);
        }
    }

    #pragma unroll
    for (int j = 0; j < 64; ++j) lds[j * 64 + lane] = silu_f(a1[j]);

    float a2[64];
    #pragma unroll
    for (int j = 0; j < 64; ++j) a2[j] = Bn2[j];
    for (int k = 0; k < 64; ++k) {
        const float v = lds[k * 64 + lane];
        const float* w = Wn2 + k * 64;
        #pragma unroll
        for (int j = 0; j < 64; ++j) a2[j] = fmaf(v, w[j], a2[j]);
    }

    float mu = 0.0f;
    #pragma unroll
    for (int j = 0; j < 64; ++j) { a2[j] += hr[j]; mu += a2[j]; }
    mu *= (1.0f / 64.0f);
    float var = 0.0f;
    #pragma unroll
    for (int j = 0; j < 64; ++j) { const float d = a2[j] - mu; var += d * d; }
    var *= (1.0f / 64.0f);
    const float rstd = rsqrtf(var + LN_EPS);

    if (act) {
        #pragma unroll
        for (int j = 0; j < 64; ++j)
            h_out[(size_t)n * 64 + j] = (a2[j] - mu) * rstd * ln_g[j] + ln_b[j];
    }
}

// ---------------- fallback (atomic path, minimal ws) ----------------

__global__ __launch_bounds__(64) void edge_atomic_kernel(
    const float* __restrict__ h, const float* __restrict__ x,
    const int* __restrict__ ei, const float* __restrict__ ea,
    const float* __restrict__ W1, const float* __restrict__ B1,
    const float* __restrict__ W2, const float* __restrict__ B2,
    const float* __restrict__ Wc1, const float* __restrict__ Bc1,
    const float* __restrict__ Wc2,
    float* __restrict__ m_acc, float* __restrict__ xagg)
{
    __shared__ float lds[64 * 64];
    const int lane = threadIdx.x;
    const int e = blockIdx.x * 64 + lane;

    const int row = ei[e];
    const int col = ei[NE + e];

    const float dx = x[row * 3 + 0] - x[col * 3 + 0];
    const float dy = x[row * 3 + 1] - x[col * 3 + 1];
    const float dz = x[row * 3 + 2] - x[col * 3 + 2];
    const float dist_sq = dx * dx + dy * dy + dz * dz;
    const float dist = sqrtf(dist_sq + EPS);
    const float logd = log1pf(dist_sq);

    float a1[64];
    #pragma unroll
    for (int j = 0; j < 64; ++j) a1[j] = B1[j];
    const float4* hr4 = (const float4*)(h + (size_t)row * 64);
    for (int k4 = 0; k4 < 16; ++k4) {
        const float4 v4 = hr4[k4];
        #pragma unroll
        for (int c = 0; c < 4; ++c) {
            const float v = (c == 0) ? v4.x : (c == 1) ? v4.y : (c == 2) ? v4.z : v4.w;
            const float* w = W1 + (k4 * 4 + c) * 64;
            #pragma unroll
            for (int j = 0; j < 64; ++j) a1[j] = fmaf(v, w[j], a1[j]);
        }
    }
    const float4* hc4 = (const float4*)(h + (size_t)col * 64);
    for (int k4 = 0; k4 < 16; ++k4) {
        const float4 v4 = hc4[k4];
        #pragma unroll
        for (int c = 0; c < 4; ++c) {
            const float v = (c == 0) ? v4.x : (c == 1) ? v4.y : (c == 2) ? v4.z : v4.w;
            const float* w = W1 + (64 + k4 * 4 + c) * 64;
            #pragma unroll
            for (int j = 0; j < 64; ++j) a1[j] = fmaf(v, w[j], a1[j]);
        }
    }
    {
        const float* w = W1 + 128 * 64;
        #pragma unroll
        for (int j = 0; j < 64; ++j) a1[j] = fmaf(logd, w[j], a1[j]);
    }
    const float4* ea4 = (const float4*)(ea + (size_t)e * 16);
    for (int k4 = 0; k4 < 4; ++k4) {
        const float4 v4 = ea4[k4];
        #pragma unroll
        for (int c = 0; c < 4; ++c) {
            const float v = (c == 0) ? v4.x : (c == 1) ? v4.y : (c == 2) ? v4.z : v4.w;
            const float* w = W1 + (129 + k4 * 4 + c) * 64;
            #pragma unroll
            for (int j = 0; j < 64; ++j) a1[j] = fmaf(v, w[j], a1[j]);
        }
    }

    #pragma unroll
    for (int j = 0; j < 64; ++j) lds[j * 64 + lane] = silu_f(a1[j]);

    float a2[64];
    #pragma unroll
    for (int j = 0; j < 64; ++j) a2[j] = B2[j];
    for (int k = 0; k < 64; ++k) {
        const float v = lds[k * 64 + lane];
        const float* w = W2 + k * 64;
        #pragma unroll
        for (int j = 0; j < 64; ++j) a2[j] = fmaf(v, w[j], a2[j]);
    }

    float* mrow = m_acc + (size_t)row * 64;
    #pragma unroll
    for (int j = 0; j < 64; ++j) {
        const float mj = silu_f(a2[j]);
        lds[j * 64 + lane] = mj;
        atomicAdd(mrow + j, mj);
    }

    float t[64];
    #pragma unroll
    for (int j = 0; j < 64; ++j) t[j] = Bc1[j];
    for (int k = 0; k < 64; ++k) {
        const float v = lds[k * 64 + lane];
        const float* w = Wc1 + k * 64;
        #pragma unroll
        for (int j = 0; j < 64; ++j) t[j] = fmaf(v, w[j], t[j]);
    }
    float g = 0.0f;
    #pragma unroll
    for (int j = 0; j < 64; ++j) g += silu_f(t[j]) * Wc2[j];

    const float s = tanhf(g) * 0.1f / (dist + EPS);
    atomicAdd(&xagg[row * 4 + 0], dx * s);
    atomicAdd(&xagg[row * 4 + 1], dy * s);
    atomicAdd(&xagg[row * 4 + 2], dz * s);
    atomicAdd(&xagg[row * 4 + 3], 1.0f);
}

__global__ void x_atomic_kernel(const float* __restrict__ x, const float* __restrict__ xagg,
                                float* __restrict__ x_out)
{
    const int i = blockIdx.x * 256 + threadIdx.x;
    if (i >= NN) return;
    const float inv_cnt = 1.0f / (xagg[i * 4 + 3] + EPS);
    #pragma unroll
    for (int c = 0; c < 3; ++c)
        x_out[(size_t)i * 3 + c] = x[(size_t)i * 3 + c] + xagg[i * 4 + c] * inv_cnt;
}

__global__ void div_m_kernel(float* __restrict__ m_acc, const float* __restrict__ xagg) {
    const int i = blockIdx.x * 256 + threadIdx.x;
    if (i >= NN * 64) return;
    m_acc[i] /= (xagg[(i >> 6) * 4 + 3] + EPS);
}

// ---------------- launch ----------------

extern "C" void kernel_launch(void* const* d_in, const int* in_sizes, int n_in,
                              void* d_out, int out_size, void* d_ws, size_t ws_size,
                              hipStream_t stream)
{
    const float* h   = (const float*)d_in[0];
    const float* x   = (const float*)d_in[1];
    const int*   ei  = (const int*)d_in[2];
    const float* ea  = (const float*)d_in[3];
    const float* W1  = (const float*)d_in[4];
    const float* B1  = (const float*)d_in[5];
    const float* W2  = (const float*)d_in[6];
    const float* B2  = (const float*)d_in[7];
    const float* Wn1 = (const float*)d_in[8];
    const float* Bn1 = (const float*)d_in[9];
    const float* Wn2 = (const float*)d_in[10];
    const float* Bn2 = (const float*)d_in[11];
    const float* Wc1 = (const float*)d_in[12];
    const float* Bc1 = (const float*)d_in[13];
    const float* Wc2 = (const float*)d_in[14];
    const float* lng = (const float*)d_in[15];
    const float* lnb = (const float*)d_in[16];

    float* out   = (float*)d_out;
    float* x_out = out + (size_t)NN * 64;

    size_t off = 0;
    auto take = [&](size_t bytes) { size_t p = off; off = (off + bytes + 255) & ~(size_t)255; return p; };
    char* ws = (char*)d_ws;
    const size_t o_mscr   = take((size_t)NE * 64 * 2);     // bf16 m_ij (CSR order)
    const size_t o_trans  = take((size_t)NE * 3 * 4);      // f32 trans (CSR order)
    const size_t o_quads  = take((size_t)NE * 16);         // int4 {eid,row,col,-}
    const size_t o_counts = take((size_t)NN * 4);
    const size_t o_cursor = take((size_t)NN * 4);
    const size_t o_offs   = take((size_t)(NN + 1) * 4);
    const size_t o_bsum   = take((size_t)1024 * 4);
    const size_t o_hbf    = take((size_t)NN * 64 * 2);     // bf16 h
    const size_t o_w1p    = take((size_t)10240 * 2);
    const size_t o_w2p    = take((size_t)4096 * 2);
    const size_t o_wc1p   = take((size_t)4096 * 2);
    const size_t need = off;

    if (ws_size >= need) {
        unsigned short* m_scr = (unsigned short*)(ws + o_mscr);
        float* trans  = (float*)(ws + o_trans);
        int4*  quads  = (int4*)(ws + o_quads);
        int*   counts = (int*)(ws + o_counts);
        int*   cursor = (int*)(ws + o_cursor);
        int*   offs   = (int*)(ws + o_offs);
        int*   bsum   = (int*)(ws + o_bsum);
        unsigned short* hbf = (unsigned short*)(ws + o_hbf);
        unsigned short* W1p = (unsigned short*)(ws + o_w1p);
        unsigned short* W2p = (unsigned short*)(ws + o_w2p);
        unsigned short* Wc1p = (unsigned short*)(ws + o_wc1p);
        float* m_i = out;   // reuse h_out region; node kernel reads-then-overwrites

        hipMemsetAsync(counts, 0, (size_t)NN * 4, stream);
        hipMemsetAsync(cursor, 0, (size_t)NN * 4, stream);

        prep_h_kernel<<<(NN * 64 / 4 + 255) / 256, 256, 0, stream>>>(h, hbf);
        prep_w_kernel<<<(18432 + 255) / 256, 256, 0, stream>>>(W1, W2, Wc1, W1p, W2p, Wc1p);

        const int nblk = (NN + SCAN_B - 1) / SCAN_B;
        count_kernel<<<(NE + 255) / 256, 256, 0, stream>>>(ei, counts);
        scan1_kernel<<<nblk, SCAN_B, 0, stream>>>(counts, offs, bsum);
        scan2_kernel<<<1, 64, 0, stream>>>(bsum, nblk, offs);
        scan3_kernel<<<nblk, SCAN_B, 0, stream>>>(offs, bsum);
        scatter_kernel<<<(NE + 255) / 256, 256, 0, stream>>>(ei, offs, cursor, quads);

        edge_mfma_kernel<<<NE / 64, 256, 0, stream>>>(hbf, x, ea, W1p, W2p, Wc1p,
                                                      B1, B2, Bc1, Wc2, quads,
                                                      m_scr, trans);
        gather_m_kernel<<<NN / 4, 256, 0, stream>>>(m_scr, offs, m_i);
        gather_x_kernel<<<(NN + 255) / 256, 256, 0, stream>>>(x, trans, offs, x_out);
        node_csr_kernel<<<(NN + 63) / 64, 64, 0, stream>>>(h, m_i, Wn1, Bn1, Wn2, Bn2,
                                                           lng, lnb, out);
    } else {
        float* m_acc = out;
        float* xagg  = (float*)d_ws;
        hipMemsetAsync(m_acc, 0, (size_t)NN * 64 * 4, stream);
        hipMemsetAsync(xagg, 0, (size_t)NN * 4 * 4, stream);
        edge_atomic_kernel<<<NE / 64, 64, 0, stream>>>(h, x, ei, ea, W1, B1, W2, B2,
                                                       Wc1, Bc1, Wc2, m_acc, xagg);
        div_m_kernel<<<(NN * 64 + 255) / 256, 256, 0, stream>>>(m_acc, xagg);
        node_csr_kernel<<<(NN + 63) / 64, 64, 0, stream>>>(h, m_acc, Wn1, Bn1, Wn2, Bn2,
                                                           lng, lnb, m_acc);
        x_atomic_kernel<<<(NN + 255) / 256, 256, 0, stream>>>(x, xagg, m_acc + (size_t)NN * 64);
    }
}

// Round 4
// 607.248 us; speedup vs baseline: 9.6347x; 1.1390x over previous
//
#include <hip/hip_runtime.h>
#include <hip/hip_bf16.h>
#include <math.h>

#define NN 100000
#define NE 1600000

constexpr float EPS = 1e-8f;
constexpr float LN_EPS = 1e-5f;

typedef short bf16x8 __attribute__((ext_vector_type(8)));
typedef float f32x4 __attribute__((ext_vector_type(4)));

__device__ __forceinline__ float silu_f(float v) {
    return v / (1.0f + __expf(-v));
}
// HW bf16 converts (compiler emits v_cvt_pk_bf16_f32)
__device__ __forceinline__ short f2bf_hw(float v) {
    union { __hip_bfloat16 b; short s; } u;
    u.b = __float2bfloat16(v);
    return u.s;
}
__device__ __forceinline__ unsigned int pk2_hw(float lo, float hi) {
    union { __hip_bfloat162 b2; unsigned int u; } u;
    u.b2 = __float22bfloat162_rn(make_float2(lo, hi));
    return u.u;
}
__device__ __forceinline__ float bf2f(unsigned short s) {
    return __uint_as_float(((unsigned int)s) << 16);
}
// legacy SW convert (fallback path only)
__device__ __forceinline__ unsigned short f2bf(float f) {
    unsigned int u = __float_as_uint(f);
    unsigned int r = (u + 0x7FFFu + ((u >> 16) & 1u)) >> 16;
    return (unsigned short)r;
}

// ---------------- fused prep: bf16 h + all frag-packed weights ----------------
// frag order: elem ((c*4+nt)*64 + l)*8 + j  ==  W[k = c*32+(l>>4)*8+j][n = nt*16+(l&15)]

#define HB_BLOCKS 6250   // NN*64/4/256

__global__ void prep_kernel(const float* __restrict__ h,
                            const float* __restrict__ W1, const float* __restrict__ W2,
                            const float* __restrict__ Wc1,
                            const float* __restrict__ Wn1, const float* __restrict__ Wn2,
                            unsigned short* __restrict__ hbf,
                            unsigned short* __restrict__ W1p, unsigned short* __restrict__ W2p,
                            unsigned short* __restrict__ Wc1p,
                            unsigned short* __restrict__ Wn1p, unsigned short* __restrict__ Wn2p)
{
    if (blockIdx.x < HB_BLOCKS) {
        const int i = blockIdx.x * 256 + threadIdx.x;     // 4 elems each
        const float4 v = ((const float4*)h)[i];
        uint2 u; u.x = pk2_hw(v.x, v.y); u.y = pk2_hw(v.z, v.w);
        ((uint2*)hbf)[i] = u;
        return;
    }
    const int idx = (blockIdx.x - HB_BLOCKS) * 256 + threadIdx.x;
    if (idx < 10240) {                           // W1: K=160 (145 real)
        const int j = idx & 7, l = (idx >> 3) & 63, nt = (idx >> 9) & 3, c = idx >> 11;
        const int k = c * 32 + (l >> 4) * 8 + j, n = nt * 16 + (l & 15);
        W1p[idx] = (k < 145) ? (unsigned short)f2bf_hw(W1[k * 64 + n]) : (unsigned short)0;
    } else if (idx < 14336) {                    // W2: K=64
        const int t = idx - 10240;
        const int j = t & 7, l = (t >> 3) & 63, nt = (t >> 9) & 3, c = t >> 11;
        W2p[t] = (unsigned short)f2bf_hw(W2[(c * 32 + (l >> 4) * 8 + j) * 64 + nt * 16 + (l & 15)]);
    } else if (idx < 18432) {                    // Wc1: K=64
        const int t = idx - 14336;
        const int j = t & 7, l = (t >> 3) & 63, nt = (t >> 9) & 3, c = t >> 11;
        Wc1p[t] = (unsigned short)f2bf_hw(Wc1[(c * 32 + (l >> 4) * 8 + j) * 64 + nt * 16 + (l & 15)]);
    } else if (idx < 26624) {                    // Wn1: K=128
        const int t = idx - 18432;
        const int j = t & 7, l = (t >> 3) & 63, nt = (t >> 9) & 3, c = t >> 11;
        Wn1p[t] = (unsigned short)f2bf_hw(Wn1[(c * 32 + (l >> 4) * 8 + j) * 64 + nt * 16 + (l & 15)]);
    } else if (idx < 30720) {                    // Wn2: K=64
        const int t = idx - 26624;
        const int j = t & 7, l = (t >> 3) & 63, nt = (t >> 9) & 3, c = t >> 11;
        Wn2p[t] = (unsigned short)f2bf_hw(Wn2[(c * 32 + (l >> 4) * 8 + j) * 64 + nt * 16 + (l & 15)]);
    }
}

// ---------------- CSR build ----------------

__global__ void count_kernel(const int* __restrict__ ei, int* __restrict__ counts) {
    const int e = blockIdx.x * 256 + threadIdx.x;
    if (e < NE) atomicAdd(&counts[ei[e]], 1);
}

#define SCAN_B 512
__global__ __launch_bounds__(SCAN_B) void scan1_kernel(const int* __restrict__ counts,
                                                       int* __restrict__ offs,
                                                       int* __restrict__ bsum) {
    __shared__ int s[SCAN_B];
    const int tid = threadIdx.x;
    const int idx = blockIdx.x * SCAN_B + tid;
    const int v = (idx < NN) ? counts[idx] : 0;
    s[tid] = v;
    __syncthreads();
    for (int off = 1; off < SCAN_B; off <<= 1) {
        const int t = (tid >= off) ? s[tid - off] : 0;
        __syncthreads();
        s[tid] += t;
        __syncthreads();
    }
    if (idx < NN) offs[idx] = s[tid] - v;
    if (tid == SCAN_B - 1) bsum[blockIdx.x] = s[tid];
}

__global__ void scan2_kernel(int* __restrict__ bsum, int nblk, int* __restrict__ offs) {
    if (threadIdx.x == 0 && blockIdx.x == 0) {
        int run = 0;
        for (int b = 0; b < nblk; ++b) { const int t = bsum[b]; bsum[b] = run; run += t; }
        offs[NN] = run;
    }
}

__global__ __launch_bounds__(SCAN_B) void scan3_kernel(int* __restrict__ offs,
                                                       const int* __restrict__ bsum) {
    const int idx = blockIdx.x * SCAN_B + threadIdx.x;
    if (idx < NN) offs[idx] += bsum[blockIdx.x];
}

__global__ void scatter_kernel(const int* __restrict__ ei, const int* __restrict__ offs,
                               int* __restrict__ cursor, int4* __restrict__ quads) {
    const int e = blockIdx.x * 256 + threadIdx.x;
    if (e >= NE) return;
    const int r = ei[e];
    const int c = ei[NE + e];
    const int pos = offs[r] + atomicAdd(&cursor[r], 1);
    quads[pos] = make_int4(e, r, c, 0);
}

// ---------------- MFMA edge kernel ----------------
// 512 thr = 8 waves, 128 CSR-ordered edges/block, 16 edges/wave.
// Only W1 staged in LDS; W2p/Wc1p B-frags via L1. One barrier.

#define FSTR 168   // bf16 row stride (160 + 8 pad; 336B)

__global__ __launch_bounds__(512) void edge_mfma_kernel(
    const unsigned short* __restrict__ hbf, const float* __restrict__ x,
    const float* __restrict__ ea,
    const unsigned short* __restrict__ W1p, const unsigned short* __restrict__ W2p,
    const unsigned short* __restrict__ Wc1p,
    const float* __restrict__ B1, const float* __restrict__ B2,
    const float* __restrict__ Bc1, const float* __restrict__ Wc2,
    const int4* __restrict__ quads,
    unsigned short* __restrict__ m_scr, float* __restrict__ trans)
{
    __shared__ short sW1[10240];       // 20480 B
    __shared__ float sBias[256];       // B1 | B2 | Bc1 | Wc2
    __shared__ short sA[128 * FSTR];   // 43008 B
    __shared__ float sGeom[128 * 4];   // 2048 B

    const int tid = threadIdx.x;
    const int p0 = blockIdx.x * 128;

    for (int i = tid; i < 1280; i += 512) ((uint4*)sW1)[i] = ((const uint4*)W1p)[i];
    if (tid < 64) {
        sBias[tid]       = B1[tid];
        sBias[64 + tid]  = B2[tid];
        sBias[128 + tid] = Bc1[tid];
        sBias[192 + tid] = Wc2[tid];
    }

    // stage features: 4 threads per edge slot
    {
        const int s = tid >> 2, q = tid & 3;
        const int4 pr = quads[p0 + s];
        const int eid = pr.x, row = pr.y, col = pr.z;

        const uint4* hr = (const uint4*)(hbf + (size_t)row * 64);
        *(uint4*)&sA[s * FSTR + q * 16]     = hr[q * 2];
        *(uint4*)&sA[s * FSTR + q * 16 + 8] = hr[q * 2 + 1];
        const uint4* hc = (const uint4*)(hbf + (size_t)col * 64);
        *(uint4*)&sA[s * FSTR + 64 + q * 16]     = hc[q * 2];
        *(uint4*)&sA[s * FSTR + 64 + q * 16 + 8] = hc[q * 2 + 1];

        const float4 e4 = ((const float4*)(ea + (size_t)eid * 16))[q];
        sA[s * FSTR + 129 + q * 4 + 0] = f2bf_hw(e4.x);
        sA[s * FSTR + 129 + q * 4 + 1] = f2bf_hw(e4.y);
        sA[s * FSTR + 129 + q * 4 + 2] = f2bf_hw(e4.z);
        sA[s * FSTR + 129 + q * 4 + 3] = f2bf_hw(e4.w);

        if (q == 0) {
            const float dx = x[row * 3 + 0] - x[col * 3 + 0];
            const float dy = x[row * 3 + 1] - x[col * 3 + 1];
            const float dz = x[row * 3 + 2] - x[col * 3 + 2];
            const float dist_sq = dx * dx + dy * dy + dz * dz;
            sGeom[s * 4 + 0] = dx;
            sGeom[s * 4 + 1] = dy;
            sGeom[s * 4 + 2] = dz;
            sGeom[s * 4 + 3] = sqrtf(dist_sq + EPS);
            sA[s * FSTR + 128] = f2bf_hw(log1pf(dist_sq));
        } else if (q == 1) {
            #pragma unroll
            for (int k = 145; k < 160; ++k) sA[s * FSTR + k] = 0;
        }
    }
    __syncthreads();

    const int w = tid >> 6, l = tid & 63;
    const int lr = l & 15;
    const int ks = l >> 4;
    short* myA = &sA[(w * 16 + lr) * FSTR];

    // ---- msg layer 1: [16,160] @ [160,64] ----
    f32x4 acc[4];
    #pragma unroll
    for (int nt = 0; nt < 4; ++nt) {
        const float b = sBias[nt * 16 + lr];
        acc[nt] = (f32x4){b, b, b, b};
    }
    #pragma unroll
    for (int c = 0; c < 5; ++c) {
        const bf16x8 af = *(const bf16x8*)&myA[c * 32 + ks * 8];
        #pragma unroll
        for (int nt = 0; nt < 4; ++nt) {
            const bf16x8 bf = *(const bf16x8*)&sW1[((c * 4 + nt) * 64 + l) * 8];
            acc[nt] = __builtin_amdgcn_mfma_f32_16x16x32_bf16(af, bf, acc[nt], 0, 0, 0);
        }
    }
    #pragma unroll
    for (int nt = 0; nt < 4; ++nt)
        #pragma unroll
        for (int i = 0; i < 4; ++i)
            sA[(w * 16 + ks * 4 + i) * FSTR + nt * 16 + lr] = f2bf_hw(silu_f(acc[nt][i]));

    // ---- msg layer 2: [16,64] @ [64,64], B via L1 ----
    f32x4 acc2[4];
    #pragma unroll
    for (int nt = 0; nt < 4; ++nt) {
        const float b = sBias[64 + nt * 16 + lr];
        acc2[nt] = (f32x4){b, b, b, b};
    }
    #pragma unroll
    for (int c = 0; c < 2; ++c) {
        const bf16x8 af = *(const bf16x8*)&myA[c * 32 + ks * 8];
        #pragma unroll
        for (int nt = 0; nt < 4; ++nt) {
            const bf16x8 bf = *(const bf16x8*)&W2p[((c * 4 + nt) * 64 + l) * 8];
            acc2[nt] = __builtin_amdgcn_mfma_f32_16x16x32_bf16(af, bf, acc2[nt], 0, 0, 0);
        }
    }
    #pragma unroll
    for (int nt = 0; nt < 4; ++nt)
        #pragma unroll
        for (int i = 0; i < 4; ++i)
            sA[(w * 16 + ks * 4 + i) * FSTR + nt * 16 + lr] = f2bf_hw(silu_f(acc2[nt][i]));

    // stream m tile to global (coalesced re-read of own wave's rows)
    {
        const short* src = &sA[(w * 16 + (l >> 2)) * FSTR + (l & 3) * 16];
        uint4* dst = (uint4*)(m_scr + ((size_t)(p0 + w * 16 + (l >> 2))) * 64 + (l & 3) * 16);
        dst[0] = *(const uint4*)src;
        dst[1] = *(const uint4*)(src + 8);
    }

    // ---- coord layer 1: [16,64] @ [64,64], B via L1 ----
    f32x4 acc3[4];
    #pragma unroll
    for (int nt = 0; nt < 4; ++nt) {
        const float b = sBias[128 + nt * 16 + lr];
        acc3[nt] = (f32x4){b, b, b, b};
    }
    #pragma unroll
    for (int c = 0; c < 2; ++c) {
        const bf16x8 af = *(const bf16x8*)&myA[c * 32 + ks * 8];
        #pragma unroll
        for (int nt = 0; nt < 4; ++nt) {
            const bf16x8 bf = *(const bf16x8*)&Wc1p[((c * 4 + nt) * 64 + l) * 8];
            acc3[nt] = __builtin_amdgcn_mfma_f32_16x16x32_bf16(af, bf, acc3[nt], 0, 0, 0);
        }
    }
    float part[4] = {0.0f, 0.0f, 0.0f, 0.0f};
    #pragma unroll
    for (int nt = 0; nt < 4; ++nt) {
        const float wv = sBias[192 + nt * 16 + lr];
        #pragma unroll
        for (int i = 0; i < 4; ++i) part[i] += silu_f(acc3[nt][i]) * wv;
    }
    #pragma unroll
    for (int m = 1; m <= 8; m <<= 1) {
        #pragma unroll
        for (int i = 0; i < 4; ++i) part[i] += __shfl_xor(part[i], m, 64);
    }
    if (lr == 0) {
        #pragma unroll
        for (int i = 0; i < 4; ++i) {
            const int slot = w * 16 + ks * 4 + i;
            const float dist = sGeom[slot * 4 + 3];
            // fast tanh: (e^{2g}-1)/(e^{2g}+1), clamped
            const float g2 = fminf(fmaxf(2.0f * part[i], -30.0f), 30.0f);
            const float t = __expf(g2);
            const float th = (t - 1.0f) / (t + 1.0f);
            const float sc = th * 0.1f / (dist + EPS);
            const size_t o = (size_t)(p0 + slot) * 3;
            trans[o + 0] = sGeom[slot * 4 + 0] * sc;
            trans[o + 1] = sGeom[slot * 4 + 1] * sc;
            trans[o + 2] = sGeom[slot * 4 + 2] * sc;
        }
    }
}

// ---------------- gathers (streaming, CSR-position-ordered scratch) ----------------

__global__ __launch_bounds__(256) void gather_m_kernel(
    const unsigned short* __restrict__ m_scr, const int* __restrict__ offs,
    float* __restrict__ m_i)
{
    const int wid = blockIdx.x * 4 + (threadIdx.x >> 6);
    const int lane = threadIdx.x & 63;
    const int o0 = offs[wid], o1 = offs[wid + 1];
    float acc = 0.0f;
    int o = o0;
    for (; o + 1 < o1; o += 2)
        acc += bf2f(m_scr[(size_t)o * 64 + lane]) + bf2f(m_scr[(size_t)(o + 1) * 64 + lane]);
    if (o < o1) acc += bf2f(m_scr[(size_t)o * 64 + lane]);
    m_i[(size_t)wid * 64 + lane] = acc / ((float)(o1 - o0) + EPS);
}

__global__ void gather_x_kernel(const float* __restrict__ x,
                                const float* __restrict__ trans,
                                const int* __restrict__ offs,
                                float* __restrict__ x_out)
{
    const int i = blockIdx.x * 256 + threadIdx.x;
    if (i >= NN) return;
    const int o0 = offs[i], o1 = offs[i + 1];
    float sx = 0.0f, sy = 0.0f, sz = 0.0f;
    for (int o = o0; o < o1; ++o) {
        sx += trans[(size_t)o * 3 + 0];
        sy += trans[(size_t)o * 3 + 1];
        sz += trans[(size_t)o * 3 + 2];
    }
    const float inv = 1.0f / ((float)(o1 - o0) + EPS);
    x_out[(size_t)i * 3 + 0] = x[(size_t)i * 3 + 0] + sx * inv;
    x_out[(size_t)i * 3 + 1] = x[(size_t)i * 3 + 1] + sy * inv;
    x_out[(size_t)i * 3 + 2] = x[(size_t)i * 3 + 2] + sz * inv;
}

// ---------------- MFMA node kernel: MLP + residual + LayerNorm ----------------
// 256 thr = 4 waves, 64 nodes/block. m_i aliases h_out rows (own-block rows only).

#define NSTR 136   // 128 + 8 pad

__global__ __launch_bounds__(256) void node_mfma_kernel(
    const unsigned short* __restrict__ hbf, const float* __restrict__ m_i,
    const unsigned short* __restrict__ Wn1p, const unsigned short* __restrict__ Wn2p,
    const float* __restrict__ Bn1, const float* __restrict__ Bn2,
    const float* __restrict__ ln_g, const float* __restrict__ ln_b,
    float* __restrict__ h_out)
{
    __shared__ short sA[64 * NSTR];   // 17408 B
    __shared__ float sBias[256];      // Bn1 | Bn2 | g | b

    const int tid = threadIdx.x;
    const int n0 = blockIdx.x * 64;

    if (tid < 64) {
        sBias[tid]       = Bn1[tid];
        sBias[64 + tid]  = Bn2[tid];
        sBias[128 + tid] = ln_g[tid];
        sBias[192 + tid] = ln_b[tid];
    }
    {
        const int s = tid >> 2, q = tid & 3;
        const int node = n0 + s;
        const int n = (node < NN) ? node : (NN - 1);
        const uint4* hr = (const uint4*)(hbf + (size_t)n * 64);
        *(uint4*)&sA[s * NSTR + q * 16]     = hr[q * 2];
        *(uint4*)&sA[s * NSTR + q * 16 + 8] = hr[q * 2 + 1];
        const float4* mr = (const float4*)(m_i + (size_t)n * 64) + q * 4;
        #pragma unroll
        for (int c2 = 0; c2 < 2; ++c2) {
            const float4 a = mr[c2 * 2], b = mr[c2 * 2 + 1];
            uint4 u;
            u.x = pk2_hw(a.x, a.y); u.y = pk2_hw(a.z, a.w);
            u.z = pk2_hw(b.x, b.y); u.w = pk2_hw(b.z, b.w);
            *(uint4*)&sA[s * NSTR + 64 + q * 16 + c2 * 8] = u;
        }
    }
    __syncthreads();

    const int w = tid >> 6, l = tid & 63;
    const int lr = l & 15;
    const int ks = l >> 4;
    const short* myA = &sA[(w * 16 + lr) * NSTR];

    // ---- node layer 1: [16,128] @ [128,64] ----
    f32x4 acc[4];
    #pragma unroll
    for (int nt = 0; nt < 4; ++nt) {
        const float b = sBias[nt * 16 + lr];
        acc[nt] = (f32x4){b, b, b, b};
    }
    #pragma unroll
    for (int c = 0; c < 4; ++c) {
        const bf16x8 af = *(const bf16x8*)&myA[c * 32 + ks * 8];
        #pragma unroll
        for (int nt = 0; nt < 4; ++nt) {
            const bf16x8 bf = *(const bf16x8*)&Wn1p[((c * 4 + nt) * 64 + l) * 8];
            acc[nt] = __builtin_amdgcn_mfma_f32_16x16x32_bf16(af, bf, acc[nt], 0, 0, 0);
        }
    }
    // silu -> cols 64..127 (keep h at cols 0..63 for the residual)
    #pragma unroll
    for (int nt = 0; nt < 4; ++nt)
        #pragma unroll
        for (int i = 0; i < 4; ++i)
            sA[(w * 16 + ks * 4 + i) * NSTR + 64 + nt * 16 + lr] = f2bf_hw(silu_f(acc[nt][i]));

    // ---- node layer 2: [16,64] @ [64,64] ----
    f32x4 acc2[4];
    #pragma unroll
    for (int nt = 0; nt < 4; ++nt) {
        const float b = sBias[64 + nt * 16 + lr];
        acc2[nt] = (f32x4){b, b, b, b};
    }
    #pragma unroll
    for (int c = 0; c < 2; ++c) {
        const bf16x8 af = *(const bf16x8*)&myA[64 + c * 32 + ks * 8];
        #pragma unroll
        for (int nt = 0; nt < 4; ++nt) {
            const bf16x8 bf = *(const bf16x8*)&Wn2p[((c * 4 + nt) * 64 + l) * 8];
            acc2[nt] = __builtin_amdgcn_mfma_f32_16x16x32_bf16(af, bf, acc2[nt], 0, 0, 0);
        }
    }

    // residual from staged h (cols 0..63), then LayerNorm per row
    float a2[4][4];
    #pragma unroll
    for (int nt = 0; nt < 4; ++nt)
        #pragma unroll
        for (int i = 0; i < 4; ++i)
            a2[nt][i] = acc2[nt][i] +
                bf2f((unsigned short)sA[(w * 16 + ks * 4 + i) * NSTR + nt * 16 + lr]);

    float su[4];
    #pragma unroll
    for (int i = 0; i < 4; ++i)
        su[i] = a2[0][i] + a2[1][i] + a2[2][i] + a2[3][i];
    #pragma unroll
    for (int m = 1; m <= 8; m <<= 1)
        #pragma unroll
        for (int i = 0; i < 4; ++i) su[i] += __shfl_xor(su[i], m, 64);
    float mu[4];
    #pragma unroll
    for (int i = 0; i < 4; ++i) mu[i] = su[i] * (1.0f / 64.0f);

    float sv[4];
    #pragma unroll
    for (int i = 0; i < 4; ++i) {
        float s = 0.0f;
        #pragma unroll
        for (int nt = 0; nt < 4; ++nt) {
            const float d = a2[nt][i] - mu[i];
            s += d * d;
        }
        sv[i] = s;
    }
    #pragma unroll
    for (int m = 1; m <= 8; m <<= 1)
        #pragma unroll
        for (int i = 0; i < 4; ++i) sv[i] += __shfl_xor(sv[i], m, 64);

    #pragma unroll
    for (int i = 0; i < 4; ++i) {
        const float rstd = rsqrtf(sv[i] * (1.0f / 64.0f) + LN_EPS);
        const int node = n0 + w * 16 + ks * 4 + i;
        if (node < NN) {
            #pragma unroll
            for (int nt = 0; nt < 4; ++nt) {
                const int colj = nt * 16 + lr;
                h_out[(size_t)node * 64 + colj] =
                    (a2[nt][i] - mu[i]) * rstd * sBias[128 + colj] + sBias[192 + colj];
            }
        }
    }
}

// ---------------- fallback (atomic path, minimal ws) ----------------

__global__ __launch_bounds__(64) void edge_atomic_kernel(
    const float* __restrict__ h, const float* __restrict__ x,
    const int* __restrict__ ei, const float* __restrict__ ea,
    const float* __restrict__ W1, const float* __restrict__ B1,
    const float* __restrict__ W2, const float* __restrict__ B2,
    const float* __restrict__ Wc1, const float* __restrict__ Bc1,
    const float* __restrict__ Wc2,
    float* __restrict__ m_acc, float* __restrict__ xagg)
{
    __shared__ float lds[64 * 64];
    const int lane = threadIdx.x;
    const int e = blockIdx.x * 64 + lane;

    const int row = ei[e];
    const int col = ei[NE + e];

    const float dx = x[row * 3 + 0] - x[col * 3 + 0];
    const float dy = x[row * 3 + 1] - x[col * 3 + 1];
    const float dz = x[row * 3 + 2] - x[col * 3 + 2];
    const float dist_sq = dx * dx + dy * dy + dz * dz;
    const float dist = sqrtf(dist_sq + EPS);
    const float logd = log1pf(dist_sq);

    float a1[64];
    #pragma unroll
    for (int j = 0; j < 64; ++j) a1[j] = B1[j];
    const float4* hr4 = (const float4*)(h + (size_t)row * 64);
    for (int k4 = 0; k4 < 16; ++k4) {
        const float4 v4 = hr4[k4];
        #pragma unroll
        for (int c = 0; c < 4; ++c) {
            const float v = (c == 0) ? v4.x : (c == 1) ? v4.y : (c == 2) ? v4.z : v4.w;
            const float* w = W1 + (k4 * 4 + c) * 64;
            #pragma unroll
            for (int j = 0; j < 64; ++j) a1[j] = fmaf(v, w[j], a1[j]);
        }
    }
    const float4* hc4 = (const float4*)(h + (size_t)col * 64);
    for (int k4 = 0; k4 < 16; ++k4) {
        const float4 v4 = hc4[k4];
        #pragma unroll
        for (int c = 0; c < 4; ++c) {
            const float v = (c == 0) ? v4.x : (c == 1) ? v4.y : (c == 2) ? v4.z : v4.w;
            const float* w = W1 + (64 + k4 * 4 + c) * 64;
            #pragma unroll
            for (int j = 0; j < 64; ++j) a1[j] = fmaf(v, w[j], a1[j]);
        }
    }
    {
        const float* w = W1 + 128 * 64;
        #pragma unroll
        for (int j = 0; j < 64; ++j) a1[j] = fmaf(logd, w[j], a1[j]);
    }
    const float4* ea4 = (const float4*)(ea + (size_t)e * 16);
    for (int k4 = 0; k4 < 4; ++k4) {
        const float4 v4 = ea4[k4];
        #pragma unroll
        for (int c = 0; c < 4; ++c) {
            const float v = (c == 0) ? v4.x : (c == 1) ? v4.y : (c == 2) ? v4.z : v4.w;
            const float* w = W1 + (129 + k4 * 4 + c) * 64;
            #pragma unroll
            for (int j = 0; j < 64; ++j) a1[j] = fmaf(v, w[j], a1[j]);
        }
    }

    #pragma unroll
    for (int j = 0; j < 64; ++j) lds[j * 64 + lane] = silu_f(a1[j]);

    float a2[64];
    #pragma unroll
    for (int j = 0; j < 64; ++j) a2[j] = B2[j];
    for (int k = 0; k < 64; ++k) {
        const float v = lds[k * 64 + lane];
        const float* w = W2 + k * 64;
        #pragma unroll
        for (int j = 0; j < 64; ++j) a2[j] = fmaf(v, w[j], a2[j]);
    }

    float* mrow = m_acc + (size_t)row * 64;
    #pragma unroll
    for (int j = 0; j < 64; ++j) {
        const float mj = silu_f(a2[j]);
        lds[j * 64 + lane] = mj;
        atomicAdd(mrow + j, mj);
    }

    float t[64];
    #pragma unroll
    for (int j = 0; j < 64; ++j) t[j] = Bc1[j];
    for (int k = 0; k < 64; ++k) {
        const float v = lds[k * 64 + lane];
        const float* w = Wc1 + k * 64;
        #pragma unroll
        for (int j = 0; j < 64; ++j) t[j] = fmaf(v, w[j], t[j]);
    }
    float g = 0.0f;
    #pragma unroll
    for (int j = 0; j < 64; ++j) g += silu_f(t[j]) * Wc2[j];

    const float s = tanhf(g) * 0.1f / (dist + EPS);
    atomicAdd(&xagg[row * 4 + 0], dx * s);
    atomicAdd(&xagg[row * 4 + 1], dy * s);
    atomicAdd(&xagg[row * 4 + 2], dz * s);
    atomicAdd(&xagg[row * 4 + 3], 1.0f);
}

__global__ __launch_bounds__(64) void node_csr_kernel(
    const float* __restrict__ h,
    const float* __restrict__ m_i,
    const float* __restrict__ Wn1, const float* __restrict__ Bn1,
    const float* __restrict__ Wn2, const float* __restrict__ Bn2,
    const float* __restrict__ ln_g, const float* __restrict__ ln_b,
    float* __restrict__ h_out)
{
    __shared__ float lds[64 * 64];
    const int lane = threadIdx.x;
    const int node = blockIdx.x * 64 + lane;
    const bool act = node < NN;
    const int n = act ? node : 0;

    float a1[64];
    #pragma unroll
    for (int j = 0; j < 64; ++j) a1[j] = Bn1[j];

    const float* hr = h + (size_t)n * 64;
    const float4* hr4 = (const float4*)hr;
    for (int k4 = 0; k4 < 16; ++k4) {
        const float4 v4 = hr4[k4];
        #pragma unroll
        for (int c = 0; c < 4; ++c) {
            const float v = (c == 0) ? v4.x : (c == 1) ? v4.y : (c == 2) ? v4.z : v4.w;
            const float* w = Wn1 + (k4 * 4 + c) * 64;
            #pragma unroll
            for (int j = 0; j < 64; ++j) a1[j] = fmaf(v, w[j], a1[j]);
        }
    }
    const float4* mr4 = (const float4*)(m_i + (size_t)n * 64);
    for (int k4 = 0; k4 < 16; ++k4) {
        const float4 v4 = mr4[k4];
        #pragma unroll
        for (int c = 0; c < 4; ++c) {
            const float v = (c == 0) ? v4.x : (c == 1) ? v4.y : (c == 2) ? v4.z : v4.w;
            const float* w = Wn1 + (64 + k4 * 4 + c) * 64;
            #pragma unroll
            for (int j = 0; j < 64; ++j) a1[j] = fmaf(v, w[j], a1[j]);
        }
    }

    #pragma unroll
    for (int j = 0; j < 64; ++j) lds[j * 64 + lane] = silu_f(a1[j]);

    float a2[64];
    #pragma unroll
    for (int j = 0; j < 64; ++j) a2[j] = Bn2[j];
    for (int k = 0; k < 64; ++k) {
        const float v = lds[k * 64 + lane];
        const float* w = Wn2 + k * 64;
        #pragma unroll
        for (int j = 0; j < 64; ++j) a2[j] = fmaf(v, w[j], a2[j]);
    }

    float mu = 0.0f;
    #pragma unroll
    for (int j = 0; j < 64; ++j) { a2[j] += hr[j]; mu += a2[j]; }
    mu *= (1.0f / 64.0f);
    float var = 0.0f;
    #pragma unroll
    for (int j = 0; j < 64; ++j) { const float d = a2[j] - mu; var += d * d; }
    var *= (1.0f / 64.0f);
    const float rstd = rsqrtf(var + LN_EPS);

    if (act) {
        #pragma unroll
        for (int j = 0; j < 64; ++j)
            h_out[(size_t)n * 64 + j] = (a2[j] - mu) * rstd * ln_g[j] + ln_b[j];
    }
}

__global__ void x_atomic_kernel(const float* __restrict__ x, const float* __restrict__ xagg,
                                float* __restrict__ x_out)
{
    const int i = blockIdx.x * 256 + threadIdx.x;
    if (i >= NN) return;
    const float inv_cnt = 1.0f / (xagg[i * 4 + 3] + EPS);
    #pragma unroll
    for (int c = 0; c < 3; ++c)
        x_out[(size_t)i * 3 + c] = x[(size_t)i * 3 + c] + xagg[i * 4 + c] * inv_cnt;
}

__global__ void div_m_kernel(float* __restrict__ m_acc, const float* __restrict__ xagg) {
    const int i = blockIdx.x * 256 + threadIdx.x;
    if (i >= NN * 64) return;
    m_acc[i] /= (xagg[(i >> 6) * 4 + 3] + EPS);
}

// ---------------- launch ----------------

extern "C" void kernel_launch(void* const* d_in, const int* in_sizes, int n_in,
                              void* d_out, int out_size, void* d_ws, size_t ws_size,
                              hipStream_t stream)
{
    const float* h   = (const float*)d_in[0];
    const float* x   = (const float*)d_in[1];
    const int*   ei  = (const int*)d_in[2];
    const float* ea  = (const float*)d_in[3];
    const float* W1  = (const float*)d_in[4];
    const float* B1  = (const float*)d_in[5];
    const float* W2  = (const float*)d_in[6];
    const float* B2  = (const float*)d_in[7];
    const float* Wn1 = (const float*)d_in[8];
    const float* Bn1 = (const float*)d_in[9];
    const float* Wn2 = (const float*)d_in[10];
    const float* Bn2 = (const float*)d_in[11];
    const float* Wc1 = (const float*)d_in[12];
    const float* Bc1 = (const float*)d_in[13];
    const float* Wc2 = (const float*)d_in[14];
    const float* lng = (const float*)d_in[15];
    const float* lnb = (const float*)d_in[16];

    float* out   = (float*)d_out;
    float* x_out = out + (size_t)NN * 64;

    size_t off = 0;
    auto take = [&](size_t bytes) { size_t p = off; off = (off + bytes + 255) & ~(size_t)255; return p; };
    char* ws = (char*)d_ws;
    const size_t o_mscr   = take((size_t)NE * 64 * 2);     // bf16 m_ij (CSR order)
    const size_t o_trans  = take((size_t)NE * 3 * 4);      // f32 trans (CSR order)
    const size_t o_quads  = take((size_t)NE * 16);         // int4 {eid,row,col,-}
    const size_t o_counts = take((size_t)NN * 4);
    const size_t o_cursor = take((size_t)NN * 4);
    const size_t o_offs   = take((size_t)(NN + 1) * 4);
    const size_t o_bsum   = take((size_t)1024 * 4);
    const size_t o_hbf    = take((size_t)NN * 64 * 2);     // bf16 h
    const size_t o_w1p    = take((size_t)10240 * 2);
    const size_t o_w2p    = take((size_t)4096 * 2);
    const size_t o_wc1p   = take((size_t)4096 * 2);
    const size_t o_wn1p   = take((size_t)8192 * 2);
    const size_t o_wn2p   = take((size_t)4096 * 2);
    const size_t need = off;

    if (ws_size >= need) {
        unsigned short* m_scr = (unsigned short*)(ws + o_mscr);
        float* trans  = (float*)(ws + o_trans);
        int4*  quads  = (int4*)(ws + o_quads);
        int*   counts = (int*)(ws + o_counts);
        int*   cursor = (int*)(ws + o_cursor);
        int*   offs   = (int*)(ws + o_offs);
        int*   bsum   = (int*)(ws + o_bsum);
        unsigned short* hbf  = (unsigned short*)(ws + o_hbf);
        unsigned short* W1p  = (unsigned short*)(ws + o_w1p);
        unsigned short* W2p  = (unsigned short*)(ws + o_w2p);
        unsigned short* Wc1p = (unsigned short*)(ws + o_wc1p);
        unsigned short* Wn1p = (unsigned short*)(ws + o_wn1p);
        unsigned short* Wn2p = (unsigned short*)(ws + o_wn2p);
        float* m_i = out;   // aliases h_out region; node kernel reads own rows first

        hipMemsetAsync(counts, 0, (size_t)NN * 4, stream);
        hipMemsetAsync(cursor, 0, (size_t)NN * 4, stream);

        prep_kernel<<<HB_BLOCKS + 120, 256, 0, stream>>>(h, W1, W2, Wc1, Wn1, Wn2,
                                                         hbf, W1p, W2p, Wc1p, Wn1p, Wn2p);

        const int nblk = (NN + SCAN_B - 1) / SCAN_B;
        count_kernel<<<(NE + 255) / 256, 256, 0, stream>>>(ei, counts);
        scan1_kernel<<<nblk, SCAN_B, 0, stream>>>(counts, offs, bsum);
        scan2_kernel<<<1, 64, 0, stream>>>(bsum, nblk, offs);
        scan3_kernel<<<nblk, SCAN_B, 0, stream>>>(offs, bsum);
        scatter_kernel<<<(NE + 255) / 256, 256, 0, stream>>>(ei, offs, cursor, quads);

        edge_mfma_kernel<<<NE / 128, 512, 0, stream>>>(hbf, x, ea, W1p, W2p, Wc1p,
                                                       B1, B2, Bc1, Wc2, quads,
                                                       m_scr, trans);
        gather_m_kernel<<<NN / 4, 256, 0, stream>>>(m_scr, offs, m_i);
        gather_x_kernel<<<(NN + 255) / 256, 256, 0, stream>>>(x, trans, offs, x_out);
        node_mfma_kernel<<<(NN + 63) / 64, 256, 0, stream>>>(hbf, m_i, Wn1p, Wn2p,
                                                             Bn1, Bn2, lng, lnb, out);
    } else {
        float* m_acc = out;
        float* xagg  = (float*)d_ws;
        hipMemsetAsync(m_acc, 0, (size_t)NN * 64 * 4, stream);
        hipMemsetAsync(xagg, 0, (size_t)NN * 4 * 4, stream);
        edge_atomic_kernel<<<NE / 64, 64, 0, stream>>>(h, x, ei, ea, W1, B1, W2, B2,
                                                       Wc1, Bc1, Wc2, m_acc, xagg);
        div_m_kernel<<<(NN * 64 + 255) / 256, 256, 0, stream>>>(m_acc, xagg);
        node_csr_kernel<<<(NN + 63) / 64, 64, 0, stream>>>(h, m_acc, Wn1, Bn1, Wn2, Bn2,
                                                           lng, lnb, m_acc);
        x_atomic_kernel<<<(NN + 255) / 256, 256, 0, stream>>>(x, xagg, m_acc + (size_t)NN * 64);
    }
}

// Round 5
// 525.021 us; speedup vs baseline: 11.1437x; 1.1566x over previous
//
#include <hip/hip_runtime.h>
#include <hip/hip_bf16.h>
#include <math.h>

#define NN 100000
#define NE 1600000

constexpr float EPS = 1e-8f;
constexpr float LN_EPS = 1e-5f;

typedef short bf16x8 __attribute__((ext_vector_type(8)));
typedef float f32x4 __attribute__((ext_vector_type(4)));

__device__ __forceinline__ float rcp_fast(float v) {
    return __builtin_amdgcn_rcpf(v);
}
__device__ __forceinline__ float silu_f(float v) {
    // v * rcp(1+exp(-v)): ~5 instr vs ~12 for precise-div path
    return v * rcp_fast(1.0f + __expf(-v));
}
// HW bf16 converts (compiler emits v_cvt_pk_bf16_f32)
__device__ __forceinline__ short f2bf_hw(float v) {
    union { __hip_bfloat16 b; short s; } u;
    u.b = __float2bfloat16(v);
    return u.s;
}
__device__ __forceinline__ unsigned int pk2_hw(float lo, float hi) {
    union { __hip_bfloat162 b2; unsigned int u; } u;
    u.b2 = __float22bfloat162_rn(make_float2(lo, hi));
    return u.u;
}
__device__ __forceinline__ float bf2f(unsigned short s) {
    return __uint_as_float(((unsigned int)s) << 16);
}

// ---------------- fused prep: bf16 h + frag-packed weights + degree count ----
// frag order: elem ((c*4+nt)*64 + l)*8 + j  ==  W[k = c*32+(l>>4)*8+j][n = nt*16+(l&15)]

#define HB_BLOCKS 6250      // NN*64/4/256
#define PW_BLOCKS 120
#define CNT_BLOCKS 6250     // NE/256

__global__ void prep_count_kernel(const float* __restrict__ h,
                            const float* __restrict__ W1, const float* __restrict__ W2,
                            const float* __restrict__ Wc1,
                            const float* __restrict__ Wn1, const float* __restrict__ Wn2,
                            const int* __restrict__ ei,
                            unsigned short* __restrict__ hbf,
                            unsigned short* __restrict__ W1p, unsigned short* __restrict__ W2p,
                            unsigned short* __restrict__ Wc1p,
                            unsigned short* __restrict__ Wn1p, unsigned short* __restrict__ Wn2p,
                            int* __restrict__ counts)
{
    const int b = blockIdx.x;
    if (b < HB_BLOCKS) {
        const int i = b * 256 + threadIdx.x;     // 4 elems each
        const float4 v = ((const float4*)h)[i];
        uint2 u; u.x = pk2_hw(v.x, v.y); u.y = pk2_hw(v.z, v.w);
        ((uint2*)hbf)[i] = u;
        return;
    }
    if (b < HB_BLOCKS + PW_BLOCKS) {
        const int idx = (b - HB_BLOCKS) * 256 + threadIdx.x;
        if (idx < 10240) {                           // W1: K=160 (145 real)
            const int j = idx & 7, l = (idx >> 3) & 63, nt = (idx >> 9) & 3, c = idx >> 11;
            const int k = c * 32 + (l >> 4) * 8 + j, n = nt * 16 + (l & 15);
            W1p[idx] = (k < 145) ? (unsigned short)f2bf_hw(W1[k * 64 + n]) : (unsigned short)0;
        } else if (idx < 14336) {                    // W2: K=64
            const int t = idx - 10240;
            const int j = t & 7, l = (t >> 3) & 63, nt = (t >> 9) & 3, c = t >> 11;
            W2p[t] = (unsigned short)f2bf_hw(W2[(c * 32 + (l >> 4) * 8 + j) * 64 + nt * 16 + (l & 15)]);
        } else if (idx < 18432) {                    // Wc1: K=64
            const int t = idx - 14336;
            const int j = t & 7, l = (t >> 3) & 63, nt = (t >> 9) & 3, c = t >> 11;
            Wc1p[t] = (unsigned short)f2bf_hw(Wc1[(c * 32 + (l >> 4) * 8 + j) * 64 + nt * 16 + (l & 15)]);
        } else if (idx < 26624) {                    // Wn1: K=128
            const int t = idx - 18432;
            const int j = t & 7, l = (t >> 3) & 63, nt = (t >> 9) & 3, c = t >> 11;
            Wn1p[t] = (unsigned short)f2bf_hw(Wn1[(c * 32 + (l >> 4) * 8 + j) * 64 + nt * 16 + (l & 15)]);
        } else if (idx < 30720) {                    // Wn2: K=64
            const int t = idx - 26624;
            const int j = t & 7, l = (t >> 3) & 63, nt = (t >> 9) & 3, c = t >> 11;
            Wn2p[t] = (unsigned short)f2bf_hw(Wn2[(c * 32 + (l >> 4) * 8 + j) * 64 + nt * 16 + (l & 15)]);
        }
        return;
    }
    const int e = (b - HB_BLOCKS - PW_BLOCKS) * 256 + threadIdx.x;
    if (e < NE) atomicAdd(&counts[ei[e]], 1);
}

// ---------------- CSR build ----------------

#define SCAN_B 512
__global__ __launch_bounds__(SCAN_B) void scan1_kernel(const int* __restrict__ counts,
                                                       int* __restrict__ offs,
                                                       int* __restrict__ bsum) {
    __shared__ int s[SCAN_B];
    const int tid = threadIdx.x;
    const int idx = blockIdx.x * SCAN_B + tid;
    const int v = (idx < NN) ? counts[idx] : 0;
    s[tid] = v;
    __syncthreads();
    for (int off = 1; off < SCAN_B; off <<= 1) {
        const int t = (tid >= off) ? s[tid - off] : 0;
        __syncthreads();
        s[tid] += t;
        __syncthreads();
    }
    if (idx < NN) offs[idx] = s[tid] - v;
    if (tid == SCAN_B - 1) bsum[blockIdx.x] = s[tid];
}

// wave-parallel block-sum scan (nblk <= 512)
__global__ __launch_bounds__(SCAN_B) void scan2_kernel(int* __restrict__ bsum, int nblk,
                                                       int* __restrict__ offs) {
    __shared__ int s[SCAN_B];
    const int tid = threadIdx.x;
    const int v = (tid < nblk) ? bsum[tid] : 0;
    s[tid] = v;
    __syncthreads();
    for (int off = 1; off < SCAN_B; off <<= 1) {
        const int t = (tid >= off) ? s[tid - off] : 0;
        __syncthreads();
        s[tid] += t;
        __syncthreads();
    }
    if (tid < nblk) bsum[tid] = s[tid] - v;       // exclusive
    if (tid == nblk - 1) offs[NN] = s[tid];       // == NE
}

__global__ __launch_bounds__(SCAN_B) void scan3_kernel(int* __restrict__ offs,
                                                       const int* __restrict__ bsum) {
    const int idx = blockIdx.x * SCAN_B + threadIdx.x;
    if (idx < NN) offs[idx] += bsum[blockIdx.x];
}

__global__ void scatter_kernel(const int* __restrict__ ei, const int* __restrict__ offs,
                               int* __restrict__ cursor, int4* __restrict__ quads) {
    const int e = blockIdx.x * 256 + threadIdx.x;
    if (e >= NE) return;
    const int r = ei[e];
    const int c = ei[NE + e];
    const int pos = offs[r] + atomicAdd(&cursor[r], 1);
    quads[pos] = make_int4(e, r, c, 0);
}

// ---------------- MFMA edge kernel ----------------
// 512 thr = 8 waves, 128 CSR-ordered edges/block, 16 edges/wave.
// Only W1 staged in LDS; W2p/Wc1p B-frags via L1. One barrier.

#define FSTR 168   // bf16 row stride (160 + 8 pad; 336B)

__global__ __launch_bounds__(512) void edge_mfma_kernel(
    const unsigned short* __restrict__ hbf, const float* __restrict__ x,
    const float* __restrict__ ea,
    const unsigned short* __restrict__ W1p, const unsigned short* __restrict__ W2p,
    const unsigned short* __restrict__ Wc1p,
    const float* __restrict__ B1, const float* __restrict__ B2,
    const float* __restrict__ Bc1, const float* __restrict__ Wc2,
    const int4* __restrict__ quads,
    unsigned short* __restrict__ m_scr, float* __restrict__ trans)
{
    __shared__ short sW1[10240];       // 20480 B
    __shared__ float sBias[256];       // B1 | B2 | Bc1 | Wc2
    __shared__ short sA[128 * FSTR];   // 43008 B
    __shared__ float sGeom[128 * 4];   // 2048 B

    const int tid = threadIdx.x;
    const int p0 = blockIdx.x * 128;

    for (int i = tid; i < 1280; i += 512) ((uint4*)sW1)[i] = ((const uint4*)W1p)[i];
    if (tid < 64) {
        sBias[tid]       = B1[tid];
        sBias[64 + tid]  = B2[tid];
        sBias[128 + tid] = Bc1[tid];
        sBias[192 + tid] = Wc2[tid];
    }

    // stage features: 4 threads per edge slot
    {
        const int s = tid >> 2, q = tid & 3;
        const int4 pr = quads[p0 + s];
        const int eid = pr.x, row = pr.y, col = pr.z;

        const uint4* hr = (const uint4*)(hbf + (size_t)row * 64);
        *(uint4*)&sA[s * FSTR + q * 16]     = hr[q * 2];
        *(uint4*)&sA[s * FSTR + q * 16 + 8] = hr[q * 2 + 1];
        const uint4* hc = (const uint4*)(hbf + (size_t)col * 64);
        *(uint4*)&sA[s * FSTR + 64 + q * 16]     = hc[q * 2];
        *(uint4*)&sA[s * FSTR + 64 + q * 16 + 8] = hc[q * 2 + 1];

        const float4 e4 = ((const float4*)(ea + (size_t)eid * 16))[q];
        sA[s * FSTR + 129 + q * 4 + 0] = f2bf_hw(e4.x);
        sA[s * FSTR + 129 + q * 4 + 1] = f2bf_hw(e4.y);
        sA[s * FSTR + 129 + q * 4 + 2] = f2bf_hw(e4.z);
        sA[s * FSTR + 129 + q * 4 + 3] = f2bf_hw(e4.w);

        if (q == 0) {
            const float dx = x[row * 3 + 0] - x[col * 3 + 0];
            const float dy = x[row * 3 + 1] - x[col * 3 + 1];
            const float dz = x[row * 3 + 2] - x[col * 3 + 2];
            const float dist_sq = dx * dx + dy * dy + dz * dz;
            sGeom[s * 4 + 0] = dx;
            sGeom[s * 4 + 1] = dy;
            sGeom[s * 4 + 2] = dz;
            sGeom[s * 4 + 3] = sqrtf(dist_sq + EPS);
            sA[s * FSTR + 128] = f2bf_hw(log1pf(dist_sq));
        } else if (q == 1) {
            #pragma unroll
            for (int k = 145; k < 160; ++k) sA[s * FSTR + k] = 0;
        }
    }
    __syncthreads();

    const int w = tid >> 6, l = tid & 63;
    const int lr = l & 15;
    const int ks = l >> 4;
    short* myA = &sA[(w * 16 + lr) * FSTR];

    // ---- msg layer 1: [16,160] @ [160,64] ----
    f32x4 acc[4];
    #pragma unroll
    for (int nt = 0; nt < 4; ++nt) {
        const float b = sBias[nt * 16 + lr];
        acc[nt] = (f32x4){b, b, b, b};
    }
    #pragma unroll
    for (int c = 0; c < 5; ++c) {
        const bf16x8 af = *(const bf16x8*)&myA[c * 32 + ks * 8];
        #pragma unroll
        for (int nt = 0; nt < 4; ++nt) {
            const bf16x8 bf = *(const bf16x8*)&sW1[((c * 4 + nt) * 64 + l) * 8];
            acc[nt] = __builtin_amdgcn_mfma_f32_16x16x32_bf16(af, bf, acc[nt], 0, 0, 0);
        }
    }
    {
        short* pw = &sA[(w * 16 + ks * 4) * FSTR + lr];
        #pragma unroll
        for (int nt = 0; nt < 4; ++nt)
            #pragma unroll
            for (int i = 0; i < 4; ++i)
                pw[i * FSTR + nt * 16] = f2bf_hw(silu_f(acc[nt][i]));
    }

    // ---- msg layer 2: [16,64] @ [64,64], B via L1 ----
    f32x4 acc2[4];
    #pragma unroll
    for (int nt = 0; nt < 4; ++nt) {
        const float b = sBias[64 + nt * 16 + lr];
        acc2[nt] = (f32x4){b, b, b, b};
    }
    #pragma unroll
    for (int c = 0; c < 2; ++c) {
        const bf16x8 af = *(const bf16x8*)&myA[c * 32 + ks * 8];
        #pragma unroll
        for (int nt = 0; nt < 4; ++nt) {
            const bf16x8 bf = *(const bf16x8*)&W2p[((c * 4 + nt) * 64 + l) * 8];
            acc2[nt] = __builtin_amdgcn_mfma_f32_16x16x32_bf16(af, bf, acc2[nt], 0, 0, 0);
        }
    }
    {
        short* pw = &sA[(w * 16 + ks * 4) * FSTR + lr];
        #pragma unroll
        for (int nt = 0; nt < 4; ++nt)
            #pragma unroll
            for (int i = 0; i < 4; ++i)
                pw[i * FSTR + nt * 16] = f2bf_hw(silu_f(acc2[nt][i]));
    }

    // stream m tile to global (coalesced re-read of own wave's rows)
    {
        const short* src = &sA[(w * 16 + (l >> 2)) * FSTR + (l & 3) * 16];
        uint4* dst = (uint4*)(m_scr + ((size_t)(p0 + w * 16 + (l >> 2))) * 64 + (l & 3) * 16);
        dst[0] = *(const uint4*)src;
        dst[1] = *(const uint4*)(src + 8);
    }

    // ---- coord layer 1: [16,64] @ [64,64], B via L1 ----
    f32x4 acc3[4];
    #pragma unroll
    for (int nt = 0; nt < 4; ++nt) {
        const float b = sBias[128 + nt * 16 + lr];
        acc3[nt] = (f32x4){b, b, b, b};
    }
    #pragma unroll
    for (int c = 0; c < 2; ++c) {
        const bf16x8 af = *(const bf16x8*)&myA[c * 32 + ks * 8];
        #pragma unroll
        for (int nt = 0; nt < 4; ++nt) {
            const bf16x8 bf = *(const bf16x8*)&Wc1p[((c * 4 + nt) * 64 + l) * 8];
            acc3[nt] = __builtin_amdgcn_mfma_f32_16x16x32_bf16(af, bf, acc3[nt], 0, 0, 0);
        }
    }
    float part[4] = {0.0f, 0.0f, 0.0f, 0.0f};
    #pragma unroll
    for (int nt = 0; nt < 4; ++nt) {
        const float wv = sBias[192 + nt * 16 + lr];
        #pragma unroll
        for (int i = 0; i < 4; ++i) part[i] += silu_f(acc3[nt][i]) * wv;
    }
    #pragma unroll
    for (int m = 1; m <= 8; m <<= 1) {
        #pragma unroll
        for (int i = 0; i < 4; ++i) part[i] += __shfl_xor(part[i], m, 64);
    }
    if (lr == 0) {
        #pragma unroll
        for (int i = 0; i < 4; ++i) {
            const int slot = w * 16 + ks * 4 + i;
            const float dist = sGeom[slot * 4 + 3];
            // fast tanh: (e^{2g}-1)*rcp(e^{2g}+1), clamped
            const float g2 = fminf(fmaxf(2.0f * part[i], -30.0f), 30.0f);
            const float t = __expf(g2);
            const float th = (t - 1.0f) * rcp_fast(t + 1.0f);
            const float sc = th * 0.1f * rcp_fast(dist + EPS);
            const size_t o = (size_t)(p0 + slot) * 3;
            trans[o + 0] = sGeom[slot * 4 + 0] * sc;
            trans[o + 1] = sGeom[slot * 4 + 1] * sc;
            trans[o + 2] = sGeom[slot * 4 + 2] * sc;
        }
    }
}

// ---------------- gathers (streaming, CSR-position-ordered scratch) ----------------

// wave per node; m_i written as bf16 (half traffic; node stages bf16 anyway)
__global__ __launch_bounds__(256) void gather_m_kernel(
    const unsigned short* __restrict__ m_scr, const int* __restrict__ offs,
    unsigned short* __restrict__ m_ibf)
{
    const int wid = blockIdx.x * 4 + (threadIdx.x >> 6);
    const int lane = threadIdx.x & 63;
    const int o0 = offs[wid], o1 = offs[wid + 1];
    float acc = 0.0f;
    int o = o0;
    for (; o + 1 < o1; o += 2)
        acc += bf2f(m_scr[(size_t)o * 64 + lane]) + bf2f(m_scr[(size_t)(o + 1) * 64 + lane]);
    if (o < o1) acc += bf2f(m_scr[(size_t)o * 64 + lane]);
    m_ibf[(size_t)wid * 64 + lane] =
        (unsigned short)f2bf_hw(acc * rcp_fast((float)(o1 - o0) + EPS));
}

__global__ void gather_x_kernel(const float* __restrict__ x,
                                const float* __restrict__ trans,
                                const int* __restrict__ offs,
                                float* __restrict__ x_out)
{
    const int i = blockIdx.x * 256 + threadIdx.x;
    if (i >= NN) return;
    const int o0 = offs[i], o1 = offs[i + 1];
    float sx = 0.0f, sy = 0.0f, sz = 0.0f;
    for (int o = o0; o < o1; ++o) {
        sx += trans[(size_t)o * 3 + 0];
        sy += trans[(size_t)o * 3 + 1];
        sz += trans[(size_t)o * 3 + 2];
    }
    const float inv = rcp_fast((float)(o1 - o0) + EPS);
    x_out[(size_t)i * 3 + 0] = x[(size_t)i * 3 + 0] + sx * inv;
    x_out[(size_t)i * 3 + 1] = x[(size_t)i * 3 + 1] + sy * inv;
    x_out[(size_t)i * 3 + 2] = x[(size_t)i * 3 + 2] + sz * inv;
}

// ---------------- MFMA node kernel: MLP + residual + LayerNorm ----------------
// 256 thr = 4 waves, 64 nodes/block.

#define NSTR 136   // 128 + 8 pad

__global__ __launch_bounds__(256) void node_mfma_kernel(
    const unsigned short* __restrict__ hbf, const unsigned short* __restrict__ m_ibf,
    const unsigned short* __restrict__ Wn1p, const unsigned short* __restrict__ Wn2p,
    const float* __restrict__ Bn1, const float* __restrict__ Bn2,
    const float* __restrict__ ln_g, const float* __restrict__ ln_b,
    float* __restrict__ h_out)
{
    __shared__ short sA[64 * NSTR];   // 17408 B
    __shared__ float sBias[256];      // Bn1 | Bn2 | g | b

    const int tid = threadIdx.x;
    const int n0 = blockIdx.x * 64;

    if (tid < 64) {
        sBias[tid]       = Bn1[tid];
        sBias[64 + tid]  = Bn2[tid];
        sBias[128 + tid] = ln_g[tid];
        sBias[192 + tid] = ln_b[tid];
    }
    {
        const int s = tid >> 2, q = tid & 3;
        const int node = n0 + s;
        const int n = (node < NN) ? node : (NN - 1);
        const uint4* hr = (const uint4*)(hbf + (size_t)n * 64);
        *(uint4*)&sA[s * NSTR + q * 16]     = hr[q * 2];
        *(uint4*)&sA[s * NSTR + q * 16 + 8] = hr[q * 2 + 1];
        const uint4* mr = (const uint4*)(m_ibf + (size_t)n * 64);
        *(uint4*)&sA[s * NSTR + 64 + q * 16]     = mr[q * 2];
        *(uint4*)&sA[s * NSTR + 64 + q * 16 + 8] = mr[q * 2 + 1];
    }
    __syncthreads();

    const int w = tid >> 6, l = tid & 63;
    const int lr = l & 15;
    const int ks = l >> 4;
    const short* myA = &sA[(w * 16 + lr) * NSTR];

    // ---- node layer 1: [16,128] @ [128,64] ----
    f32x4 acc[4];
    #pragma unroll
    for (int nt = 0; nt < 4; ++nt) {
        const float b = sBias[nt * 16 + lr];
        acc[nt] = (f32x4){b, b, b, b};
    }
    #pragma unroll
    for (int c = 0; c < 4; ++c) {
        const bf16x8 af = *(const bf16x8*)&myA[c * 32 + ks * 8];
        #pragma unroll
        for (int nt = 0; nt < 4; ++nt) {
            const bf16x8 bf = *(const bf16x8*)&Wn1p[((c * 4 + nt) * 64 + l) * 8];
            acc[nt] = __builtin_amdgcn_mfma_f32_16x16x32_bf16(af, bf, acc[nt], 0, 0, 0);
        }
    }
    // silu -> cols 64..127 (keep h at cols 0..63 for the residual)
    {
        short* pw = &sA[(w * 16 + ks * 4) * NSTR + 64 + lr];
        #pragma unroll
        for (int nt = 0; nt < 4; ++nt)
            #pragma unroll
            for (int i = 0; i < 4; ++i)
                pw[i * NSTR + nt * 16] = f2bf_hw(silu_f(acc[nt][i]));
    }

    // ---- node layer 2: [16,64] @ [64,64] ----
    f32x4 acc2[4];
    #pragma unroll
    for (int nt = 0; nt < 4; ++nt) {
        const float b = sBias[64 + nt * 16 + lr];
        acc2[nt] = (f32x4){b, b, b, b};
    }
    #pragma unroll
    for (int c = 0; c < 2; ++c) {
        const bf16x8 af = *(const bf16x8*)&myA[64 + c * 32 + ks * 8];
        #pragma unroll
        for (int nt = 0; nt < 4; ++nt) {
            const bf16x8 bf = *(const bf16x8*)&Wn2p[((c * 4 + nt) * 64 + l) * 8];
            acc2[nt] = __builtin_amdgcn_mfma_f32_16x16x32_bf16(af, bf, acc2[nt], 0, 0, 0);
        }
    }

    // residual from staged h (cols 0..63), then LayerNorm per row
    float a2[4][4];
    #pragma unroll
    for (int nt = 0; nt < 4; ++nt)
        #pragma unroll
        for (int i = 0; i < 4; ++i)
            a2[nt][i] = acc2[nt][i] +
                bf2f((unsigned short)sA[(w * 16 + ks * 4 + i) * NSTR + nt * 16 + lr]);

    float su[4];
    #pragma unroll
    for (int i = 0; i < 4; ++i)
        su[i] = a2[0][i] + a2[1][i] + a2[2][i] + a2[3][i];
    #pragma unroll
    for (int m = 1; m <= 8; m <<= 1)
        #pragma unroll
        for (int i = 0; i < 4; ++i) su[i] += __shfl_xor(su[i], m, 64);
    float mu[4];
    #pragma unroll
    for (int i = 0; i < 4; ++i) mu[i] = su[i] * (1.0f / 64.0f);

    float sv[4];
    #pragma unroll
    for (int i = 0; i < 4; ++i) {
        float s = 0.0f;
        #pragma unroll
        for (int nt = 0; nt < 4; ++nt) {
            const float d = a2[nt][i] - mu[i];
            s += d * d;
        }
        sv[i] = s;
    }
    #pragma unroll
    for (int m = 1; m <= 8; m <<= 1)
        #pragma unroll
        for (int i = 0; i < 4; ++i) sv[i] += __shfl_xor(sv[i], m, 64);

    #pragma unroll
    for (int i = 0; i < 4; ++i) {
        const float rstd = rsqrtf(sv[i] * (1.0f / 64.0f) + LN_EPS);
        const int node = n0 + w * 16 + ks * 4 + i;
        if (node < NN) {
            #pragma unroll
            for (int nt = 0; nt < 4; ++nt) {
                const int colj = nt * 16 + lr;
                h_out[(size_t)node * 64 + colj] =
                    (a2[nt][i] - mu[i]) * rstd * sBias[128 + colj] + sBias[192 + colj];
            }
        }
    }
}

// ---------------- fallback (atomic path, minimal ws) ----------------

__global__ __launch_bounds__(64) void edge_atomic_kernel(
    const float* __restrict__ h, const float* __restrict__ x,
    const int* __restrict__ ei, const float* __restrict__ ea,
    const float* __restrict__ W1, const float* __restrict__ B1,
    const float* __restrict__ W2, const float* __restrict__ B2,
    const float* __restrict__ Wc1, const float* __restrict__ Bc1,
    const float* __restrict__ Wc2,
    float* __restrict__ m_acc, float* __restrict__ xagg)
{
    __shared__ float lds[64 * 64];
    const int lane = threadIdx.x;
    const int e = blockIdx.x * 64 + lane;

    const int row = ei[e];
    const int col = ei[NE + e];

    const float dx = x[row * 3 + 0] - x[col * 3 + 0];
    const float dy = x[row * 3 + 1] - x[col * 3 + 1];
    const float dz = x[row * 3 + 2] - x[col * 3 + 2];
    const float dist_sq = dx * dx + dy * dy + dz * dz;
    const float dist = sqrtf(dist_sq + EPS);
    const float logd = log1pf(dist_sq);

    float a1[64];
    #pragma unroll
    for (int j = 0; j < 64; ++j) a1[j] = B1[j];
    const float4* hr4 = (const float4*)(h + (size_t)row * 64);
    for (int k4 = 0; k4 < 16; ++k4) {
        const float4 v4 = hr4[k4];
        #pragma unroll
        for (int c = 0; c < 4; ++c) {
            const float v = (c == 0) ? v4.x : (c == 1) ? v4.y : (c == 2) ? v4.z : v4.w;
            const float* w = W1 + (k4 * 4 + c) * 64;
            #pragma unroll
            for (int j = 0; j < 64; ++j) a1[j] = fmaf(v, w[j], a1[j]);
        }
    }
    const float4* hc4 = (const float4*)(h + (size_t)col * 64);
    for (int k4 = 0; k4 < 16; ++k4) {
        const float4 v4 = hc4[k4];
        #pragma unroll
        for (int c = 0; c < 4; ++c) {
            const float v = (c == 0) ? v4.x : (c == 1) ? v4.y : (c == 2) ? v4.z : v4.w;
            const float* w = W1 + (64 + k4 * 4 + c) * 64;
            #pragma unroll
            for (int j = 0; j < 64; ++j) a1[j] = fmaf(v, w[j], a1[j]);
        }
    }
    {
        const float* w = W1 + 128 * 64;
        #pragma unroll
        for (int j = 0; j < 64; ++j) a1[j] = fmaf(logd, w[j], a1[j]);
    }
    const float4* ea4 = (const float4*)(ea + (size_t)e * 16);
    for (int k4 = 0; k4 < 4; ++k4) {
        const float4 v4 = ea4[k4];
        #pragma unroll
        for (int c = 0; c < 4; ++c) {
            const float v = (c == 0) ? v4.x : (c == 1) ? v4.y : (c == 2) ? v4.z : v4.w;
            const float* w = W1 + (129 + k4 * 4 + c) * 64;
            #pragma unroll
            for (int j = 0; j < 64; ++j) a1[j] = fmaf(v, w[j], a1[j]);
        }
    }

    #pragma unroll
    for (int j = 0; j < 64; ++j) lds[j * 64 + lane] = silu_f(a1[j]);

    float a2[64];
    #pragma unroll
    for (int j = 0; j < 64; ++j) a2[j] = B2[j];
    for (int k = 0; k < 64; ++k) {
        const float v = lds[k * 64 + lane];
        const float* w = W2 + k * 64;
        #pragma unroll
        for (int j = 0; j < 64; ++j) a2[j] = fmaf(v, w[j], a2[j]);
    }

    float* mrow = m_acc + (size_t)row * 64;
    #pragma unroll
    for (int j = 0; j < 64; ++j) {
        const float mj = silu_f(a2[j]);
        lds[j * 64 + lane] = mj;
        atomicAdd(mrow + j, mj);
    }

    float t[64];
    #pragma unroll
    for (int j = 0; j < 64; ++j) t[j] = Bc1[j];
    for (int k = 0; k < 64; ++k) {
        const float v = lds[k * 64 + lane];
        const float* w = Wc1 + k * 64;
        #pragma unroll
        for (int j = 0; j < 64; ++j) t[j] = fmaf(v, w[j], t[j]);
    }
    float g = 0.0f;
    #pragma unroll
    for (int j = 0; j < 64; ++j) g += silu_f(t[j]) * Wc2[j];

    const float s = tanhf(g) * 0.1f / (dist + EPS);
    atomicAdd(&xagg[row * 4 + 0], dx * s);
    atomicAdd(&xagg[row * 4 + 1], dy * s);
    atomicAdd(&xagg[row * 4 + 2], dz * s);
    atomicAdd(&xagg[row * 4 + 3], 1.0f);
}

__global__ __launch_bounds__(64) void node_csr_kernel(
    const float* __restrict__ h,
    const float* __restrict__ m_i,
    const float* __restrict__ Wn1, const float* __restrict__ Bn1,
    const float* __restrict__ Wn2, const float* __restrict__ Bn2,
    const float* __restrict__ ln_g, const float* __restrict__ ln_b,
    float* __restrict__ h_out)
{
    __shared__ float lds[64 * 64];
    const int lane = threadIdx.x;
    const int node = blockIdx.x * 64 + lane;
    const bool act = node < NN;
    const int n = act ? node : 0;

    float a1[64];
    #pragma unroll
    for (int j = 0; j < 64; ++j) a1[j] = Bn1[j];

    const float* hr = h + (size_t)n * 64;
    const float4* hr4 = (const float4*)hr;
    for (int k4 = 0; k4 < 16; ++k4) {
        const float4 v4 = hr4[k4];
        #pragma unroll
        for (int c = 0; c < 4; ++c) {
            const float v = (c == 0) ? v4.x : (c == 1) ? v4.y : (c == 2) ? v4.z : v4.w;
            const float* w = Wn1 + (k4 * 4 + c) * 64;
            #pragma unroll
            for (int j = 0; j < 64; ++j) a1[j] = fmaf(v, w[j], a1[j]);
        }
    }
    const float4* mr4 = (const float4*)(m_i + (size_t)n * 64);
    for (int k4 = 0; k4 < 16; ++k4) {
        const float4 v4 = mr4[k4];
        #pragma unroll
        for (int c = 0; c < 4; ++c) {
            const float v = (c == 0) ? v4.x : (c == 1) ? v4.y : (c == 2) ? v4.z : v4.w;
            const float* w = Wn1 + (64 + k4 * 4 + c) * 64;
            #pragma unroll
            for (int j = 0; j < 64; ++j) a1[j] = fmaf(v, w[j], a1[j]);
        }
    }

    #pragma unroll
    for (int j = 0; j < 64; ++j) lds[j * 64 + lane] = silu_f(a1[j]);

    float a2[64];
    #pragma unroll
    for (int j = 0; j < 64; ++j) a2[j] = Bn2[j];
    for (int k = 0; k < 64; ++k) {
        const float v = lds[k * 64 + lane];
        const float* w = Wn2 + k * 64;
        #pragma unroll
        for (int j = 0; j < 64; ++j) a2[j] = fmaf(v, w[j], a2[j]);
    }

    float mu = 0.0f;
    #pragma unroll
    for (int j = 0; j < 64; ++j) { a2[j] += hr[j]; mu += a2[j]; }
    mu *= (1.0f / 64.0f);
    float var = 0.0f;
    #pragma unroll
    for (int j = 0; j < 64; ++j) { const float d = a2[j] - mu; var += d * d; }
    var *= (1.0f / 64.0f);
    const float rstd = rsqrtf(var + LN_EPS);

    if (act) {
        #pragma unroll
        for (int j = 0; j < 64; ++j)
            h_out[(size_t)n * 64 + j] = (a2[j] - mu) * rstd * ln_g[j] + ln_b[j];
    }
}

__global__ void x_atomic_kernel(const float* __restrict__ x, const float* __restrict__ xagg,
                                float* __restrict__ x_out)
{
    const int i = blockIdx.x * 256 + threadIdx.x;
    if (i >= NN) return;
    const float inv_cnt = 1.0f / (xagg[i * 4 + 3] + EPS);
    #pragma unroll
    for (int c = 0; c < 3; ++c)
        x_out[(size_t)i * 3 + c] = x[(size_t)i * 3 + c] + xagg[i * 4 + c] * inv_cnt;
}

__global__ void div_m_kernel(float* __restrict__ m_acc, const float* __restrict__ xagg) {
    const int i = blockIdx.x * 256 + threadIdx.x;
    if (i >= NN * 64) return;
    m_acc[i] /= (xagg[(i >> 6) * 4 + 3] + EPS);
}

// ---------------- launch ----------------

extern "C" void kernel_launch(void* const* d_in, const int* in_sizes, int n_in,
                              void* d_out, int out_size, void* d_ws, size_t ws_size,
                              hipStream_t stream)
{
    const float* h   = (const float*)d_in[0];
    const float* x   = (const float*)d_in[1];
    const int*   ei  = (const int*)d_in[2];
    const float* ea  = (const float*)d_in[3];
    const float* W1  = (const float*)d_in[4];
    const float* B1  = (const float*)d_in[5];
    const float* W2  = (const float*)d_in[6];
    const float* B2  = (const float*)d_in[7];
    const float* Wn1 = (const float*)d_in[8];
    const float* Bn1 = (const float*)d_in[9];
    const float* Wn2 = (const float*)d_in[10];
    const float* Bn2 = (const float*)d_in[11];
    const float* Wc1 = (const float*)d_in[12];
    const float* Bc1 = (const float*)d_in[13];
    const float* Wc2 = (const float*)d_in[14];
    const float* lng = (const float*)d_in[15];
    const float* lnb = (const float*)d_in[16];

    float* out   = (float*)d_out;
    float* x_out = out + (size_t)NN * 64;

    size_t off = 0;
    auto take = [&](size_t bytes) { size_t p = off; off = (off + bytes + 255) & ~(size_t)255; return p; };
    char* ws = (char*)d_ws;
    const size_t o_mscr   = take((size_t)NE * 64 * 2);     // bf16 m_ij (CSR order)
    const size_t o_trans  = take((size_t)NE * 3 * 4);      // f32 trans (CSR order)
    const size_t o_quads  = take((size_t)NE * 16);         // int4 {eid,row,col,-}
    const size_t o_counts = take((size_t)NN * 4);
    const size_t o_cursor = take((size_t)NN * 4);
    const size_t o_offs   = take((size_t)(NN + 1) * 4);
    const size_t o_bsum   = take((size_t)1024 * 4);
    const size_t o_hbf    = take((size_t)NN * 64 * 2);     // bf16 h
    const size_t o_mibf   = take((size_t)NN * 64 * 2);     // bf16 m_i
    const size_t o_w1p    = take((size_t)10240 * 2);
    const size_t o_w2p    = take((size_t)4096 * 2);
    const size_t o_wc1p   = take((size_t)4096 * 2);
    const size_t o_wn1p   = take((size_t)8192 * 2);
    const size_t o_wn2p   = take((size_t)4096 * 2);
    const size_t need = off;

    if (ws_size >= need) {
        unsigned short* m_scr = (unsigned short*)(ws + o_mscr);
        float* trans  = (float*)(ws + o_trans);
        int4*  quads  = (int4*)(ws + o_quads);
        int*   counts = (int*)(ws + o_counts);
        int*   cursor = (int*)(ws + o_cursor);
        int*   offs   = (int*)(ws + o_offs);
        int*   bsum   = (int*)(ws + o_bsum);
        unsigned short* hbf   = (unsigned short*)(ws + o_hbf);
        unsigned short* m_ibf = (unsigned short*)(ws + o_mibf);
        unsigned short* W1p   = (unsigned short*)(ws + o_w1p);
        unsigned short* W2p   = (unsigned short*)(ws + o_w2p);
        unsigned short* Wc1p  = (unsigned short*)(ws + o_wc1p);
        unsigned short* Wn1p  = (unsigned short*)(ws + o_wn1p);
        unsigned short* Wn2p  = (unsigned short*)(ws + o_wn2p);

        hipMemsetAsync(counts, 0, (size_t)NN * 4, stream);
        hipMemsetAsync(cursor, 0, (size_t)NN * 4, stream);

        prep_count_kernel<<<HB_BLOCKS + PW_BLOCKS + CNT_BLOCKS, 256, 0, stream>>>(
            h, W1, W2, Wc1, Wn1, Wn2, ei,
            hbf, W1p, W2p, Wc1p, Wn1p, Wn2p, counts);

        const int nblk = (NN + SCAN_B - 1) / SCAN_B;
        scan1_kernel<<<nblk, SCAN_B, 0, stream>>>(counts, offs, bsum);
        scan2_kernel<<<1, SCAN_B, 0, stream>>>(bsum, nblk, offs);
        scan3_kernel<<<nblk, SCAN_B, 0, stream>>>(offs, bsum);
        scatter_kernel<<<(NE + 255) / 256, 256, 0, stream>>>(ei, offs, cursor, quads);

        edge_mfma_kernel<<<NE / 128, 512, 0, stream>>>(hbf, x, ea, W1p, W2p, Wc1p,
                                                       B1, B2, Bc1, Wc2, quads,
                                                       m_scr, trans);
        gather_m_kernel<<<NN / 4, 256, 0, stream>>>(m_scr, offs, m_ibf);
        gather_x_kernel<<<(NN + 255) / 256, 256, 0, stream>>>(x, trans, offs, x_out);
        node_mfma_kernel<<<(NN + 63) / 64, 256, 0, stream>>>(hbf, m_ibf, Wn1p, Wn2p,
                                                             Bn1, Bn2, lng, lnb, out);
    } else {
        float* m_acc = out;
        float* xagg  = (float*)d_ws;
        hipMemsetAsync(m_acc, 0, (size_t)NN * 64 * 4, stream);
        hipMemsetAsync(xagg, 0, (size_t)NN * 4 * 4, stream);
        edge_atomic_kernel<<<NE / 64, 64, 0, stream>>>(h, x, ei, ea, W1, B1, W2, B2,
                                                       Wc1, Bc1, Wc2, m_acc, xagg);
        div_m_kernel<<<(NN * 64 + 255) / 256, 256, 0, stream>>>(m_acc, xagg);
        node_csr_kernel<<<(NN + 63) / 64, 64, 0, stream>>>(h, m_acc, Wn1, Bn1, Wn2, Bn2,
                                                           lng, lnb, m_acc);
        x_atomic_kernel<<<(NN + 255) / 256, 256, 0, stream>>>(x, xagg, m_acc + (size_t)NN * 64);
    }
}

// Round 6
// 455.463 us; speedup vs baseline: 12.8456x; 1.1527x over previous
//
#include <hip/hip_runtime.h>
#include <hip/hip_bf16.h>
#include <math.h>

#define NN 100000
#define NE 1600000

constexpr float EPS = 1e-8f;
constexpr float LN_EPS = 1e-5f;

typedef short bf16x8 __attribute__((ext_vector_type(8)));
typedef float f32x4 __attribute__((ext_vector_type(4)));

__device__ __forceinline__ float rcp_fast(float v) {
    return __builtin_amdgcn_rcpf(v);
}
__device__ __forceinline__ float silu_f(float v) {
    return v * rcp_fast(1.0f + __expf(-v));
}
// HW bf16 converts (compiler emits v_cvt_pk_bf16_f32)
__device__ __forceinline__ short f2bf_hw(float v) {
    union { __hip_bfloat16 b; short s; } u;
    u.b = __float2bfloat16(v);
    return u.s;
}
__device__ __forceinline__ unsigned int pk2_hw(float lo, float hi) {
    union { __hip_bfloat162 b2; unsigned int u; } u;
    u.b2 = __float22bfloat162_rn(make_float2(lo, hi));
    return u.u;
}
__device__ __forceinline__ float bf2f(unsigned short s) {
    return __uint_as_float(((unsigned int)s) << 16);
}

// ---------------- fused prep: bf16 h + frag-packed weights + count+rank ------
// frag order: elem ((c*4+nt)*64 + l)*8 + j  ==  W[k = c*32+(l>>4)*8+j][n = nt*16+(l&15)]

#define HB_BLOCKS 6250      // NN*64/4/256
#define PW_BLOCKS 120
#define CNT_BLOCKS 6250     // NE/256

__global__ void prep_count_kernel(const float* __restrict__ h,
                            const float* __restrict__ W1, const float* __restrict__ W2,
                            const float* __restrict__ Wc1,
                            const float* __restrict__ Wn1, const float* __restrict__ Wn2,
                            const int* __restrict__ ei,
                            unsigned short* __restrict__ hbf,
                            unsigned short* __restrict__ W1p, unsigned short* __restrict__ W2p,
                            unsigned short* __restrict__ Wc1p,
                            unsigned short* __restrict__ Wn1p, unsigned short* __restrict__ Wn2p,
                            int* __restrict__ counts, int* __restrict__ rank)
{
    const int b = blockIdx.x;
    if (b < HB_BLOCKS) {
        const int i = b * 256 + threadIdx.x;     // 4 elems each
        const float4 v = ((const float4*)h)[i];
        uint2 u; u.x = pk2_hw(v.x, v.y); u.y = pk2_hw(v.z, v.w);
        ((uint2*)hbf)[i] = u;
        return;
    }
    if (b < HB_BLOCKS + PW_BLOCKS) {
        const int idx = (b - HB_BLOCKS) * 256 + threadIdx.x;
        if (idx < 10240) {                           // W1: K=160 (145 real)
            const int j = idx & 7, l = (idx >> 3) & 63, nt = (idx >> 9) & 3, c = idx >> 11;
            const int k = c * 32 + (l >> 4) * 8 + j, n = nt * 16 + (l & 15);
            W1p[idx] = (k < 145) ? (unsigned short)f2bf_hw(W1[k * 64 + n]) : (unsigned short)0;
        } else if (idx < 14336) {                    // W2: K=64
            const int t = idx - 10240;
            const int j = t & 7, l = (t >> 3) & 63, nt = (t >> 9) & 3, c = t >> 11;
            W2p[t] = (unsigned short)f2bf_hw(W2[(c * 32 + (l >> 4) * 8 + j) * 64 + nt * 16 + (l & 15)]);
        } else if (idx < 18432) {                    // Wc1: K=64
            const int t = idx - 14336;
            const int j = t & 7, l = (t >> 3) & 63, nt = (t >> 9) & 3, c = t >> 11;
            Wc1p[t] = (unsigned short)f2bf_hw(Wc1[(c * 32 + (l >> 4) * 8 + j) * 64 + nt * 16 + (l & 15)]);
        } else if (idx < 26624) {                    // Wn1: K=128
            const int t = idx - 18432;
            const int j = t & 7, l = (t >> 3) & 63, nt = (t >> 9) & 3, c = t >> 11;
            Wn1p[t] = (unsigned short)f2bf_hw(Wn1[(c * 32 + (l >> 4) * 8 + j) * 64 + nt * 16 + (l & 15)]);
        } else if (idx < 30720) {                    // Wn2: K=64
            const int t = idx - 26624;
            const int j = t & 7, l = (t >> 3) & 63, nt = (t >> 9) & 3, c = t >> 11;
            Wn2p[t] = (unsigned short)f2bf_hw(Wn2[(c * 32 + (l >> 4) * 8 + j) * 64 + nt * 16 + (l & 15)]);
        }
        return;
    }
    // count + rank in one atomic pass: the returned old value IS the rank
    const int e = (b - HB_BLOCKS - PW_BLOCKS) * 256 + threadIdx.x;
    if (e < NE) rank[e] = atomicAdd(&counts[ei[e]], 1);
}

// ---------------- CSR build (scan + atomic-free scatter) ----------------

#define SCAN_B 512
__global__ __launch_bounds__(SCAN_B) void scan1_kernel(const int* __restrict__ counts,
                                                       int* __restrict__ offs,
                                                       int* __restrict__ bsum) {
    __shared__ int s[SCAN_B];
    const int tid = threadIdx.x;
    const int idx = blockIdx.x * SCAN_B + tid;
    const int v = (idx < NN) ? counts[idx] : 0;
    s[tid] = v;
    __syncthreads();
    for (int off = 1; off < SCAN_B; off <<= 1) {
        const int t = (tid >= off) ? s[tid - off] : 0;
        __syncthreads();
        s[tid] += t;
        __syncthreads();
    }
    if (idx < NN) offs[idx] = s[tid] - v;
    if (tid == SCAN_B - 1) bsum[blockIdx.x] = s[tid];
}

__global__ __launch_bounds__(SCAN_B) void scan2_kernel(int* __restrict__ bsum, int nblk,
                                                       int* __restrict__ offs) {
    __shared__ int s[SCAN_B];
    const int tid = threadIdx.x;
    const int v = (tid < nblk) ? bsum[tid] : 0;
    s[tid] = v;
    __syncthreads();
    for (int off = 1; off < SCAN_B; off <<= 1) {
        const int t = (tid >= off) ? s[tid - off] : 0;
        __syncthreads();
        s[tid] += t;
        __syncthreads();
    }
    if (tid < nblk) bsum[tid] = s[tid] - v;       // exclusive
    if (tid == nblk - 1) offs[NN] = s[tid];       // == NE
}

__global__ __launch_bounds__(SCAN_B) void scan3_kernel(int* __restrict__ offs,
                                                       const int* __restrict__ bsum) {
    const int idx = blockIdx.x * SCAN_B + threadIdx.x;
    if (idx < NN) offs[idx] += bsum[blockIdx.x];
}

__global__ void scatter_kernel(const int* __restrict__ ei, const int* __restrict__ offs,
                               const int* __restrict__ rank, int4* __restrict__ quads) {
    const int e = blockIdx.x * 256 + threadIdx.x;
    if (e >= NE) return;
    const int r = ei[e];
    const int c = ei[NE + e];
    const int pos = offs[r] + rank[e];           // no atomic
    quads[pos] = make_int4(e, r, c, 0);
}

// ---------------- MFMA edge kernel ----------------
// 512 thr = 8 waves, 128 CSR-ordered edges/block, 16 edges/wave.
// NO weight staging: all B-frags via L1/L2 (weights ~36KB, L2-resident).
// LDS 46KB -> 3 blocks/CU (24 waves). One barrier.

#define FSTR 168   // bf16 row stride (160 + 8 pad; 336B)

__global__ __launch_bounds__(512) void edge_mfma_kernel(
    const unsigned short* __restrict__ hbf, const float* __restrict__ x,
    const float* __restrict__ ea,
    const unsigned short* __restrict__ W1p, const unsigned short* __restrict__ W2p,
    const unsigned short* __restrict__ Wc1p,
    const float* __restrict__ B1, const float* __restrict__ B2,
    const float* __restrict__ Bc1, const float* __restrict__ Wc2,
    const int4* __restrict__ quads,
    unsigned short* __restrict__ m_scr, float* __restrict__ trans)
{
    __shared__ float sBias[256];       // B1 | B2 | Bc1 | Wc2
    __shared__ short sA[128 * FSTR];   // 43008 B
    __shared__ float sGeom[128 * 4];   // 2048 B

    const int tid = threadIdx.x;
    const int p0 = blockIdx.x * 128;

    if (tid < 64) {
        sBias[tid]       = B1[tid];
        sBias[64 + tid]  = B2[tid];
        sBias[128 + tid] = Bc1[tid];
        sBias[192 + tid] = Wc2[tid];
    }

    // stage features: 4 threads per edge slot
    {
        const int s = tid >> 2, q = tid & 3;
        const int4 pr = quads[p0 + s];
        const int eid = pr.x, row = pr.y, col = pr.z;

        const uint4* hr = (const uint4*)(hbf + (size_t)row * 64);
        *(uint4*)&sA[s * FSTR + q * 16]     = hr[q * 2];
        *(uint4*)&sA[s * FSTR + q * 16 + 8] = hr[q * 2 + 1];
        const uint4* hc = (const uint4*)(hbf + (size_t)col * 64);
        *(uint4*)&sA[s * FSTR + 64 + q * 16]     = hc[q * 2];
        *(uint4*)&sA[s * FSTR + 64 + q * 16 + 8] = hc[q * 2 + 1];

        const float4 e4 = ((const float4*)(ea + (size_t)eid * 16))[q];
        sA[s * FSTR + 129 + q * 4 + 0] = f2bf_hw(e4.x);
        sA[s * FSTR + 129 + q * 4 + 1] = f2bf_hw(e4.y);
        sA[s * FSTR + 129 + q * 4 + 2] = f2bf_hw(e4.z);
        sA[s * FSTR + 129 + q * 4 + 3] = f2bf_hw(e4.w);

        if (q == 0) {
            const float dx = x[row * 3 + 0] - x[col * 3 + 0];
            const float dy = x[row * 3 + 1] - x[col * 3 + 1];
            const float dz = x[row * 3 + 2] - x[col * 3 + 2];
            const float dist_sq = dx * dx + dy * dy + dz * dz;
            sGeom[s * 4 + 0] = dx;
            sGeom[s * 4 + 1] = dy;
            sGeom[s * 4 + 2] = dz;
            sGeom[s * 4 + 3] = sqrtf(dist_sq + EPS);
            sA[s * FSTR + 128] = f2bf_hw(log1pf(dist_sq));
        } else if (q == 1) {
            #pragma unroll
            for (int k = 145; k < 160; ++k) sA[s * FSTR + k] = 0;
        }
    }
    __syncthreads();

    const int w = tid >> 6, l = tid & 63;
    const int lr = l & 15;
    const int ks = l >> 4;
    short* myA = &sA[(w * 16 + lr) * FSTR];

    // ---- msg layer 1: [16,160] @ [160,64], B via L1/L2 ----
    f32x4 acc[4];
    #pragma unroll
    for (int nt = 0; nt < 4; ++nt) {
        const float b = sBias[nt * 16 + lr];
        acc[nt] = (f32x4){b, b, b, b};
    }
    #pragma unroll
    for (int c = 0; c < 5; ++c) {
        const bf16x8 af = *(const bf16x8*)&myA[c * 32 + ks * 8];
        #pragma unroll
        for (int nt = 0; nt < 4; ++nt) {
            const bf16x8 bf = *(const bf16x8*)&W1p[((c * 4 + nt) * 64 + l) * 8];
            acc[nt] = __builtin_amdgcn_mfma_f32_16x16x32_bf16(af, bf, acc[nt], 0, 0, 0);
        }
    }
    {
        short* pw = &sA[(w * 16 + ks * 4) * FSTR + lr];
        #pragma unroll
        for (int nt = 0; nt < 4; ++nt)
            #pragma unroll
            for (int i = 0; i < 4; ++i)
                pw[i * FSTR + nt * 16] = f2bf_hw(silu_f(acc[nt][i]));
    }

    // ---- msg layer 2: [16,64] @ [64,64], B via L1 ----
    f32x4 acc2[4];
    #pragma unroll
    for (int nt = 0; nt < 4; ++nt) {
        const float b = sBias[64 + nt * 16 + lr];
        acc2[nt] = (f32x4){b, b, b, b};
    }
    #pragma unroll
    for (int c = 0; c < 2; ++c) {
        const bf16x8 af = *(const bf16x8*)&myA[c * 32 + ks * 8];
        #pragma unroll
        for (int nt = 0; nt < 4; ++nt) {
            const bf16x8 bf = *(const bf16x8*)&W2p[((c * 4 + nt) * 64 + l) * 8];
            acc2[nt] = __builtin_amdgcn_mfma_f32_16x16x32_bf16(af, bf, acc2[nt], 0, 0, 0);
        }
    }
    {
        short* pw = &sA[(w * 16 + ks * 4) * FSTR + lr];
        #pragma unroll
        for (int nt = 0; nt < 4; ++nt)
            #pragma unroll
            for (int i = 0; i < 4; ++i)
                pw[i * FSTR + nt * 16] = f2bf_hw(silu_f(acc2[nt][i]));
    }

    // stream m tile to global (coalesced re-read of own wave's rows)
    {
        const short* src = &sA[(w * 16 + (l >> 2)) * FSTR + (l & 3) * 16];
        uint4* dst = (uint4*)(m_scr + ((size_t)(p0 + w * 16 + (l >> 2))) * 64 + (l & 3) * 16);
        dst[0] = *(const uint4*)src;
        dst[1] = *(const uint4*)(src + 8);
    }

    // ---- coord layer 1: [16,64] @ [64,64], B via L1 ----
    f32x4 acc3[4];
    #pragma unroll
    for (int nt = 0; nt < 4; ++nt) {
        const float b = sBias[128 + nt * 16 + lr];
        acc3[nt] = (f32x4){b, b, b, b};
    }
    #pragma unroll
    for (int c = 0; c < 2; ++c) {
        const bf16x8 af = *(const bf16x8*)&myA[c * 32 + ks * 8];
        #pragma unroll
        for (int nt = 0; nt < 4; ++nt) {
            const bf16x8 bf = *(const bf16x8*)&Wc1p[((c * 4 + nt) * 64 + l) * 8];
            acc3[nt] = __builtin_amdgcn_mfma_f32_16x16x32_bf16(af, bf, acc3[nt], 0, 0, 0);
        }
    }
    float part[4] = {0.0f, 0.0f, 0.0f, 0.0f};
    #pragma unroll
    for (int nt = 0; nt < 4; ++nt) {
        const float wv = sBias[192 + nt * 16 + lr];
        #pragma unroll
        for (int i = 0; i < 4; ++i) part[i] += silu_f(acc3[nt][i]) * wv;
    }
    #pragma unroll
    for (int m = 1; m <= 8; m <<= 1) {
        #pragma unroll
        for (int i = 0; i < 4; ++i) part[i] += __shfl_xor(part[i], m, 64);
    }
    if (lr == 0) {
        #pragma unroll
        for (int i = 0; i < 4; ++i) {
            const int slot = w * 16 + ks * 4 + i;
            const float dist = sGeom[slot * 4 + 3];
            const float g2 = fminf(fmaxf(2.0f * part[i], -30.0f), 30.0f);
            const float t = __expf(g2);
            const float th = (t - 1.0f) * rcp_fast(t + 1.0f);
            const float sc = th * 0.1f * rcp_fast(dist + EPS);
            const size_t o = (size_t)(p0 + slot) * 3;
            trans[o + 0] = sGeom[slot * 4 + 0] * sc;
            trans[o + 1] = sGeom[slot * 4 + 1] * sc;
            trans[o + 2] = sGeom[slot * 4 + 2] * sc;
        }
    }
}

// ---------------- gathers (streaming, CSR-position-ordered scratch) ----------------

__global__ __launch_bounds__(256) void gather_m_kernel(
    const unsigned short* __restrict__ m_scr, const int* __restrict__ offs,
    unsigned short* __restrict__ m_ibf)
{
    const int wid = blockIdx.x * 4 + (threadIdx.x >> 6);
    const int lane = threadIdx.x & 63;
    const int o0 = offs[wid], o1 = offs[wid + 1];
    float acc = 0.0f;
    int o = o0;
    for (; o + 1 < o1; o += 2)
        acc += bf2f(m_scr[(size_t)o * 64 + lane]) + bf2f(m_scr[(size_t)(o + 1) * 64 + lane]);
    if (o < o1) acc += bf2f(m_scr[(size_t)o * 64 + lane]);
    m_ibf[(size_t)wid * 64 + lane] =
        (unsigned short)f2bf_hw(acc * rcp_fast((float)(o1 - o0) + EPS));
}

__global__ void gather_x_kernel(const float* __restrict__ x,
                                const float* __restrict__ trans,
                                const int* __restrict__ offs,
                                float* __restrict__ x_out)
{
    const int i = blockIdx.x * 256 + threadIdx.x;
    if (i >= NN) return;
    const int o0 = offs[i], o1 = offs[i + 1];
    float sx = 0.0f, sy = 0.0f, sz = 0.0f;
    for (int o = o0; o < o1; ++o) {
        sx += trans[(size_t)o * 3 + 0];
        sy += trans[(size_t)o * 3 + 1];
        sz += trans[(size_t)o * 3 + 2];
    }
    const float inv = rcp_fast((float)(o1 - o0) + EPS);
    x_out[(size_t)i * 3 + 0] = x[(size_t)i * 3 + 0] + sx * inv;
    x_out[(size_t)i * 3 + 1] = x[(size_t)i * 3 + 1] + sy * inv;
    x_out[(size_t)i * 3 + 2] = x[(size_t)i * 3 + 2] + sz * inv;
}

// ---------------- MFMA node kernel: MLP + residual + LayerNorm ----------------

#define NSTR 136   // 128 + 8 pad

__global__ __launch_bounds__(256) void node_mfma_kernel(
    const unsigned short* __restrict__ hbf, const unsigned short* __restrict__ m_ibf,
    const unsigned short* __restrict__ Wn1p, const unsigned short* __restrict__ Wn2p,
    const float* __restrict__ Bn1, const float* __restrict__ Bn2,
    const float* __restrict__ ln_g, const float* __restrict__ ln_b,
    float* __restrict__ h_out)
{
    __shared__ short sA[64 * NSTR];   // 17408 B
    __shared__ float sBias[256];      // Bn1 | Bn2 | g | b

    const int tid = threadIdx.x;
    const int n0 = blockIdx.x * 64;

    if (tid < 64) {
        sBias[tid]       = Bn1[tid];
        sBias[64 + tid]  = Bn2[tid];
        sBias[128 + tid] = ln_g[tid];
        sBias[192 + tid] = ln_b[tid];
    }
    {
        const int s = tid >> 2, q = tid & 3;
        const int node = n0 + s;
        const int n = (node < NN) ? node : (NN - 1);
        const uint4* hr = (const uint4*)(hbf + (size_t)n * 64);
        *(uint4*)&sA[s * NSTR + q * 16]     = hr[q * 2];
        *(uint4*)&sA[s * NSTR + q * 16 + 8] = hr[q * 2 + 1];
        const uint4* mr = (const uint4*)(m_ibf + (size_t)n * 64);
        *(uint4*)&sA[s * NSTR + 64 + q * 16]     = mr[q * 2];
        *(uint4*)&sA[s * NSTR + 64 + q * 16 + 8] = mr[q * 2 + 1];
    }
    __syncthreads();

    const int w = tid >> 6, l = tid & 63;
    const int lr = l & 15;
    const int ks = l >> 4;
    const short* myA = &sA[(w * 16 + lr) * NSTR];

    // ---- node layer 1: [16,128] @ [128,64] ----
    f32x4 acc[4];
    #pragma unroll
    for (int nt = 0; nt < 4; ++nt) {
        const float b = sBias[nt * 16 + lr];
        acc[nt] = (f32x4){b, b, b, b};
    }
    #pragma unroll
    for (int c = 0; c < 4; ++c) {
        const bf16x8 af = *(const bf16x8*)&myA[c * 32 + ks * 8];
        #pragma unroll
        for (int nt = 0; nt < 4; ++nt) {
            const bf16x8 bf = *(const bf16x8*)&Wn1p[((c * 4 + nt) * 64 + l) * 8];
            acc[nt] = __builtin_amdgcn_mfma_f32_16x16x32_bf16(af, bf, acc[nt], 0, 0, 0);
        }
    }
    {
        short* pw = &sA[(w * 16 + ks * 4) * NSTR + 64 + lr];
        #pragma unroll
        for (int nt = 0; nt < 4; ++nt)
            #pragma unroll
            for (int i = 0; i < 4; ++i)
                pw[i * NSTR + nt * 16] = f2bf_hw(silu_f(acc[nt][i]));
    }

    // ---- node layer 2: [16,64] @ [64,64] ----
    f32x4 acc2[4];
    #pragma unroll
    for (int nt = 0; nt < 4; ++nt) {
        const float b = sBias[64 + nt * 16 + lr];
        acc2[nt] = (f32x4){b, b, b, b};
    }
    #pragma unroll
    for (int c = 0; c < 2; ++c) {
        const bf16x8 af = *(const bf16x8*)&myA[64 + c * 32 + ks * 8];
        #pragma unroll
        for (int nt = 0; nt < 4; ++nt) {
            const bf16x8 bf = *(const bf16x8*)&Wn2p[((c * 4 + nt) * 64 + l) * 8];
            acc2[nt] = __builtin_amdgcn_mfma_f32_16x16x32_bf16(af, bf, acc2[nt], 0, 0, 0);
        }
    }

    float a2[4][4];
    #pragma unroll
    for (int nt = 0; nt < 4; ++nt)
        #pragma unroll
        for (int i = 0; i < 4; ++i)
            a2[nt][i] = acc2[nt][i] +
                bf2f((unsigned short)sA[(w * 16 + ks * 4 + i) * NSTR + nt * 16 + lr]);

    float su[4];
    #pragma unroll
    for (int i = 0; i < 4; ++i)
        su[i] = a2[0][i] + a2[1][i] + a2[2][i] + a2[3][i];
    #pragma unroll
    for (int m = 1; m <= 8; m <<= 1)
        #pragma unroll
        for (int i = 0; i < 4; ++i) su[i] += __shfl_xor(su[i], m, 64);
    float mu[4];
    #pragma unroll
    for (int i = 0; i < 4; ++i) mu[i] = su[i] * (1.0f / 64.0f);

    float sv[4];
    #pragma unroll
    for (int i = 0; i < 4; ++i) {
        float s = 0.0f;
        #pragma unroll
        for (int nt = 0; nt < 4; ++nt) {
            const float d = a2[nt][i] - mu[i];
            s += d * d;
        }
        sv[i] = s;
    }
    #pragma unroll
    for (int m = 1; m <= 8; m <<= 1)
        #pragma unroll
        for (int i = 0; i < 4; ++i) sv[i] += __shfl_xor(sv[i], m, 64);

    #pragma unroll
    for (int i = 0; i < 4; ++i) {
        const float rstd = rsqrtf(sv[i] * (1.0f / 64.0f) + LN_EPS);
        const int node = n0 + w * 16 + ks * 4 + i;
        if (node < NN) {
            #pragma unroll
            for (int nt = 0; nt < 4; ++nt) {
                const int colj = nt * 16 + lr;
                h_out[(size_t)node * 64 + colj] =
                    (a2[nt][i] - mu[i]) * rstd * sBias[128 + colj] + sBias[192 + colj];
            }
        }
    }
}

// ---------------- fallback (atomic path, minimal ws) ----------------

__global__ __launch_bounds__(64) void edge_atomic_kernel(
    const float* __restrict__ h, const float* __restrict__ x,
    const int* __restrict__ ei, const float* __restrict__ ea,
    const float* __restrict__ W1, const float* __restrict__ B1,
    const float* __restrict__ W2, const float* __restrict__ B2,
    const float* __restrict__ Wc1, const float* __restrict__ Bc1,
    const float* __restrict__ Wc2,
    float* __restrict__ m_acc, float* __restrict__ xagg)
{
    __shared__ float lds[64 * 64];
    const int lane = threadIdx.x;
    const int e = blockIdx.x * 64 + lane;

    const int row = ei[e];
    const int col = ei[NE + e];

    const float dx = x[row * 3 + 0] - x[col * 3 + 0];
    const float dy = x[row * 3 + 1] - x[col * 3 + 1];
    const float dz = x[row * 3 + 2] - x[col * 3 + 2];
    const float dist_sq = dx * dx + dy * dy + dz * dz;
    const float dist = sqrtf(dist_sq + EPS);
    const float logd = log1pf(dist_sq);

    float a1[64];
    #pragma unroll
    for (int j = 0; j < 64; ++j) a1[j] = B1[j];
    const float4* hr4 = (const float4*)(h + (size_t)row * 64);
    for (int k4 = 0; k4 < 16; ++k4) {
        const float4 v4 = hr4[k4];
        #pragma unroll
        for (int c = 0; c < 4; ++c) {
            const float v = (c == 0) ? v4.x : (c == 1) ? v4.y : (c == 2) ? v4.z : v4.w;
            const float* w = W1 + (k4 * 4 + c) * 64;
            #pragma unroll
            for (int j = 0; j < 64; ++j) a1[j] = fmaf(v, w[j], a1[j]);
        }
    }
    const float4* hc4 = (const float4*)(h + (size_t)col * 64);
    for (int k4 = 0; k4 < 16; ++k4) {
        const float4 v4 = hc4[k4];
        #pragma unroll
        for (int c = 0; c < 4; ++c) {
            const float v = (c == 0) ? v4.x : (c == 1) ? v4.y : (c == 2) ? v4.z : v4.w;
            const float* w = W1 + (64 + k4 * 4 + c) * 64;
            #pragma unroll
            for (int j = 0; j < 64; ++j) a1[j] = fmaf(v, w[j], a1[j]);
        }
    }
    {
        const float* w = W1 + 128 * 64;
        #pragma unroll
        for (int j = 0; j < 64; ++j) a1[j] = fmaf(logd, w[j], a1[j]);
    }
    const float4* ea4 = (const float4*)(ea + (size_t)e * 16);
    for (int k4 = 0; k4 < 4; ++k4) {
        const float4 v4 = ea4[k4];
        #pragma unroll
        for (int c = 0; c < 4; ++c) {
            const float v = (c == 0) ? v4.x : (c == 1) ? v4.y : (c == 2) ? v4.z : v4.w;
            const float* w = W1 + (129 + k4 * 4 + c) * 64;
            #pragma unroll
            for (int j = 0; j < 64; ++j) a1[j] = fmaf(v, w[j], a1[j]);
        }
    }

    #pragma unroll
    for (int j = 0; j < 64; ++j) lds[j * 64 + lane] = silu_f(a1[j]);

    float a2[64];
    #pragma unroll
    for (int j = 0; j < 64; ++j) a2[j] = B2[j];
    for (int k = 0; k < 64; ++k) {
        const float v = lds[k * 64 + lane];
        const float* w = W2 + k * 64;
        #pragma unroll
        for (int j = 0; j < 64; ++j) a2[j] = fmaf(v, w[j], a2[j]);
    }

    float* mrow = m_acc + (size_t)row * 64;
    #pragma unroll
    for (int j = 0; j < 64; ++j) {
        const float mj = silu_f(a2[j]);
        lds[j * 64 + lane] = mj;
        atomicAdd(mrow + j, mj);
    }

    float t[64];
    #pragma unroll
    for (int j = 0; j < 64; ++j) t[j] = Bc1[j];
    for (int k = 0; k < 64; ++k) {
        const float v = lds[k * 64 + lane];
        const float* w = Wc1 + k * 64;
        #pragma unroll
        for (int j = 0; j < 64; ++j) t[j] = fmaf(v, w[j], t[j]);
    }
    float g = 0.0f;
    #pragma unroll
    for (int j = 0; j < 64; ++j) g += silu_f(t[j]) * Wc2[j];

    const float s = tanhf(g) * 0.1f / (dist + EPS);
    atomicAdd(&xagg[row * 4 + 0], dx * s);
    atomicAdd(&xagg[row * 4 + 1], dy * s);
    atomicAdd(&xagg[row * 4 + 2], dz * s);
    atomicAdd(&xagg[row * 4 + 3], 1.0f);
}

__global__ __launch_bounds__(64) void node_csr_kernel(
    const float* __restrict__ h,
    const float* __restrict__ m_i,
    const float* __restrict__ Wn1, const float* __restrict__ Bn1,
    const float* __restrict__ Wn2, const float* __restrict__ Bn2,
    const float* __restrict__ ln_g, const float* __restrict__ ln_b,
    float* __restrict__ h_out)
{
    __shared__ float lds[64 * 64];
    const int lane = threadIdx.x;
    const int node = blockIdx.x * 64 + lane;
    const bool act = node < NN;
    const int n = act ? node : 0;

    float a1[64];
    #pragma unroll
    for (int j = 0; j < 64; ++j) a1[j] = Bn1[j];

    const float* hr = h + (size_t)n * 64;
    const float4* hr4 = (const float4*)hr;
    for (int k4 = 0; k4 < 16; ++k4) {
        const float4 v4 = hr4[k4];
        #pragma unroll
        for (int c = 0; c < 4; ++c) {
            const float v = (c == 0) ? v4.x : (c == 1) ? v4.y : (c == 2) ? v4.z : v4.w;
            const float* w = Wn1 + (k4 * 4 + c) * 64;
            #pragma unroll
            for (int j = 0; j < 64; ++j) a1[j] = fmaf(v, w[j], a1[j]);
        }
    }
    const float4* mr4 = (const float4*)(m_i + (size_t)n * 64);
    for (int k4 = 0; k4 < 16; ++k4) {
        const float4 v4 = mr4[k4];
        #pragma unroll
        for (int c = 0; c < 4; ++c) {
            const float v = (c == 0) ? v4.x : (c == 1) ? v4.y : (c == 2) ? v4.z : v4.w;
            const float* w = Wn1 + (64 + k4 * 4 + c) * 64;
            #pragma unroll
            for (int j = 0; j < 64; ++j) a1[j] = fmaf(v, w[j], a1[j]);
        }
    }

    #pragma unroll
    for (int j = 0; j < 64; ++j) lds[j * 64 + lane] = silu_f(a1[j]);

    float a2[64];
    #pragma unroll
    for (int j = 0; j < 64; ++j) a2[j] = Bn2[j];
    for (int k = 0; k < 64; ++k) {
        const float v = lds[k * 64 + lane];
        const float* w = Wn2 + k * 64;
        #pragma unroll
        for (int j = 0; j < 64; ++j) a2[j] = fmaf(v, w[j], a2[j]);
    }

    float mu = 0.0f;
    #pragma unroll
    for (int j = 0; j < 64; ++j) { a2[j] += hr[j]; mu += a2[j]; }
    mu *= (1.0f / 64.0f);
    float var = 0.0f;
    #pragma unroll
    for (int j = 0; j < 64; ++j) { const float d = a2[j] - mu; var += d * d; }
    var *= (1.0f / 64.0f);
    const float rstd = rsqrtf(var + LN_EPS);

    if (act) {
        #pragma unroll
        for (int j = 0; j < 64; ++j)
            h_out[(size_t)n * 64 + j] = (a2[j] - mu) * rstd * ln_g[j] + ln_b[j];
    }
}

__global__ void x_atomic_kernel(const float* __restrict__ x, const float* __restrict__ xagg,
                                float* __restrict__ x_out)
{
    const int i = blockIdx.x * 256 + threadIdx.x;
    if (i >= NN) return;
    const float inv_cnt = 1.0f / (xagg[i * 4 + 3] + EPS);
    #pragma unroll
    for (int c = 0; c < 3; ++c)
        x_out[(size_t)i * 3 + c] = x[(size_t)i * 3 + c] + xagg[i * 4 + c] * inv_cnt;
}

__global__ void div_m_kernel(float* __restrict__ m_acc, const float* __restrict__ xagg) {
    const int i = blockIdx.x * 256 + threadIdx.x;
    if (i >= NN * 64) return;
    m_acc[i] /= (xagg[(i >> 6) * 4 + 3] + EPS);
}

// ---------------- launch ----------------

extern "C" void kernel_launch(void* const* d_in, const int* in_sizes, int n_in,
                              void* d_out, int out_size, void* d_ws, size_t ws_size,
                              hipStream_t stream)
{
    const float* h   = (const float*)d_in[0];
    const float* x   = (const float*)d_in[1];
    const int*   ei  = (const int*)d_in[2];
    const float* ea  = (const float*)d_in[3];
    const float* W1  = (const float*)d_in[4];
    const float* B1  = (const float*)d_in[5];
    const float* W2  = (const float*)d_in[6];
    const float* B2  = (const float*)d_in[7];
    const float* Wn1 = (const float*)d_in[8];
    const float* Bn1 = (const float*)d_in[9];
    const float* Wn2 = (const float*)d_in[10];
    const float* Bn2 = (const float*)d_in[11];
    const float* Wc1 = (const float*)d_in[12];
    const float* Bc1 = (const float*)d_in[13];
    const float* Wc2 = (const float*)d_in[14];
    const float* lng = (const float*)d_in[15];
    const float* lnb = (const float*)d_in[16];

    float* out   = (float*)d_out;
    float* x_out = out + (size_t)NN * 64;

    size_t off = 0;
    auto take = [&](size_t bytes) { size_t p = off; off = (off + bytes + 255) & ~(size_t)255; return p; };
    char* ws = (char*)d_ws;
    const size_t o_mscr   = take((size_t)NE * 64 * 2);     // bf16 m_ij (CSR order)
    const size_t o_trans  = take((size_t)NE * 3 * 4);      // f32 trans (CSR order)
    const size_t o_quads  = take((size_t)NE * 16);         // int4 {eid,row,col,-}
    const size_t o_counts = take((size_t)NN * 4);
    const size_t o_rank   = take((size_t)NE * 4);          // within-node rank per edge
    const size_t o_offs   = take((size_t)(NN + 1) * 4);
    const size_t o_bsum   = take((size_t)1024 * 4);
    const size_t o_hbf    = take((size_t)NN * 64 * 2);     // bf16 h
    const size_t o_mibf   = take((size_t)NN * 64 * 2);     // bf16 m_i
    const size_t o_w1p    = take((size_t)10240 * 2);
    const size_t o_w2p    = take((size_t)4096 * 2);
    const size_t o_wc1p   = take((size_t)4096 * 2);
    const size_t o_wn1p   = take((size_t)8192 * 2);
    const size_t o_wn2p   = take((size_t)4096 * 2);
    const size_t need = off;

    if (ws_size >= need) {
        unsigned short* m_scr = (unsigned short*)(ws + o_mscr);
        float* trans  = (float*)(ws + o_trans);
        int4*  quads  = (int4*)(ws + o_quads);
        int*   counts = (int*)(ws + o_counts);
        int*   rank   = (int*)(ws + o_rank);
        int*   offs   = (int*)(ws + o_offs);
        int*   bsum   = (int*)(ws + o_bsum);
        unsigned short* hbf   = (unsigned short*)(ws + o_hbf);
        unsigned short* m_ibf = (unsigned short*)(ws + o_mibf);
        unsigned short* W1p   = (unsigned short*)(ws + o_w1p);
        unsigned short* W2p   = (unsigned short*)(ws + o_w2p);
        unsigned short* Wc1p  = (unsigned short*)(ws + o_wc1p);
        unsigned short* Wn1p  = (unsigned short*)(ws + o_wn1p);
        unsigned short* Wn2p  = (unsigned short*)(ws + o_wn2p);

        hipMemsetAsync(counts, 0, (size_t)NN * 4, stream);

        prep_count_kernel<<<HB_BLOCKS + PW_BLOCKS + CNT_BLOCKS, 256, 0, stream>>>(
            h, W1, W2, Wc1, Wn1, Wn2, ei,
            hbf, W1p, W2p, Wc1p, Wn1p, Wn2p, counts, rank);

        const int nblk = (NN + SCAN_B - 1) / SCAN_B;
        scan1_kernel<<<nblk, SCAN_B, 0, stream>>>(counts, offs, bsum);
        scan2_kernel<<<1, SCAN_B, 0, stream>>>(bsum, nblk, offs);
        scan3_kernel<<<nblk, SCAN_B, 0, stream>>>(offs, bsum);
        scatter_kernel<<<(NE + 255) / 256, 256, 0, stream>>>(ei, offs, rank, quads);

        edge_mfma_kernel<<<NE / 128, 512, 0, stream>>>(hbf, x, ea, W1p, W2p, Wc1p,
                                                       B1, B2, Bc1, Wc2, quads,
                                                       m_scr, trans);
        gather_m_kernel<<<NN / 4, 256, 0, stream>>>(m_scr, offs, m_ibf);
        gather_x_kernel<<<(NN + 255) / 256, 256, 0, stream>>>(x, trans, offs, x_out);
        node_mfma_kernel<<<(NN + 63) / 64, 256, 0, stream>>>(hbf, m_ibf, Wn1p, Wn2p,
                                                             Bn1, Bn2, lng, lnb, out);
    } else {
        float* m_acc = out;
        float* xagg  = (float*)d_ws;
        hipMemsetAsync(m_acc, 0, (size_t)NN * 64 * 4, stream);
        hipMemsetAsync(xagg, 0, (size_t)NN * 4 * 4, stream);
        edge_atomic_kernel<<<NE / 64, 64, 0, stream>>>(h, x, ei, ea, W1, B1, W2, B2,
                                                       Wc1, Bc1, Wc2, m_acc, xagg);
        div_m_kernel<<<(NN * 64 + 255) / 256, 256, 0, stream>>>(m_acc, xagg);
        node_csr_kernel<<<(NN + 63) / 64, 64, 0, stream>>>(h, m_acc, Wn1, Bn1, Wn2, Bn2,
                                                           lng, lnb, m_acc);
        x_atomic_kernel<<<(NN + 255) / 256, 256, 0, stream>>>(x, xagg, m_acc + (size_t)NN * 64);
    }
}

// Round 7
// 357.911 us; speedup vs baseline: 16.3467x; 1.2726x over previous
//
#include <hip/hip_runtime.h>
#include <hip/hip_bf16.h>
#include <math.h>

#define NN 100000
#define NE 1600000

constexpr float EPS = 1e-8f;
constexpr float LN_EPS = 1e-5f;

typedef short bf16x8 __attribute__((ext_vector_type(8)));
typedef float f32x4 __attribute__((ext_vector_type(4)));

__device__ __forceinline__ float rcp_fast(float v) {
    return __builtin_amdgcn_rcpf(v);
}
__device__ __forceinline__ float silu_f(float v) {
    return v * rcp_fast(1.0f + __expf(-v));
}
__device__ __forceinline__ short f2bf_hw(float v) {
    union { __hip_bfloat16 b; short s; } u;
    u.b = __float2bfloat16(v);
    return u.s;
}
__device__ __forceinline__ unsigned int pk2_hw(float lo, float hi) {
    union { __hip_bfloat162 b2; unsigned int u; } u;
    u.b2 = __float22bfloat162_rn(make_float2(lo, hi));
    return u.u;
}
__device__ __forceinline__ float bf2f(unsigned short s) {
    return __uint_as_float(((unsigned int)s) << 16);
}

// ---------------- fused prep: bf16 h + frag-packed weights + count+rank ------
// frag order: elem ((c*4+nt)*64 + l)*8 + j  ==  W[k = c*32+(l>>4)*8+j][n = nt*16+(l&15)]

#define HB_BLOCKS 6250      // NN*64/4/256
#define PW_BLOCKS 120
#define CNT_BLOCKS 6250     // NE/256

__global__ void prep_count_kernel(const float* __restrict__ h,
                            const float* __restrict__ W1, const float* __restrict__ W2,
                            const float* __restrict__ Wc1,
                            const float* __restrict__ Wn1, const float* __restrict__ Wn2,
                            const int* __restrict__ ei,
                            unsigned short* __restrict__ hbf,
                            unsigned short* __restrict__ W1p, unsigned short* __restrict__ W2p,
                            unsigned short* __restrict__ Wc1p,
                            unsigned short* __restrict__ Wn1p, unsigned short* __restrict__ Wn2p,
                            int* __restrict__ counts, int* __restrict__ rank)
{
    const int b = blockIdx.x;
    if (b < HB_BLOCKS) {
        const int i = b * 256 + threadIdx.x;     // 4 elems each
        const float4 v = ((const float4*)h)[i];
        uint2 u; u.x = pk2_hw(v.x, v.y); u.y = pk2_hw(v.z, v.w);
        ((uint2*)hbf)[i] = u;
        return;
    }
    if (b < HB_BLOCKS + PW_BLOCKS) {
        const int idx = (b - HB_BLOCKS) * 256 + threadIdx.x;
        if (idx < 10240) {                           // W1: K=160 (145 real)
            const int j = idx & 7, l = (idx >> 3) & 63, nt = (idx >> 9) & 3, c = idx >> 11;
            const int k = c * 32 + (l >> 4) * 8 + j, n = nt * 16 + (l & 15);
            W1p[idx] = (k < 145) ? (unsigned short)f2bf_hw(W1[k * 64 + n]) : (unsigned short)0;
        } else if (idx < 14336) {                    // W2: K=64
            const int t = idx - 10240;
            const int j = t & 7, l = (t >> 3) & 63, nt = (t >> 9) & 3, c = t >> 11;
            W2p[t] = (unsigned short)f2bf_hw(W2[(c * 32 + (l >> 4) * 8 + j) * 64 + nt * 16 + (l & 15)]);
        } else if (idx < 18432) {                    // Wc1: K=64
            const int t = idx - 14336;
            const int j = t & 7, l = (t >> 3) & 63, nt = (t >> 9) & 3, c = t >> 11;
            Wc1p[t] = (unsigned short)f2bf_hw(Wc1[(c * 32 + (l >> 4) * 8 + j) * 64 + nt * 16 + (l & 15)]);
        } else if (idx < 26624) {                    // Wn1: K=128
            const int t = idx - 18432;
            const int j = t & 7, l = (t >> 3) & 63, nt = (t >> 9) & 3, c = t >> 11;
            Wn1p[t] = (unsigned short)f2bf_hw(Wn1[(c * 32 + (l >> 4) * 8 + j) * 64 + nt * 16 + (l & 15)]);
        } else if (idx < 30720) {                    // Wn2: K=64
            const int t = idx - 26624;
            const int j = t & 7, l = (t >> 3) & 63, nt = (t >> 9) & 3, c = t >> 11;
            Wn2p[t] = (unsigned short)f2bf_hw(Wn2[(c * 32 + (l >> 4) * 8 + j) * 64 + nt * 16 + (l & 15)]);
        }
        return;
    }
    // count + rank in one atomic pass: the returned old value IS the rank
    const int e = (b - HB_BLOCKS - PW_BLOCKS) * 256 + threadIdx.x;
    if (e < NE) rank[e] = atomicAdd(&counts[ei[e]], 1);
}

// ---------------- CSR build (scan + atomic-free scatter) ----------------

#define SCAN_B 512
__global__ __launch_bounds__(SCAN_B) void scan1_kernel(const int* __restrict__ counts,
                                                       int* __restrict__ offs,
                                                       int* __restrict__ bsum) {
    __shared__ int s[SCAN_B];
    const int tid = threadIdx.x;
    const int idx = blockIdx.x * SCAN_B + tid;
    const int v = (idx < NN) ? counts[idx] : 0;
    s[tid] = v;
    __syncthreads();
    for (int off = 1; off < SCAN_B; off <<= 1) {
        const int t = (tid >= off) ? s[tid - off] : 0;
        __syncthreads();
        s[tid] += t;
        __syncthreads();
    }
    if (idx < NN) offs[idx] = s[tid] - v;
    if (tid == SCAN_B - 1) bsum[blockIdx.x] = s[tid];
}

__global__ __launch_bounds__(SCAN_B) void scan2_kernel(int* __restrict__ bsum, int nblk,
                                                       int* __restrict__ offs) {
    __shared__ int s[SCAN_B];
    const int tid = threadIdx.x;
    const int v = (tid < nblk) ? bsum[tid] : 0;
    s[tid] = v;
    __syncthreads();
    for (int off = 1; off < SCAN_B; off <<= 1) {
        const int t = (tid >= off) ? s[tid - off] : 0;
        __syncthreads();
        s[tid] += t;
        __syncthreads();
    }
    if (tid < nblk) bsum[tid] = s[tid] - v;       // exclusive
    if (tid == nblk - 1) offs[NN] = s[tid];       // == NE
}

__global__ __launch_bounds__(SCAN_B) void scan3_kernel(int* __restrict__ offs,
                                                       const int* __restrict__ bsum) {
    const int idx = blockIdx.x * SCAN_B + threadIdx.x;
    if (idx < NN) offs[idx] += bsum[blockIdx.x];
}

__global__ void scatter_kernel(const int* __restrict__ ei, const int* __restrict__ offs,
                               const int* __restrict__ rank, int4* __restrict__ quads) {
    const int e = blockIdx.x * 256 + threadIdx.x;
    if (e >= NE) return;
    const int r = ei[e];
    const int c = ei[NE + e];
    const int pos = offs[r] + rank[e];           // no atomic
    quads[pos] = make_int4(e, r, c, 0);
}

// ---------------- MFMA edge kernel with in-kernel segmented reductions -------
// 512 thr = 8 waves, 128 CSR-ordered edges/block, 16 edges/wave.
// m_i: each wave segment-reduces its OWN 16 rows (wave-uniform boundaries),
// coalesced f32 atomics into mf[node*64+lane]. trans: LDS + ~10 walker threads
// emit 3 atomics per segment into xagg. No m_scr / trans buffers.

#define FSTR 168   // bf16 row stride (160 + 8 pad; 336B)

__global__ __launch_bounds__(512) void edge_mfma_kernel(
    const unsigned short* __restrict__ hbf, const float* __restrict__ x,
    const float* __restrict__ ea,
    const unsigned short* __restrict__ W1p, const unsigned short* __restrict__ W2p,
    const unsigned short* __restrict__ Wc1p,
    const float* __restrict__ B1, const float* __restrict__ B2,
    const float* __restrict__ Bc1, const float* __restrict__ Wc2,
    const int4* __restrict__ quads,
    float* __restrict__ mf, float* __restrict__ xagg)
{
    __shared__ float sBias[256];        // B1 | B2 | Bc1 | Wc2
    __shared__ short sA[128 * FSTR];    // 43008 B
    __shared__ float sGeom[128 * 4];    // dx,dy,dz,dist
    __shared__ int   sRow[128];         // node id per slot
    __shared__ float sTrans[128][3];    // per-edge trans (block-local)

    const int tid = threadIdx.x;
    const int p0 = blockIdx.x * 128;

    if (tid < 64) {
        sBias[tid]       = B1[tid];
        sBias[64 + tid]  = B2[tid];
        sBias[128 + tid] = Bc1[tid];
        sBias[192 + tid] = Wc2[tid];
    }

    // stage features: 4 threads per edge slot
    {
        const int s = tid >> 2, q = tid & 3;
        const int4 pr = quads[p0 + s];
        const int eid = pr.x, row = pr.y, col = pr.z;

        const uint4* hr = (const uint4*)(hbf + (size_t)row * 64);
        *(uint4*)&sA[s * FSTR + q * 16]     = hr[q * 2];
        *(uint4*)&sA[s * FSTR + q * 16 + 8] = hr[q * 2 + 1];
        const uint4* hc = (const uint4*)(hbf + (size_t)col * 64);
        *(uint4*)&sA[s * FSTR + 64 + q * 16]     = hc[q * 2];
        *(uint4*)&sA[s * FSTR + 64 + q * 16 + 8] = hc[q * 2 + 1];

        const float4 e4 = ((const float4*)(ea + (size_t)eid * 16))[q];
        sA[s * FSTR + 129 + q * 4 + 0] = f2bf_hw(e4.x);
        sA[s * FSTR + 129 + q * 4 + 1] = f2bf_hw(e4.y);
        sA[s * FSTR + 129 + q * 4 + 2] = f2bf_hw(e4.z);
        sA[s * FSTR + 129 + q * 4 + 3] = f2bf_hw(e4.w);

        if (q == 0) {
            const float dx = x[row * 3 + 0] - x[col * 3 + 0];
            const float dy = x[row * 3 + 1] - x[col * 3 + 1];
            const float dz = x[row * 3 + 2] - x[col * 3 + 2];
            const float dist_sq = dx * dx + dy * dy + dz * dz;
            sGeom[s * 4 + 0] = dx;
            sGeom[s * 4 + 1] = dy;
            sGeom[s * 4 + 2] = dz;
            sGeom[s * 4 + 3] = sqrtf(dist_sq + EPS);
            sA[s * FSTR + 128] = f2bf_hw(log1pf(dist_sq));
        } else if (q == 1) {
            #pragma unroll
            for (int k = 145; k < 160; ++k) sA[s * FSTR + k] = 0;
        } else if (q == 2) {
            sRow[s] = row;
        }
    }
    __syncthreads();

    const int w = tid >> 6, l = tid & 63;
    const int lr = l & 15;
    const int ks = l >> 4;
    short* myA = &sA[(w * 16 + lr) * FSTR];

    // ---- msg layer 1: [16,160] @ [160,64], B via L1/L2 ----
    f32x4 acc[4];
    #pragma unroll
    for (int nt = 0; nt < 4; ++nt) {
        const float b = sBias[nt * 16 + lr];
        acc[nt] = (f32x4){b, b, b, b};
    }
    #pragma unroll
    for (int c = 0; c < 5; ++c) {
        const bf16x8 af = *(const bf16x8*)&myA[c * 32 + ks * 8];
        #pragma unroll
        for (int nt = 0; nt < 4; ++nt) {
            const bf16x8 bf = *(const bf16x8*)&W1p[((c * 4 + nt) * 64 + l) * 8];
            acc[nt] = __builtin_amdgcn_mfma_f32_16x16x32_bf16(af, bf, acc[nt], 0, 0, 0);
        }
    }
    {
        short* pw = &sA[(w * 16 + ks * 4) * FSTR + lr];
        #pragma unroll
        for (int nt = 0; nt < 4; ++nt)
            #pragma unroll
            for (int i = 0; i < 4; ++i)
                pw[i * FSTR + nt * 16] = f2bf_hw(silu_f(acc[nt][i]));
    }

    // ---- msg layer 2: [16,64] @ [64,64], B via L1 ----
    f32x4 acc2[4];
    #pragma unroll
    for (int nt = 0; nt < 4; ++nt) {
        const float b = sBias[64 + nt * 16 + lr];
        acc2[nt] = (f32x4){b, b, b, b};
    }
    #pragma unroll
    for (int c = 0; c < 2; ++c) {
        const bf16x8 af = *(const bf16x8*)&myA[c * 32 + ks * 8];
        #pragma unroll
        for (int nt = 0; nt < 4; ++nt) {
            const bf16x8 bf = *(const bf16x8*)&W2p[((c * 4 + nt) * 64 + l) * 8];
            acc2[nt] = __builtin_amdgcn_mfma_f32_16x16x32_bf16(af, bf, acc2[nt], 0, 0, 0);
        }
    }
    {
        short* pw = &sA[(w * 16 + ks * 4) * FSTR + lr];
        #pragma unroll
        for (int nt = 0; nt < 4; ++nt)
            #pragma unroll
            for (int i = 0; i < 4; ++i)
                pw[i * FSTR + nt * 16] = f2bf_hw(silu_f(acc2[nt][i]));
    }

    // ---- coord layer 1: [16,64] @ [64,64], input = m (cols 0..63) ----
    f32x4 acc3[4];
    #pragma unroll
    for (int nt = 0; nt < 4; ++nt) {
        const float b = sBias[128 + nt * 16 + lr];
        acc3[nt] = (f32x4){b, b, b, b};
    }
    #pragma unroll
    for (int c = 0; c < 2; ++c) {
        const bf16x8 af = *(const bf16x8*)&myA[c * 32 + ks * 8];
        #pragma unroll
        for (int nt = 0; nt < 4; ++nt) {
            const bf16x8 bf = *(const bf16x8*)&Wc1p[((c * 4 + nt) * 64 + l) * 8];
            acc3[nt] = __builtin_amdgcn_mfma_f32_16x16x32_bf16(af, bf, acc3[nt], 0, 0, 0);
        }
    }
    float part[4] = {0.0f, 0.0f, 0.0f, 0.0f};
    #pragma unroll
    for (int nt = 0; nt < 4; ++nt) {
        const float wv = sBias[192 + nt * 16 + lr];
        #pragma unroll
        for (int i = 0; i < 4; ++i) part[i] += silu_f(acc3[nt][i]) * wv;
    }
    #pragma unroll
    for (int m = 1; m <= 8; m <<= 1) {
        #pragma unroll
        for (int i = 0; i < 4; ++i) part[i] += __shfl_xor(part[i], m, 64);
    }
    if (lr == 0) {
        #pragma unroll
        for (int i = 0; i < 4; ++i) {
            const int slot = w * 16 + ks * 4 + i;
            const float dist = sGeom[slot * 4 + 3];
            const float g2 = fminf(fmaxf(2.0f * part[i], -30.0f), 30.0f);
            const float t = __expf(g2);
            const float th = (t - 1.0f) * rcp_fast(t + 1.0f);
            const float sc = th * 0.1f * rcp_fast(dist + EPS);
            sTrans[slot][0] = sGeom[slot * 4 + 0] * sc;
            sTrans[slot][1] = sGeom[slot * 4 + 1] * sc;
            sTrans[slot][2] = sGeom[slot * 4 + 2] * sc;
        }
    }

    // ---- m segmented reduce: wave reduces its OWN 16 rows (uniform branches),
    //      coalesced f32 atomics (64 consecutive floats per burst) ----
    {
        const int baserow = w * 16;
        int run_node = sRow[baserow];
        float runsum = 0.0f;
        #pragma unroll
        for (int r = 0; r < 16; ++r) {
            const int n = sRow[baserow + r];
            const float v = bf2f((unsigned short)sA[(baserow + r) * FSTR + l]);
            if (n != run_node) {
                atomicAdd(&mf[(size_t)run_node * 64 + l], runsum);
                run_node = n;
                runsum = v;
            } else {
                runsum += v;
            }
        }
        atomicAdd(&mf[(size_t)run_node * 64 + l], runsum);
    }

    // ---- trans segmented reduce: one walker thread per segment start ----
    __syncthreads();
    if (tid < 128) {
        const int s = tid;
        const int n = sRow[s];
        if (s == 0 || sRow[s - 1] != n) {
            float sx = 0.0f, sy = 0.0f, sz = 0.0f;
            int j = s;
            while (j < 128 && sRow[j] == n) {
                sx += sTrans[j][0];
                sy += sTrans[j][1];
                sz += sTrans[j][2];
                ++j;
            }
            atomicAdd(&xagg[n * 4 + 0], sx);
            atomicAdd(&xagg[n * 4 + 1], sy);
            atomicAdd(&xagg[n * 4 + 2], sz);
        }
    }
}

// ---------------- x finalize ----------------

__global__ void x_finalize_kernel(const float* __restrict__ x,
                                  const float* __restrict__ xagg,
                                  const int* __restrict__ offs,
                                  float* __restrict__ x_out)
{
    const int i = blockIdx.x * 256 + threadIdx.x;
    if (i >= NN) return;
    const float inv = rcp_fast((float)(offs[i + 1] - offs[i]) + EPS);
    x_out[(size_t)i * 3 + 0] = x[(size_t)i * 3 + 0] + xagg[i * 4 + 0] * inv;
    x_out[(size_t)i * 3 + 1] = x[(size_t)i * 3 + 1] + xagg[i * 4 + 1] * inv;
    x_out[(size_t)i * 3 + 2] = x[(size_t)i * 3 + 2] + xagg[i * 4 + 2] * inv;
}

// ---------------- MFMA node kernel: MLP + residual + LayerNorm ----------------

#define NSTR 136   // 128 + 8 pad

__global__ __launch_bounds__(256) void node_mfma_kernel(
    const unsigned short* __restrict__ hbf, const float* __restrict__ mf,
    const int* __restrict__ offs,
    const unsigned short* __restrict__ Wn1p, const unsigned short* __restrict__ Wn2p,
    const float* __restrict__ Bn1, const float* __restrict__ Bn2,
    const float* __restrict__ ln_g, const float* __restrict__ ln_b,
    float* __restrict__ h_out)
{
    __shared__ short sA[64 * NSTR];   // 17408 B
    __shared__ float sBias[256];      // Bn1 | Bn2 | g | b

    const int tid = threadIdx.x;
    const int n0 = blockIdx.x * 64;

    if (tid < 64) {
        sBias[tid]       = Bn1[tid];
        sBias[64 + tid]  = Bn2[tid];
        sBias[128 + tid] = ln_g[tid];
        sBias[192 + tid] = ln_b[tid];
    }
    {
        const int s = tid >> 2, q = tid & 3;
        const int node = n0 + s;
        const int n = (node < NN) ? node : (NN - 1);
        const uint4* hr = (const uint4*)(hbf + (size_t)n * 64);
        *(uint4*)&sA[s * NSTR + q * 16]     = hr[q * 2];
        *(uint4*)&sA[s * NSTR + q * 16 + 8] = hr[q * 2 + 1];
        // m_i = mf / (count + EPS), f32 -> bf16
        const float inv = rcp_fast((float)(offs[n + 1] - offs[n]) + EPS);
        const float4* mr = (const float4*)(mf + (size_t)n * 64) + q * 4;
        #pragma unroll
        for (int c2 = 0; c2 < 2; ++c2) {
            const float4 a = mr[c2 * 2], b = mr[c2 * 2 + 1];
            uint4 u;
            u.x = pk2_hw(a.x * inv, a.y * inv); u.y = pk2_hw(a.z * inv, a.w * inv);
            u.z = pk2_hw(b.x * inv, b.y * inv); u.w = pk2_hw(b.z * inv, b.w * inv);
            *(uint4*)&sA[s * NSTR + 64 + q * 16 + c2 * 8] = u;
        }
    }
    __syncthreads();

    const int w = tid >> 6, l = tid & 63;
    const int lr = l & 15;
    const int ks = l >> 4;
    const short* myA = &sA[(w * 16 + lr) * NSTR];

    // ---- node layer 1: [16,128] @ [128,64] ----
    f32x4 acc[4];
    #pragma unroll
    for (int nt = 0; nt < 4; ++nt) {
        const float b = sBias[nt * 16 + lr];
        acc[nt] = (f32x4){b, b, b, b};
    }
    #pragma unroll
    for (int c = 0; c < 4; ++c) {
        const bf16x8 af = *(const bf16x8*)&myA[c * 32 + ks * 8];
        #pragma unroll
        for (int nt = 0; nt < 4; ++nt) {
            const bf16x8 bf = *(const bf16x8*)&Wn1p[((c * 4 + nt) * 64 + l) * 8];
            acc[nt] = __builtin_amdgcn_mfma_f32_16x16x32_bf16(af, bf, acc[nt], 0, 0, 0);
        }
    }
    {
        short* pw = &sA[(w * 16 + ks * 4) * NSTR + 64 + lr];
        #pragma unroll
        for (int nt = 0; nt < 4; ++nt)
            #pragma unroll
            for (int i = 0; i < 4; ++i)
                pw[i * NSTR + nt * 16] = f2bf_hw(silu_f(acc[nt][i]));
    }

    // ---- node layer 2: [16,64] @ [64,64] ----
    f32x4 acc2[4];
    #pragma unroll
    for (int nt = 0; nt < 4; ++nt) {
        const float b = sBias[64 + nt * 16 + lr];
        acc2[nt] = (f32x4){b, b, b, b};
    }
    #pragma unroll
    for (int c = 0; c < 2; ++c) {
        const bf16x8 af = *(const bf16x8*)&myA[64 + c * 32 + ks * 8];
        #pragma unroll
        for (int nt = 0; nt < 4; ++nt) {
            const bf16x8 bf = *(const bf16x8*)&Wn2p[((c * 4 + nt) * 64 + l) * 8];
            acc2[nt] = __builtin_amdgcn_mfma_f32_16x16x32_bf16(af, bf, acc2[nt], 0, 0, 0);
        }
    }

    float a2[4][4];
    #pragma unroll
    for (int nt = 0; nt < 4; ++nt)
        #pragma unroll
        for (int i = 0; i < 4; ++i)
            a2[nt][i] = acc2[nt][i] +
                bf2f((unsigned short)sA[(w * 16 + ks * 4 + i) * NSTR + nt * 16 + lr]);

    float su[4];
    #pragma unroll
    for (int i = 0; i < 4; ++i)
        su[i] = a2[0][i] + a2[1][i] + a2[2][i] + a2[3][i];
    #pragma unroll
    for (int m = 1; m <= 8; m <<= 1)
        #pragma unroll
        for (int i = 0; i < 4; ++i) su[i] += __shfl_xor(su[i], m, 64);
    float mu[4];
    #pragma unroll
    for (int i = 0; i < 4; ++i) mu[i] = su[i] * (1.0f / 64.0f);

    float sv[4];
    #pragma unroll
    for (int i = 0; i < 4; ++i) {
        float s = 0.0f;
        #pragma unroll
        for (int nt = 0; nt < 4; ++nt) {
            const float d = a2[nt][i] - mu[i];
            s += d * d;
        }
        sv[i] = s;
    }
    #pragma unroll
    for (int m = 1; m <= 8; m <<= 1)
        #pragma unroll
        for (int i = 0; i < 4; ++i) sv[i] += __shfl_xor(sv[i], m, 64);

    #pragma unroll
    for (int i = 0; i < 4; ++i) {
        const float rstd = rsqrtf(sv[i] * (1.0f / 64.0f) + LN_EPS);
        const int node = n0 + w * 16 + ks * 4 + i;
        if (node < NN) {
            #pragma unroll
            for (int nt = 0; nt < 4; ++nt) {
                const int colj = nt * 16 + lr;
                h_out[(size_t)node * 64 + colj] =
                    (a2[nt][i] - mu[i]) * rstd * sBias[128 + colj] + sBias[192 + colj];
            }
        }
    }
}

// ---------------- fallback (atomic path, minimal ws) ----------------

__global__ __launch_bounds__(64) void edge_atomic_kernel(
    const float* __restrict__ h, const float* __restrict__ x,
    const int* __restrict__ ei, const float* __restrict__ ea,
    const float* __restrict__ W1, const float* __restrict__ B1,
    const float* __restrict__ W2, const float* __restrict__ B2,
    const float* __restrict__ Wc1, const float* __restrict__ Bc1,
    const float* __restrict__ Wc2,
    float* __restrict__ m_acc, float* __restrict__ xagg)
{
    __shared__ float lds[64 * 64];
    const int lane = threadIdx.x;
    const int e = blockIdx.x * 64 + lane;

    const int row = ei[e];
    const int col = ei[NE + e];

    const float dx = x[row * 3 + 0] - x[col * 3 + 0];
    const float dy = x[row * 3 + 1] - x[col * 3 + 1];
    const float dz = x[row * 3 + 2] - x[col * 3 + 2];
    const float dist_sq = dx * dx + dy * dy + dz * dz;
    const float dist = sqrtf(dist_sq + EPS);
    const float logd = log1pf(dist_sq);

    float a1[64];
    #pragma unroll
    for (int j = 0; j < 64; ++j) a1[j] = B1[j];
    const float4* hr4 = (const float4*)(h + (size_t)row * 64);
    for (int k4 = 0; k4 < 16; ++k4) {
        const float4 v4 = hr4[k4];
        #pragma unroll
        for (int c = 0; c < 4; ++c) {
            const float v = (c == 0) ? v4.x : (c == 1) ? v4.y : (c == 2) ? v4.z : v4.w;
            const float* w = W1 + (k4 * 4 + c) * 64;
            #pragma unroll
            for (int j = 0; j < 64; ++j) a1[j] = fmaf(v, w[j], a1[j]);
        }
    }
    const float4* hc4 = (const float4*)(h + (size_t)col * 64);
    for (int k4 = 0; k4 < 16; ++k4) {
        const float4 v4 = hc4[k4];
        #pragma unroll
        for (int c = 0; c < 4; ++c) {
            const float v = (c == 0) ? v4.x : (c == 1) ? v4.y : (c == 2) ? v4.z : v4.w;
            const float* w = W1 + (64 + k4 * 4 + c) * 64;
            #pragma unroll
            for (int j = 0; j < 64; ++j) a1[j] = fmaf(v, w[j], a1[j]);
        }
    }
    {
        const float* w = W1 + 128 * 64;
        #pragma unroll
        for (int j = 0; j < 64; ++j) a1[j] = fmaf(logd, w[j], a1[j]);
    }
    const float4* ea4 = (const float4*)(ea + (size_t)e * 16);
    for (int k4 = 0; k4 < 4; ++k4) {
        const float4 v4 = ea4[k4];
        #pragma unroll
        for (int c = 0; c < 4; ++c) {
            const float v = (c == 0) ? v4.x : (c == 1) ? v4.y : (c == 2) ? v4.z : v4.w;
            const float* w = W1 + (129 + k4 * 4 + c) * 64;
            #pragma unroll
            for (int j = 0; j < 64; ++j) a1[j] = fmaf(v, w[j], a1[j]);
        }
    }

    #pragma unroll
    for (int j = 0; j < 64; ++j) lds[j * 64 + lane] = silu_f(a1[j]);

    float a2[64];
    #pragma unroll
    for (int j = 0; j < 64; ++j) a2[j] = B2[j];
    for (int k = 0; k < 64; ++k) {
        const float v = lds[k * 64 + lane];
        const float* w = W2 + k * 64;
        #pragma unroll
        for (int j = 0; j < 64; ++j) a2[j] = fmaf(v, w[j], a2[j]);
    }

    float* mrow = m_acc + (size_t)row * 64;
    #pragma unroll
    for (int j = 0; j < 64; ++j) {
        const float mj = silu_f(a2[j]);
        lds[j * 64 + lane] = mj;
        atomicAdd(mrow + j, mj);
    }

    float t[64];
    #pragma unroll
    for (int j = 0; j < 64; ++j) t[j] = Bc1[j];
    for (int k = 0; k < 64; ++k) {
        const float v = lds[k * 64 + lane];
        const float* w = Wc1 + k * 64;
        #pragma unroll
        for (int j = 0; j < 64; ++j) t[j] = fmaf(v, w[j], t[j]);
    }
    float g = 0.0f;
    #pragma unroll
    for (int j = 0; j < 64; ++j) g += silu_f(t[j]) * Wc2[j];

    const float s = tanhf(g) * 0.1f / (dist + EPS);
    atomicAdd(&xagg[row * 4 + 0], dx * s);
    atomicAdd(&xagg[row * 4 + 1], dy * s);
    atomicAdd(&xagg[row * 4 + 2], dz * s);
    atomicAdd(&xagg[row * 4 + 3], 1.0f);
}

__global__ __launch_bounds__(64) void node_csr_kernel(
    const float* __restrict__ h,
    const float* __restrict__ m_i,
    const float* __restrict__ Wn1, const float* __restrict__ Bn1,
    const float* __restrict__ Wn2, const float* __restrict__ Bn2,
    const float* __restrict__ ln_g, const float* __restrict__ ln_b,
    float* __restrict__ h_out)
{
    __shared__ float lds[64 * 64];
    const int lane = threadIdx.x;
    const int node = blockIdx.x * 64 + lane;
    const bool act = node < NN;
    const int n = act ? node : 0;

    float a1[64];
    #pragma unroll
    for (int j = 0; j < 64; ++j) a1[j] = Bn1[j];

    const float* hr = h + (size_t)n * 64;
    const float4* hr4 = (const float4*)hr;
    for (int k4 = 0; k4 < 16; ++k4) {
        const float4 v4 = hr4[k4];
        #pragma unroll
        for (int c = 0; c < 4; ++c) {
            const float v = (c == 0) ? v4.x : (c == 1) ? v4.y : (c == 2) ? v4.z : v4.w;
            const float* w = Wn1 + (k4 * 4 + c) * 64;
            #pragma unroll
            for (int j = 0; j < 64; ++j) a1[j] = fmaf(v, w[j], a1[j]);
        }
    }
    const float4* mr4 = (const float4*)(m_i + (size_t)n * 64);
    for (int k4 = 0; k4 < 16; ++k4) {
        const float4 v4 = mr4[k4];
        #pragma unroll
        for (int c = 0; c < 4; ++c) {
            const float v = (c == 0) ? v4.x : (c == 1) ? v4.y : (c == 2) ? v4.z : v4.w;
            const float* w = Wn1 + (64 + k4 * 4 + c) * 64;
            #pragma unroll
            for (int j = 0; j < 64; ++j) a1[j] = fmaf(v, w[j], a1[j]);
        }
    }

    #pragma unroll
    for (int j = 0; j < 64; ++j) lds[j * 64 + lane] = silu_f(a1[j]);

    float a2[64];
    #pragma unroll
    for (int j = 0; j < 64; ++j) a2[j] = Bn2[j];
    for (int k = 0; k < 64; ++k) {
        const float v = lds[k * 64 + lane];
        const float* w = Wn2 + k * 64;
        #pragma unroll
        for (int j = 0; j < 64; ++j) a2[j] = fmaf(v, w[j], a2[j]);
    }

    float mu = 0.0f;
    #pragma unroll
    for (int j = 0; j < 64; ++j) { a2[j] += hr[j]; mu += a2[j]; }
    mu *= (1.0f / 64.0f);
    float var = 0.0f;
    #pragma unroll
    for (int j = 0; j < 64; ++j) { const float d = a2[j] - mu; var += d * d; }
    var *= (1.0f / 64.0f);
    const float rstd = rsqrtf(var + LN_EPS);

    if (act) {
        #pragma unroll
        for (int j = 0; j < 64; ++j)
            h_out[(size_t)n * 64 + j] = (a2[j] - mu) * rstd * ln_g[j] + ln_b[j];
    }
}

__global__ void x_atomic_kernel(const float* __restrict__ x, const float* __restrict__ xagg,
                                float* __restrict__ x_out)
{
    const int i = blockIdx.x * 256 + threadIdx.x;
    if (i >= NN) return;
    const float inv_cnt = 1.0f / (xagg[i * 4 + 3] + EPS);
    #pragma unroll
    for (int c = 0; c < 3; ++c)
        x_out[(size_t)i * 3 + c] = x[(size_t)i * 3 + c] + xagg[i * 4 + c] * inv_cnt;
}

__global__ void div_m_kernel(float* __restrict__ m_acc, const float* __restrict__ xagg) {
    const int i = blockIdx.x * 256 + threadIdx.x;
    if (i >= NN * 64) return;
    m_acc[i] /= (xagg[(i >> 6) * 4 + 3] + EPS);
}

// ---------------- launch ----------------

extern "C" void kernel_launch(void* const* d_in, const int* in_sizes, int n_in,
                              void* d_out, int out_size, void* d_ws, size_t ws_size,
                              hipStream_t stream)
{
    const float* h   = (const float*)d_in[0];
    const float* x   = (const float*)d_in[1];
    const int*   ei  = (const int*)d_in[2];
    const float* ea  = (const float*)d_in[3];
    const float* W1  = (const float*)d_in[4];
    const float* B1  = (const float*)d_in[5];
    const float* W2  = (const float*)d_in[6];
    const float* B2  = (const float*)d_in[7];
    const float* Wn1 = (const float*)d_in[8];
    const float* Bn1 = (const float*)d_in[9];
    const float* Wn2 = (const float*)d_in[10];
    const float* Bn2 = (const float*)d_in[11];
    const float* Wc1 = (const float*)d_in[12];
    const float* Bc1 = (const float*)d_in[13];
    const float* Wc2 = (const float*)d_in[14];
    const float* lng = (const float*)d_in[15];
    const float* lnb = (const float*)d_in[16];

    float* out   = (float*)d_out;
    float* x_out = out + (size_t)NN * 64;

    size_t off = 0;
    auto take = [&](size_t bytes) { size_t p = off; off = (off + bytes + 255) & ~(size_t)255; return p; };
    char* ws = (char*)d_ws;
    const size_t o_quads  = take((size_t)NE * 16);         // int4 {eid,row,col,-}
    const size_t o_counts = take((size_t)NN * 4);
    const size_t o_rank   = take((size_t)NE * 4);          // within-node rank per edge
    const size_t o_offs   = take((size_t)(NN + 1) * 4);
    const size_t o_bsum   = take((size_t)1024 * 4);
    const size_t o_hbf    = take((size_t)NN * 64 * 2);     // bf16 h
    const size_t o_mf     = take((size_t)NN * 64 * 4);     // f32 m sum accumulator
    const size_t o_xagg   = take((size_t)NN * 4 * 4);      // f32 x aggregate
    const size_t o_w1p    = take((size_t)10240 * 2);
    const size_t o_w2p    = take((size_t)4096 * 2);
    const size_t o_wc1p   = take((size_t)4096 * 2);
    const size_t o_wn1p   = take((size_t)8192 * 2);
    const size_t o_wn2p   = take((size_t)4096 * 2);
    const size_t need = off;

    if (ws_size >= need) {
        int4*  quads  = (int4*)(ws + o_quads);
        int*   counts = (int*)(ws + o_counts);
        int*   rank   = (int*)(ws + o_rank);
        int*   offs   = (int*)(ws + o_offs);
        int*   bsum   = (int*)(ws + o_bsum);
        unsigned short* hbf   = (unsigned short*)(ws + o_hbf);
        float* mf     = (float*)(ws + o_mf);
        float* xagg   = (float*)(ws + o_xagg);
        unsigned short* W1p   = (unsigned short*)(ws + o_w1p);
        unsigned short* W2p   = (unsigned short*)(ws + o_w2p);
        unsigned short* Wc1p  = (unsigned short*)(ws + o_wc1p);
        unsigned short* Wn1p  = (unsigned short*)(ws + o_wn1p);
        unsigned short* Wn2p  = (unsigned short*)(ws + o_wn2p);

        hipMemsetAsync(counts, 0, (size_t)NN * 4, stream);
        hipMemsetAsync(mf, 0, (size_t)NN * 64 * 4, stream);
        hipMemsetAsync(xagg, 0, (size_t)NN * 4 * 4, stream);

        prep_count_kernel<<<HB_BLOCKS + PW_BLOCKS + CNT_BLOCKS, 256, 0, stream>>>(
            h, W1, W2, Wc1, Wn1, Wn2, ei,
            hbf, W1p, W2p, Wc1p, Wn1p, Wn2p, counts, rank);

        const int nblk = (NN + SCAN_B - 1) / SCAN_B;
        scan1_kernel<<<nblk, SCAN_B, 0, stream>>>(counts, offs, bsum);
        scan2_kernel<<<1, SCAN_B, 0, stream>>>(bsum, nblk, offs);
        scan3_kernel<<<nblk, SCAN_B, 0, stream>>>(offs, bsum);
        scatter_kernel<<<(NE + 255) / 256, 256, 0, stream>>>(ei, offs, rank, quads);

        edge_mfma_kernel<<<NE / 128, 512, 0, stream>>>(hbf, x, ea, W1p, W2p, Wc1p,
                                                       B1, B2, Bc1, Wc2, quads,
                                                       mf, xagg);
        node_mfma_kernel<<<(NN + 63) / 64, 256, 0, stream>>>(hbf, mf, offs, Wn1p, Wn2p,
                                                             Bn1, Bn2, lng, lnb, out);
        x_finalize_kernel<<<(NN + 255) / 256, 256, 0, stream>>>(x, xagg, offs, x_out);
    } else {
        float* m_acc = out;
        float* xagg  = (float*)d_ws;
        hipMemsetAsync(m_acc, 0, (size_t)NN * 64 * 4, stream);
        hipMemsetAsync(xagg, 0, (size_t)NN * 4 * 4, stream);
        edge_atomic_kernel<<<NE / 64, 64, 0, stream>>>(h, x, ei, ea, W1, B1, W2, B2,
                                                       Wc1, Bc1, Wc2, m_acc, xagg);
        div_m_kernel<<<(NN * 64 + 255) / 256, 256, 0, stream>>>(m_acc, xagg);
        node_csr_kernel<<<(NN + 63) / 64, 64, 0, stream>>>(h, m_acc, Wn1, Bn1, Wn2, Bn2,
                                                           lng, lnb, m_acc);
        x_atomic_kernel<<<(NN + 255) / 256, 256, 0, stream>>>(x, xagg, m_acc + (size_t)NN * 64);
    }
}